// Round 15
// baseline (563.417 us; speedup 1.0000x reference)
//
#include <hip/hip_runtime.h>
#include <hip/hip_bf16.h>
#include <math.h>

#define TB 256

typedef __attribute__((ext_vector_type(8))) short bf16x8;
typedef __attribute__((ext_vector_type(4))) float f32x4;
typedef __attribute__((ext_vector_type(2))) float f32x2;

__device__ inline float bf2f(ushort u) {
    union { uint u; float f; } c; c.u = ((uint)u) << 16; return c.f;
}
__device__ inline ushort f2bf(float f) {
    __hip_bfloat16 h = __float2bfloat16(f);
    union { __hip_bfloat16 h; ushort u; } c; c.h = h; return c.u;
}
__device__ inline float i2f(int i) { union { int i; float f; } c; c.i = i; return c.f; }
__device__ inline int f2i(float f) { union { float f; int i; } c; c.f = f; return c.i; }

// ---------------- fp8 e4m3 encode/decode (HW cvt preferred; manual fallback) ----------------

#if __has_builtin(__builtin_amdgcn_cvt_pk_fp8_f32) && __has_builtin(__builtin_amdgcn_cvt_pk_f32_fp8)
#define FP8_HW 1
#endif

__device__ inline unsigned char f2fp8(float v) {
#ifdef FP8_HW
    unsigned int r = __builtin_amdgcn_cvt_pk_fp8_f32(v, v, 0u, false);
    return (unsigned char)(r & 0xffu);
#else
    unsigned int s = (v < 0.f) ? 0x80u : 0u;
    float a = fabsf(v);
    if (a >= 448.f) return (unsigned char)(s | 0x7E);
    if (a < 0.015625f) {
        int m = (int)(a * 512.f + 0.5f);
        if (m >= 8) return (unsigned char)(s | 0x08);
        return (unsigned char)(s | m);
    }
    int e; float fr = frexpf(a, &e);
    int m = (int)(fr * 16.f + 0.5f) - 8;
    int E = e + 6;
    if (m == 8) { m = 0; E += 1; }
    if (E >= 16) return (unsigned char)(s | 0x7E);
    return (unsigned char)(s | (E << 3) | m);
#endif
}

#ifndef FP8_HW
__device__ inline float fp8_to_f(unsigned int b) {
    unsigned int s = (b & 0x80u) << 24;
    unsigned int e = (b >> 3) & 0xFu;
    unsigned int m = b & 7u;
    if (e == 0) { float val = (float)m * 0.001953125f; return s ? -val : val; }
    union { unsigned int u; float f; } c;
    c.u = s | ((e + 120u) << 23) | (m << 20);
    return c.f;
}
#endif

__device__ inline void fp8x4_fma(unsigned int v, float w, float4& acc) {
#ifdef FP8_HW
    f32x2 lo = __builtin_amdgcn_cvt_pk_f32_fp8(v, false);
    f32x2 hi = __builtin_amdgcn_cvt_pk_f32_fp8(v, true);
    acc.x = fmaf(lo.x, w, acc.x);
    acc.y = fmaf(lo.y, w, acc.y);
    acc.z = fmaf(hi.x, w, acc.z);
    acc.w = fmaf(hi.y, w, acc.w);
#else
    acc.x = fmaf(fp8_to_f(v & 0xff), w, acc.x);
    acc.y = fmaf(fp8_to_f((v >> 8) & 0xff), w, acc.y);
    acc.z = fmaf(fp8_to_f((v >> 16) & 0xff), w, acc.z);
    acc.w = fmaf(fp8_to_f(v >> 24), w, acc.w);
#endif
}

__device__ inline float fp8_dec1(unsigned int b) {
#ifdef FP8_HW
    f32x2 lo = __builtin_amdgcn_cvt_pk_f32_fp8(b & 0xffu, false);
    return lo.x;
#else
    return fp8_to_f(b & 0xffu);
#endif
}

// ---------------- fused setup: W1/W2 transpose+cast, bhist zero, deg init ----------------
// blocks [0,512): W1T; [512,576): W2T; 576: zero bhist; [577,...): deg=1

__global__ __launch_bounds__(256) void k_setup(const float* __restrict__ W1, ushort* __restrict__ W1T,
                                               const float* __restrict__ W2, ushort* __restrict__ W2T,
                                               int* __restrict__ bhist, int* __restrict__ deg, int n) {
    int b = blockIdx.x;
    int t = threadIdx.x;
    if (b < 512) {
        int id = b * 256 + t;                 // K=512, N=256
        int k = id >> 8, nn = id & 255;
        W1T[(size_t)nn * 512 + k] = f2bf(W1[id]);
    } else if (b < 576) {
        int id = (b - 512) * 256 + t;         // K=256, N=64
        int k = id >> 6, nn = id & 63;
        W2T[(size_t)nn * 256 + k] = f2bf(W2[id]);
    } else if (b == 576) {
        bhist[t] = 0;
    } else {
        int i = (b - 577) * 256 + t;
        if (i < n) deg[i] = 1;
    }
}

// ---------------- bucket partition (256 buckets by dst>>9) ----------------

__global__ __launch_bounds__(256) void k_bhist(const int* __restrict__ dst, int E,
                                               int* __restrict__ hist) {
    __shared__ int lh[256];
    int t = threadIdx.x;
    lh[t] = 0;
    __syncthreads();
    for (int e = blockIdx.x * blockDim.x + t; e < E; e += gridDim.x * blockDim.x)
        atomicAdd(&lh[dst[e] >> 9], 1);
    __syncthreads();
    if (lh[t]) atomicAdd(&hist[t], lh[t]);
}

__global__ __launch_bounds__(256) void k_bscan(const int* __restrict__ hist,
                                               int* __restrict__ bcur) {
    __shared__ int sh[256];
    int t = threadIdx.x;
    int v = hist[t];
    sh[t] = v;
    __syncthreads();
    for (int off = 1; off < 256; off <<= 1) {
        int u = (t >= off) ? sh[t - off] : 0;
        __syncthreads();
        sh[t] += u;
        __syncthreads();
    }
    bcur[t] = sh[t] - v;   // exclusive
}

// partition + deg count fused (saves a 25.6MB re-read pass)
__global__ __launch_bounds__(256) void k_partition(const int* __restrict__ src,
                                                   const int* __restrict__ dst, int E,
                                                   int* __restrict__ bcur,
                                                   int* __restrict__ deg,
                                                   int2* __restrict__ sorted) {
    __shared__ int lh[256];
    const int per = 8192;
    int e0 = blockIdx.x * per;
    int e1 = min(E, e0 + per);
    int t = threadIdx.x;
    lh[t] = 0;
    __syncthreads();
    for (int e = e0 + t; e < e1; e += 256)
        atomicAdd(&lh[dst[e] >> 9], 1);
    __syncthreads();
    int cnt = lh[t];
    int base = cnt ? atomicAdd(&bcur[t], cnt) : 0;
    __syncthreads();
    lh[t] = base;
    __syncthreads();
    for (int e = e0 + t; e < e1; e += 256) {
        int d = dst[e], s = src[e];
        int pos = atomicAdd(&lh[d >> 9], 1);
        sorted[pos] = make_int2(s, d);
        atomicAdd(&deg[d], 1);
    }
}

// ---------------- hierarchical exclusive scan of (deg-1); also writes dis, cursor ----------------

__global__ __launch_bounds__(256) void k_scan_partial(const int* __restrict__ deg,
                                                      int* __restrict__ partials, int n) {
    __shared__ int red[256];
    int base = blockIdx.x * 1024;
    int t = threadIdx.x;
    int s = 0;
    #pragma unroll
    for (int j = 0; j < 4; ++j) {
        int i = base + t * 4 + j;
        if (i < n) s += deg[i] - 1;
    }
    red[t] = s;
    __syncthreads();
    for (int off = 128; off > 0; off >>= 1) {
        if (t < off) red[t] += red[t + off];
        __syncthreads();
    }
    if (t == 0) partials[blockIdx.x] = red[0];
}

__global__ __launch_bounds__(128) void k_scan_tops(int* __restrict__ partials, int B) {
    __shared__ int sh[128];
    int t = threadIdx.x;
    int v = (t < B) ? partials[t] : 0;
    sh[t] = v;
    __syncthreads();
    for (int off = 1; off < 128; off <<= 1) {
        int u = (t >= off) ? sh[t - off] : 0;
        __syncthreads();
        sh[t] += u;
        __syncthreads();
    }
    if (t < B) partials[t] = sh[t] - v;
}

__global__ __launch_bounds__(256) void k_scan_final(const int* __restrict__ deg,
                                                    const int* __restrict__ partials,
                                                    int* __restrict__ offsets,
                                                    int* __restrict__ cursor,
                                                    float* __restrict__ dis, int n) {
    __shared__ int sh[256];
    int base = blockIdx.x * 1024;
    int t = threadIdx.x;
    int c[4];
    int s = 0;
    #pragma unroll
    for (int j = 0; j < 4; ++j) {
        int i = base + t * 4 + j;
        c[j] = (i < n) ? deg[i] - 1 : 0;
        s += c[j];
    }
    sh[t] = s;
    __syncthreads();
    for (int off = 1; off < 256; off <<= 1) {
        int u = (t >= off) ? sh[t - off] : 0;
        __syncthreads();
        sh[t] += u;
        __syncthreads();
    }
    int run = partials[blockIdx.x] + sh[t] - s;
    #pragma unroll
    for (int j = 0; j < 4; ++j) {
        int i = base + t * 4 + j;
        if (i < n) {
            offsets[i] = run;
            cursor[i]  = run;
            dis[i] = rsqrtf((float)(c[j] + 1));
            run += c[j];
        }
    }
}

__global__ __launch_bounds__(256) void k_fill_sorted(const int2* __restrict__ sorted, int E,
                                                     int* cursor,
                                                     const float* __restrict__ dis,
                                                     int2* __restrict__ csr_p) {
    int e = blockIdx.x * blockDim.x + threadIdx.x;
    if (e >= E) return;
    int2 p = sorted[e];
    int pos = atomicAdd(&cursor[p.y], 1);
    csr_p[pos] = make_int2(p.x, f2i(dis[p.x]));
}

// ---------------- GEMM1 (LDS): h1_fp8[M,256] = fp8(bf16(A_fp32[M,512]) @ W1T[256,512]^T)

__global__ __launch_bounds__(256) void k_gemm1(const float* __restrict__ A,
                                               const ushort* __restrict__ BT,
                                               unsigned char* __restrict__ C,
                                               int M, int N, int K) {
    const int BM = 64, BK = 32;
    __shared__ ushort Al[BM][40];
    __shared__ ushort Bl[256][40];

    const int t    = threadIdx.x;
    const int lane = t & 63;
    const int wid  = t >> 6;
    const int m0   = blockIdx.x * BM;
    const int lr   = lane & 15;
    const int lg   = lane >> 4;

    f32x4 acc[4][4] = {};

    for (int k0 = 0; k0 < K; k0 += BK) {
        {
            int row = t >> 2, q = t & 3;
            int gm = m0 + row;
            ushort4 o0 = {0,0,0,0}, o1 = {0,0,0,0};
            if (gm < M) {
                const float* ap = A + (size_t)gm * K + k0 + q * 8;
                float4 u = *(const float4*)ap;
                float4 w = *(const float4*)(ap + 4);
                o0.x = f2bf(u.x); o0.y = f2bf(u.y); o0.z = f2bf(u.z); o0.w = f2bf(u.w);
                o1.x = f2bf(w.x); o1.y = f2bf(w.y); o1.z = f2bf(w.z); o1.w = f2bf(w.w);
            }
            *(ushort4*)(&Al[row][q * 8])     = o0;
            *(ushort4*)(&Al[row][q * 8 + 4]) = o1;
        }
        #pragma unroll
        for (int it = 0; it < 4; ++it) {
            int c = t + it * 256;
            int row = c >> 2, q = c & 3;
            uint4 v = *(const uint4*)(BT + (size_t)row * K + k0 + q * 8);
            *(uint4*)(&Bl[row][q * 8]) = v;
        }
        __syncthreads();

        bf16x8 fa[4], fb[4];
        #pragma unroll
        for (int mi = 0; mi < 4; ++mi)
            fa[mi] = *(const bf16x8*)(&Al[mi * 16 + lr][lg * 8]);
        #pragma unroll
        for (int ni = 0; ni < 4; ++ni)
            fb[ni] = *(const bf16x8*)(&Bl[wid * 64 + ni * 16 + lr][lg * 8]);
        #pragma unroll
        for (int mi = 0; mi < 4; ++mi)
            #pragma unroll
            for (int ni = 0; ni < 4; ++ni)
                acc[mi][ni] = __builtin_amdgcn_mfma_f32_16x16x32_bf16(fa[mi], fb[ni], acc[mi][ni], 0, 0, 0);
        __syncthreads();
    }

    #pragma unroll
    for (int mi = 0; mi < 4; ++mi) {
        int rbase = m0 + mi * 16 + lg * 4;
        #pragma unroll
        for (int v = 0; v < 4; ++v) {
            int gm = rbase + v;
            if (gm < M) {
                #pragma unroll
                for (int ni = 0; ni < 4; ++ni)
                    C[(size_t)gm * N + wid * 64 + ni * 16 + lr] = f2fp8(acc[mi][ni][v]);
            }
        }
    }
}

// ---------------- GEMM2 (LDS): h2_fp8[M,64] = fp8(relu(A_bf16[M,256]) @ W2T[64,256]^T) ----------------

__device__ inline uint relu_pk(uint u) {
    uint lo = u & 0x0000FFFFu;
    uint hi = u & 0xFFFF0000u;
    if (u & 0x00008000u) lo = 0;
    if (u & 0x80000000u) hi = 0;
    return lo | hi;
}

__global__ __launch_bounds__(256) void k_gemm2(const ushort* __restrict__ A,
                                               const ushort* __restrict__ BT,
                                               unsigned char* __restrict__ C,
                                               int M, int N, int K) {
    const int BM = 128, BK = 32;
    __shared__ ushort Al[BM][40];
    __shared__ ushort Bl[64][40];

    const int t    = threadIdx.x;
    const int lane = t & 63;
    const int wid  = t >> 6;
    const int wm   = wid >> 1, wn = wid & 1;
    const int m0   = blockIdx.x * BM;
    const int lr   = lane & 15;
    const int lg   = lane >> 4;

    f32x4 acc[4][2] = {};

    for (int k0 = 0; k0 < K; k0 += BK) {
        #pragma unroll
        for (int i = 0; i < 2; ++i) {
            int c = t + i * 256;
            int row = c >> 2, q = c & 3;
            int gm = m0 + row;
            uint4 v = make_uint4(0, 0, 0, 0);
            if (gm < M) v = *(const uint4*)(A + (size_t)gm * K + k0 + q * 8);
            v.x = relu_pk(v.x); v.y = relu_pk(v.y); v.z = relu_pk(v.z); v.w = relu_pk(v.w);
            *(uint4*)(&Al[row][q * 8]) = v;
        }
        {
            int row = t >> 2, q = t & 3;
            uint4 v = *(const uint4*)(BT + (size_t)(row) * K + k0 + q * 8);
            *(uint4*)(&Bl[row][q * 8]) = v;
        }
        __syncthreads();

        bf16x8 fa[4], fb[2];
        #pragma unroll
        for (int mi = 0; mi < 4; ++mi)
            fa[mi] = *(const bf16x8*)(&Al[wm * 64 + mi * 16 + lr][lg * 8]);
        #pragma unroll
        for (int ni = 0; ni < 2; ++ni)
            fb[ni] = *(const bf16x8*)(&Bl[wn * 32 + ni * 16 + lr][lg * 8]);
        #pragma unroll
        for (int mi = 0; mi < 4; ++mi)
            #pragma unroll
            for (int ni = 0; ni < 2; ++ni)
                acc[mi][ni] = __builtin_amdgcn_mfma_f32_16x16x32_bf16(fa[mi], fb[ni], acc[mi][ni], 0, 0, 0);
        __syncthreads();
    }

    #pragma unroll
    for (int mi = 0; mi < 4; ++mi) {
        int rbase = m0 + wm * 64 + mi * 16 + lg * 4;
        #pragma unroll
        for (int v = 0; v < 4; ++v) {
            int gm = rbase + v;
            if (gm < M) {
                #pragma unroll
                for (int ni = 0; ni < 2; ++ni)
                    C[(size_t)gm * N + wn * 32 + ni * 16 + lr] = f2fp8(acc[mi][ni][v]);
            }
        }
    }
}

// ---------------- gather aggregation (fp8 h1), one wave per dst node, 4-deep MLP ----------------

__global__ __launch_bounds__(256) void k_agg256(const unsigned char* __restrict__ h,
                                                const int2* __restrict__ csr_p,
                                                const int* __restrict__ off,
                                                const int* __restrict__ deg,
                                                const float* __restrict__ dis,
                                                const float* __restrict__ bias,
                                                ushort* __restrict__ out, int n) {
    int wave = (int)((blockIdx.x * (size_t)blockDim.x + threadIdx.x) >> 6);
    int lane = threadIdx.x & 63;
    if (wave >= n) return;
    const int i = wave;
    const float di = dis[i];
    const int beg = off[i], cnt = deg[i] - 1, end = beg + cnt;

    float4 bv = ((const float4*)bias)[lane];
    unsigned int hv = ((const unsigned int*)(h + (size_t)i * 256))[lane];
    float sl = di * di;
    float4 a0 = bv, a1 = {0,0,0,0}, a2 = {0,0,0,0}, a3 = {0,0,0,0};
    fp8x4_fma(hv, sl, a0);

    for (int base = beg; base < end; base += 64) {
        int m = end - base; if (m > 64) m = 64;
        int2 p = (lane < m) ? csr_p[base + lane] : make_int2(0, 0);
        int   msrc = p.x;
        float mw   = (lane < m) ? i2f(p.y) * di : 0.f;
        int k = 0;
        for (; k + 4 <= m; k += 4) {
            int s0 = __shfl(msrc, k),     s1 = __shfl(msrc, k + 1);
            int s2 = __shfl(msrc, k + 2), s3 = __shfl(msrc, k + 3);
            float w0 = __shfl(mw, k),     w1 = __shfl(mw, k + 1);
            float w2 = __shfl(mw, k + 2), w3 = __shfl(mw, k + 3);
            unsigned int v0 = ((const unsigned int*)(h + (size_t)s0 * 256))[lane];
            unsigned int v1 = ((const unsigned int*)(h + (size_t)s1 * 256))[lane];
            unsigned int v2 = ((const unsigned int*)(h + (size_t)s2 * 256))[lane];
            unsigned int v3 = ((const unsigned int*)(h + (size_t)s3 * 256))[lane];
            fp8x4_fma(v0, w0, a0);
            fp8x4_fma(v1, w1, a1);
            fp8x4_fma(v2, w2, a2);
            fp8x4_fma(v3, w3, a3);
        }
        for (; k < m; ++k) {
            int   s0 = __shfl(msrc, k); float w0 = __shfl(mw, k);
            unsigned int v0 = ((const unsigned int*)(h + (size_t)s0 * 256))[lane];
            fp8x4_fma(v0, w0, a0);
        }
    }
    ushort4 o;
    o.x = f2bf((a0.x + a1.x) + (a2.x + a3.x));
    o.y = f2bf((a0.y + a1.y) + (a2.y + a3.y));
    o.z = f2bf((a0.z + a1.z) + (a2.z + a3.z));
    o.w = f2bf((a0.w + a1.w) + (a2.w + a3.w));
    ((ushort4*)(out + (size_t)i * 256))[lane] = o;
}

// ---------------- agg64 (fp8 h2) fused with log-softmax: one wave per node; lane == class ----------------

__global__ __launch_bounds__(256) void k_agg64_lsm(const unsigned char* __restrict__ h,
                                                   const int2* __restrict__ csr_p,
                                                   const int* __restrict__ off,
                                                   const int* __restrict__ deg,
                                                   const float* __restrict__ dis,
                                                   const float* __restrict__ bias,
                                                   float* __restrict__ out, int n) {
    int wave = (int)((blockIdx.x * (size_t)blockDim.x + threadIdx.x) >> 6);
    int lane = threadIdx.x & 63;
    if (wave >= n) return;
    const int i = wave;
    const float di = dis[i];
    const int beg = off[i], cnt = deg[i] - 1, end = beg + cnt;

    float a0 = fmaf(fp8_dec1(h[(size_t)i * 64 + lane]), di * di, bias[lane]);
    float a1 = 0.f, a2 = 0.f, a3 = 0.f;

    for (int base = beg; base < end; base += 64) {
        int m = end - base; if (m > 64) m = 64;
        int2 p = (lane < m) ? csr_p[base + lane] : make_int2(0, 0);
        int   msrc = p.x;
        float mw   = (lane < m) ? i2f(p.y) * di : 0.f;
        int k = 0;
        for (; k + 4 <= m; k += 4) {
            int s0 = __shfl(msrc, k),     s1 = __shfl(msrc, k + 1);
            int s2 = __shfl(msrc, k + 2), s3 = __shfl(msrc, k + 3);
            float w0 = __shfl(mw, k),     w1 = __shfl(mw, k + 1);
            float w2 = __shfl(mw, k + 2), w3 = __shfl(mw, k + 3);
            a0 = fmaf(fp8_dec1(h[(size_t)s0 * 64 + lane]), w0, a0);
            a1 = fmaf(fp8_dec1(h[(size_t)s1 * 64 + lane]), w1, a1);
            a2 = fmaf(fp8_dec1(h[(size_t)s2 * 64 + lane]), w2, a2);
            a3 = fmaf(fp8_dec1(h[(size_t)s3 * 64 + lane]), w3, a3);
        }
        for (; k < m; ++k) {
            int s0 = __shfl(msrc, k); float w0 = __shfl(mw, k);
            a0 = fmaf(fp8_dec1(h[(size_t)s0 * 64 + lane]), w0, a0);
        }
    }
    float v = (a0 + a1) + (a2 + a3);

    float mx = v;
    #pragma unroll
    for (int o = 32; o > 0; o >>= 1) mx = fmaxf(mx, __shfl_xor(mx, o));
    float ex = __expf(v - mx);
    float ssum = ex;
    #pragma unroll
    for (int o = 32; o > 0; o >>= 1) ssum += __shfl_xor(ssum, o);
    out[(size_t)i * 64 + lane] = v - mx - logf(ssum);
}

// ---------------- launch ----------------

extern "C" void kernel_launch(void* const* d_in, const int* in_sizes, int n_in,
                              void* d_out, int out_size, void* d_ws, size_t ws_size,
                              hipStream_t stream) {
    const float* x  = (const float*)d_in[0];
    const int*   ei = (const int*)d_in[1];
    const float* W1 = (const float*)d_in[2];
    const float* b1 = (const float*)d_in[3];
    const float* W2 = (const float*)d_in[4];
    const float* b2 = (const float*)d_in[5];
    float* out = (float*)d_out;

    const int n = in_sizes[0] / 512;     // 100000
    const int E = in_sizes[1] / 2;       // 3200000
    const int* src = ei;
    const int* dst = ei + E;

    // workspace layout (bytes), 16B-aligned blocks
    char* ws = (char*)d_ws;
    int*    deg     = (int*)(ws + 0);               //    400,000
    int*    cursor  = (int*)(ws + 400000);          //    400,000
    float*  dis     = (float*)(ws + 800000);        //    400,000
    int*    offsets = (int*)(ws + 1200000);         //    400,000
    int*    partials= (int*)(ws + 1600000);         //        512
    int*    bhist   = (int*)(ws + 1600512);         //      1,024
    int*    bcur    = (int*)(ws + 1601536);         //      1,024
    int2*   csr_p   = (int2*)(ws + 1602560);        // 25,600,000 -> 27,202,560
    ushort* W1T     = (ushort*)(ws + 27202560);     //    262,144 -> 27,464,704
    ushort* W2T     = (ushort*)(ws + 27464704);     //     32,768 -> 27,497,472
    unsigned char* h1 = (unsigned char*)(ws + 27497472);  // 25,600,000 -> 53,097,472
    ushort* out1    = (ushort*)(ws + 53097472);     // 51,200,000 -> 104,297,472
    unsigned char* h2 = (unsigned char*)(ws + 104297472); //  6,400,000 -> 110,697,472
    int2*   sorted  = (int2*)(ws + 117097472);      // 25,600,000 -> 142,697,472

    const int SB = (n + 1023) / 1024;         // scan blocks
    const int PB = (E + 8191) / 8192;         // partition blocks
    const int SETUP_B = 577 + (n + 255) / 256;

    // 0. fused setup (weight transposes, bhist zero, deg init)
    k_setup<<<SETUP_B, 256, 0, stream>>>(W1, W1T, W2, W2T, bhist, deg, n);

    // 1. bucket partition of edges by dst>>9 (coalesced scatter) + deg count
    k_bhist<<<512, 256, 0, stream>>>(dst, E, bhist);
    k_bscan<<<1, 256, 0, stream>>>(bhist, bcur);
    k_partition<<<PB, 256, 0, stream>>>(src, dst, E, bcur, deg, sorted);

    // 2. CSR build from bucket-sorted edges
    k_scan_partial<<<SB, 256, 0, stream>>>(deg, partials, n);
    k_scan_tops<<<1, 128, 0, stream>>>(partials, SB);
    k_scan_final<<<SB, 256, 0, stream>>>(deg, partials, offsets, cursor, dis, n);
    k_fill_sorted<<<(E + TB - 1) / TB, TB, 0, stream>>>(sorted, E, cursor, dis, csr_p);

    // 3. h1 = fp8(x @ W1)
    k_gemm1<<<(n + 63) / 64, TB, 0, stream>>>(x, W1T, h1, n, 256, 512);

    // 4. out1 = b1 + Â h1  (fp8 gathers)
    k_agg256<<<(n + 3) / 4, TB, 0, stream>>>(h1, csr_p, offsets, deg, dis, b1, out1, n);

    // 5. h2 = fp8(relu(out1) @ W2)
    k_gemm2<<<(n + 127) / 128, TB, 0, stream>>>(out1, W2T, h2, n, 64, 256);

    // 6. out = b2 + Â h2, log-softmax fused (fp8 gathers, one 64B line per row)
    k_agg64_lsm<<<(n + 3) / 4, TB, 0, stream>>>(h2, csr_p, offsets, deg, dis, b2, out, n);
}

// Round 16
// 553.825 us; speedup vs baseline: 1.0173x; 1.0173x over previous
//
#include <hip/hip_runtime.h>
#include <hip/hip_bf16.h>
#include <math.h>

#define TB 256

typedef __attribute__((ext_vector_type(8))) short bf16x8;
typedef __attribute__((ext_vector_type(4))) float f32x4;
typedef __attribute__((ext_vector_type(2))) float f32x2;

__device__ inline float bf2f(ushort u) {
    union { uint u; float f; } c; c.u = ((uint)u) << 16; return c.f;
}
__device__ inline ushort f2bf(float f) {
    __hip_bfloat16 h = __float2bfloat16(f);
    union { __hip_bfloat16 h; ushort u; } c; c.h = h; return c.u;
}
__device__ inline float i2f(int i) { union { int i; float f; } c; c.i = i; return c.f; }
__device__ inline int f2i(float f) { union { float f; int i; } c; c.f = f; return c.i; }

// ---------------- fp8 e4m3 encode/decode (HW cvt preferred; manual fallback) ----------------

#if __has_builtin(__builtin_amdgcn_cvt_pk_fp8_f32) && __has_builtin(__builtin_amdgcn_cvt_pk_f32_fp8)
#define FP8_HW 1
#endif

__device__ inline unsigned char f2fp8(float v) {
#ifdef FP8_HW
    unsigned int r = __builtin_amdgcn_cvt_pk_fp8_f32(v, v, 0u, false);
    return (unsigned char)(r & 0xffu);
#else
    unsigned int s = (v < 0.f) ? 0x80u : 0u;
    float a = fabsf(v);
    if (a >= 448.f) return (unsigned char)(s | 0x7E);
    if (a < 0.015625f) {
        int m = (int)(a * 512.f + 0.5f);
        if (m >= 8) return (unsigned char)(s | 0x08);
        return (unsigned char)(s | m);
    }
    int e; float fr = frexpf(a, &e);
    int m = (int)(fr * 16.f + 0.5f) - 8;
    int E = e + 6;
    if (m == 8) { m = 0; E += 1; }
    if (E >= 16) return (unsigned char)(s | 0x7E);
    return (unsigned char)(s | (E << 3) | m);
#endif
}

#ifndef FP8_HW
__device__ inline float fp8_to_f(unsigned int b) {
    unsigned int s = (b & 0x80u) << 24;
    unsigned int e = (b >> 3) & 0xFu;
    unsigned int m = b & 7u;
    if (e == 0) { float val = (float)m * 0.001953125f; return s ? -val : val; }
    union { unsigned int u; float f; } c;
    c.u = s | ((e + 120u) << 23) | (m << 20);
    return c.f;
}
#endif

__device__ inline void fp8x4_fma(unsigned int v, float w, float4& acc) {
#ifdef FP8_HW
    f32x2 lo = __builtin_amdgcn_cvt_pk_f32_fp8(v, false);
    f32x2 hi = __builtin_amdgcn_cvt_pk_f32_fp8(v, true);
    acc.x = fmaf(lo.x, w, acc.x);
    acc.y = fmaf(lo.y, w, acc.y);
    acc.z = fmaf(hi.x, w, acc.z);
    acc.w = fmaf(hi.y, w, acc.w);
#else
    acc.x = fmaf(fp8_to_f(v & 0xff), w, acc.x);
    acc.y = fmaf(fp8_to_f((v >> 8) & 0xff), w, acc.y);
    acc.z = fmaf(fp8_to_f((v >> 16) & 0xff), w, acc.z);
    acc.w = fmaf(fp8_to_f(v >> 24), w, acc.w);
#endif
}

__device__ inline float fp8_dec1(unsigned int b) {
#ifdef FP8_HW
    f32x2 lo = __builtin_amdgcn_cvt_pk_f32_fp8(b & 0xffu, false);
    return lo.x;
#else
    return fp8_to_f(b & 0xffu);
#endif
}

// ---------------- fused setup: W1/W2 transpose+cast, bhist zero, deg init ----------------

__global__ __launch_bounds__(256) void k_setup(const float* __restrict__ W1, ushort* __restrict__ W1T,
                                               const float* __restrict__ W2, ushort* __restrict__ W2T,
                                               int* __restrict__ bhist, int* __restrict__ deg, int n) {
    int b = blockIdx.x;
    int t = threadIdx.x;
    if (b < 512) {
        int id = b * 256 + t;                 // K=512, N=256
        int k = id >> 8, nn = id & 255;
        W1T[(size_t)nn * 512 + k] = f2bf(W1[id]);
    } else if (b < 576) {
        int id = (b - 512) * 256 + t;         // K=256, N=64
        int k = id >> 6, nn = id & 63;
        W2T[(size_t)nn * 256 + k] = f2bf(W2[id]);
    } else if (b == 576) {
        bhist[t] = 0;
    } else {
        int i = (b - 577) * 256 + t;
        if (i < n) deg[i] = 1;
    }
}

// ---------------- bucket partition (256 buckets by dst>>9) ----------------

__global__ __launch_bounds__(256) void k_bhist(const int* __restrict__ dst, int E,
                                               int* __restrict__ hist) {
    __shared__ int lh[256];
    int t = threadIdx.x;
    lh[t] = 0;
    __syncthreads();
    for (int e = blockIdx.x * blockDim.x + t; e < E; e += gridDim.x * blockDim.x)
        atomicAdd(&lh[dst[e] >> 9], 1);
    __syncthreads();
    if (lh[t]) atomicAdd(&hist[t], lh[t]);
}

__global__ __launch_bounds__(256) void k_bscan(const int* __restrict__ hist,
                                               int* __restrict__ bcur) {
    __shared__ int sh[256];
    int t = threadIdx.x;
    int v = hist[t];
    sh[t] = v;
    __syncthreads();
    for (int off = 1; off < 256; off <<= 1) {
        int u = (t >= off) ? sh[t - off] : 0;
        __syncthreads();
        sh[t] += u;
        __syncthreads();
    }
    bcur[t] = sh[t] - v;   // exclusive
}

__global__ __launch_bounds__(256) void k_partition(const int* __restrict__ src,
                                                   const int* __restrict__ dst, int E,
                                                   int* __restrict__ bcur,
                                                   int2* __restrict__ sorted) {
    __shared__ int lh[256];
    const int per = 2048;
    int e0 = blockIdx.x * per;
    int e1 = min(E, e0 + per);
    int t = threadIdx.x;
    lh[t] = 0;
    __syncthreads();
    for (int e = e0 + t; e < e1; e += 256)
        atomicAdd(&lh[dst[e] >> 9], 1);
    __syncthreads();
    int cnt = lh[t];
    int base = cnt ? atomicAdd(&bcur[t], cnt) : 0;
    __syncthreads();
    lh[t] = base;
    __syncthreads();
    for (int e = e0 + t; e < e1; e += 256) {
        int d = dst[e], s = src[e];
        int pos = atomicAdd(&lh[d >> 9], 1);
        sorted[pos] = make_int2(s, d);
    }
}

// deg count on bucket-sorted edges: atomics land in a hot window
__global__ __launch_bounds__(256) void k_count_sorted(const int2* __restrict__ sorted, int E,
                                                      int* __restrict__ deg) {
    int e = blockIdx.x * blockDim.x + threadIdx.x;
    if (e < E) atomicAdd(&deg[sorted[e].y], 1);
}

// ---------------- hierarchical exclusive scan of (deg-1); also writes dis, cursor ----------------

__global__ __launch_bounds__(256) void k_scan_partial(const int* __restrict__ deg,
                                                      int* __restrict__ partials, int n) {
    __shared__ int red[256];
    int base = blockIdx.x * 1024;
    int t = threadIdx.x;
    int s = 0;
    #pragma unroll
    for (int j = 0; j < 4; ++j) {
        int i = base + t * 4 + j;
        if (i < n) s += deg[i] - 1;
    }
    red[t] = s;
    __syncthreads();
    for (int off = 128; off > 0; off >>= 1) {
        if (t < off) red[t] += red[t + off];
        __syncthreads();
    }
    if (t == 0) partials[blockIdx.x] = red[0];
}

__global__ __launch_bounds__(128) void k_scan_tops(int* __restrict__ partials, int B) {
    __shared__ int sh[128];
    int t = threadIdx.x;
    int v = (t < B) ? partials[t] : 0;
    sh[t] = v;
    __syncthreads();
    for (int off = 1; off < 128; off <<= 1) {
        int u = (t >= off) ? sh[t - off] : 0;
        __syncthreads();
        sh[t] += u;
        __syncthreads();
    }
    if (t < B) partials[t] = sh[t] - v;
}

__global__ __launch_bounds__(256) void k_scan_final(const int* __restrict__ deg,
                                                    const int* __restrict__ partials,
                                                    int* __restrict__ offsets,
                                                    int* __restrict__ cursor,
                                                    float* __restrict__ dis, int n) {
    __shared__ int sh[256];
    int base = blockIdx.x * 1024;
    int t = threadIdx.x;
    int c[4];
    int s = 0;
    #pragma unroll
    for (int j = 0; j < 4; ++j) {
        int i = base + t * 4 + j;
        c[j] = (i < n) ? deg[i] - 1 : 0;
        s += c[j];
    }
    sh[t] = s;
    __syncthreads();
    for (int off = 1; off < 256; off <<= 1) {
        int u = (t >= off) ? sh[t - off] : 0;
        __syncthreads();
        sh[t] += u;
        __syncthreads();
    }
    int run = partials[blockIdx.x] + sh[t] - s;
    #pragma unroll
    for (int j = 0; j < 4; ++j) {
        int i = base + t * 4 + j;
        if (i < n) {
            offsets[i] = run;
            cursor[i]  = run;
            dis[i] = rsqrtf((float)(c[j] + 1));
            run += c[j];
        }
    }
}

__global__ __launch_bounds__(256) void k_fill_sorted(const int2* __restrict__ sorted, int E,
                                                     int* cursor,
                                                     const float* __restrict__ dis,
                                                     int2* __restrict__ csr_p) {
    int e = blockIdx.x * blockDim.x + threadIdx.x;
    if (e >= E) return;
    int2 p = sorted[e];
    int pos = atomicAdd(&cursor[p.y], 1);
    csr_p[pos] = make_int2(p.x, f2i(dis[p.x]));
}

// ---------------- GEMM1 (LDS): h1_fp8[M,256] = fp8(bf16(A_fp32[M,512]) @ W1T[256,512]^T)

__global__ __launch_bounds__(256) void k_gemm1(const float* __restrict__ A,
                                               const ushort* __restrict__ BT,
                                               unsigned char* __restrict__ C,
                                               int M, int N, int K) {
    const int BM = 64, BK = 32;
    __shared__ ushort Al[BM][40];
    __shared__ ushort Bl[256][40];

    const int t    = threadIdx.x;
    const int lane = t & 63;
    const int wid  = t >> 6;
    const int m0   = blockIdx.x * BM;
    const int lr   = lane & 15;
    const int lg   = lane >> 4;

    f32x4 acc[4][4] = {};

    for (int k0 = 0; k0 < K; k0 += BK) {
        {
            int row = t >> 2, q = t & 3;
            int gm = m0 + row;
            ushort4 o0 = {0,0,0,0}, o1 = {0,0,0,0};
            if (gm < M) {
                const float* ap = A + (size_t)gm * K + k0 + q * 8;
                float4 u = *(const float4*)ap;
                float4 w = *(const float4*)(ap + 4);
                o0.x = f2bf(u.x); o0.y = f2bf(u.y); o0.z = f2bf(u.z); o0.w = f2bf(u.w);
                o1.x = f2bf(w.x); o1.y = f2bf(w.y); o1.z = f2bf(w.z); o1.w = f2bf(w.w);
            }
            *(ushort4*)(&Al[row][q * 8])     = o0;
            *(ushort4*)(&Al[row][q * 8 + 4]) = o1;
        }
        #pragma unroll
        for (int it = 0; it < 4; ++it) {
            int c = t + it * 256;
            int row = c >> 2, q = c & 3;
            uint4 v = *(const uint4*)(BT + (size_t)row * K + k0 + q * 8);
            *(uint4*)(&Bl[row][q * 8]) = v;
        }
        __syncthreads();

        bf16x8 fa[4], fb[4];
        #pragma unroll
        for (int mi = 0; mi < 4; ++mi)
            fa[mi] = *(const bf16x8*)(&Al[mi * 16 + lr][lg * 8]);
        #pragma unroll
        for (int ni = 0; ni < 4; ++ni)
            fb[ni] = *(const bf16x8*)(&Bl[wid * 64 + ni * 16 + lr][lg * 8]);
        #pragma unroll
        for (int mi = 0; mi < 4; ++mi)
            #pragma unroll
            for (int ni = 0; ni < 4; ++ni)
                acc[mi][ni] = __builtin_amdgcn_mfma_f32_16x16x32_bf16(fa[mi], fb[ni], acc[mi][ni], 0, 0, 0);
        __syncthreads();
    }

    #pragma unroll
    for (int mi = 0; mi < 4; ++mi) {
        int rbase = m0 + mi * 16 + lg * 4;
        #pragma unroll
        for (int v = 0; v < 4; ++v) {
            int gm = rbase + v;
            if (gm < M) {
                #pragma unroll
                for (int ni = 0; ni < 4; ++ni)
                    C[(size_t)gm * N + wid * 64 + ni * 16 + lr] = f2fp8(acc[mi][ni][v]);
            }
        }
    }
}

// ---------------- GEMM2 (LDS): h2_fp8[M,64] = fp8(relu(A_bf16[M,256]) @ W2T[64,256]^T) ----------------

__device__ inline uint relu_pk(uint u) {
    uint lo = u & 0x0000FFFFu;
    uint hi = u & 0xFFFF0000u;
    if (u & 0x00008000u) lo = 0;
    if (u & 0x80000000u) hi = 0;
    return lo | hi;
}

__global__ __launch_bounds__(256) void k_gemm2(const ushort* __restrict__ A,
                                               const ushort* __restrict__ BT,
                                               unsigned char* __restrict__ C,
                                               int M, int N, int K) {
    const int BM = 128, BK = 32;
    __shared__ ushort Al[BM][40];
    __shared__ ushort Bl[64][40];

    const int t    = threadIdx.x;
    const int lane = t & 63;
    const int wid  = t >> 6;
    const int wm   = wid >> 1, wn = wid & 1;
    const int m0   = blockIdx.x * BM;
    const int lr   = lane & 15;
    const int lg   = lane >> 4;

    f32x4 acc[4][2] = {};

    for (int k0 = 0; k0 < K; k0 += BK) {
        #pragma unroll
        for (int i = 0; i < 2; ++i) {
            int c = t + i * 256;
            int row = c >> 2, q = c & 3;
            int gm = m0 + row;
            uint4 v = make_uint4(0, 0, 0, 0);
            if (gm < M) v = *(const uint4*)(A + (size_t)gm * K + k0 + q * 8);
            v.x = relu_pk(v.x); v.y = relu_pk(v.y); v.z = relu_pk(v.z); v.w = relu_pk(v.w);
            *(uint4*)(&Al[row][q * 8]) = v;
        }
        {
            int row = t >> 2, q = t & 3;
            uint4 v = *(const uint4*)(BT + (size_t)(row) * K + k0 + q * 8);
            *(uint4*)(&Bl[row][q * 8]) = v;
        }
        __syncthreads();

        bf16x8 fa[4], fb[2];
        #pragma unroll
        for (int mi = 0; mi < 4; ++mi)
            fa[mi] = *(const bf16x8*)(&Al[wm * 64 + mi * 16 + lr][lg * 8]);
        #pragma unroll
        for (int ni = 0; ni < 2; ++ni)
            fb[ni] = *(const bf16x8*)(&Bl[wn * 32 + ni * 16 + lr][lg * 8]);
        #pragma unroll
        for (int mi = 0; mi < 4; ++mi)
            #pragma unroll
            for (int ni = 0; ni < 2; ++ni)
                acc[mi][ni] = __builtin_amdgcn_mfma_f32_16x16x32_bf16(fa[mi], fb[ni], acc[mi][ni], 0, 0, 0);
        __syncthreads();
    }

    #pragma unroll
    for (int mi = 0; mi < 4; ++mi) {
        int rbase = m0 + wm * 64 + mi * 16 + lg * 4;
        #pragma unroll
        for (int v = 0; v < 4; ++v) {
            int gm = rbase + v;
            if (gm < M) {
                #pragma unroll
                for (int ni = 0; ni < 2; ++ni)
                    C[(size_t)gm * N + wn * 32 + ni * 16 + lr] = f2fp8(acc[mi][ni][v]);
            }
        }
    }
}

// ---------------- gather aggregation (fp8 h1), one wave per dst node, 4-deep MLP ----------------

__global__ __launch_bounds__(256) void k_agg256(const unsigned char* __restrict__ h,
                                                const int2* __restrict__ csr_p,
                                                const int* __restrict__ off,
                                                const int* __restrict__ deg,
                                                const float* __restrict__ dis,
                                                const float* __restrict__ bias,
                                                ushort* __restrict__ out, int n) {
    int wave = (int)((blockIdx.x * (size_t)blockDim.x + threadIdx.x) >> 6);
    int lane = threadIdx.x & 63;
    if (wave >= n) return;
    const int i = wave;
    const float di = dis[i];
    const int beg = off[i], cnt = deg[i] - 1, end = beg + cnt;

    float4 bv = ((const float4*)bias)[lane];
    unsigned int hv = ((const unsigned int*)(h + (size_t)i * 256))[lane];
    float sl = di * di;
    float4 a0 = bv, a1 = {0,0,0,0}, a2 = {0,0,0,0}, a3 = {0,0,0,0};
    fp8x4_fma(hv, sl, a0);

    for (int base = beg; base < end; base += 64) {
        int m = end - base; if (m > 64) m = 64;
        int2 p = (lane < m) ? csr_p[base + lane] : make_int2(0, 0);
        int   msrc = p.x;
        float mw   = (lane < m) ? i2f(p.y) * di : 0.f;
        int k = 0;
        for (; k + 4 <= m; k += 4) {
            int s0 = __shfl(msrc, k),     s1 = __shfl(msrc, k + 1);
            int s2 = __shfl(msrc, k + 2), s3 = __shfl(msrc, k + 3);
            float w0 = __shfl(mw, k),     w1 = __shfl(mw, k + 1);
            float w2 = __shfl(mw, k + 2), w3 = __shfl(mw, k + 3);
            unsigned int v0 = ((const unsigned int*)(h + (size_t)s0 * 256))[lane];
            unsigned int v1 = ((const unsigned int*)(h + (size_t)s1 * 256))[lane];
            unsigned int v2 = ((const unsigned int*)(h + (size_t)s2 * 256))[lane];
            unsigned int v3 = ((const unsigned int*)(h + (size_t)s3 * 256))[lane];
            fp8x4_fma(v0, w0, a0);
            fp8x4_fma(v1, w1, a1);
            fp8x4_fma(v2, w2, a2);
            fp8x4_fma(v3, w3, a3);
        }
        for (; k < m; ++k) {
            int   s0 = __shfl(msrc, k); float w0 = __shfl(mw, k);
            unsigned int v0 = ((const unsigned int*)(h + (size_t)s0 * 256))[lane];
            fp8x4_fma(v0, w0, a0);
        }
    }
    ushort4 o;
    o.x = f2bf((a0.x + a1.x) + (a2.x + a3.x));
    o.y = f2bf((a0.y + a1.y) + (a2.y + a3.y));
    o.z = f2bf((a0.z + a1.z) + (a2.z + a3.z));
    o.w = f2bf((a0.w + a1.w) + (a2.w + a3.w));
    ((ushort4*)(out + (size_t)i * 256))[lane] = o;
}

// ---------------- agg64 (fp8 h2) fused with log-softmax: one wave per node; lane == class ----------------

__global__ __launch_bounds__(256) void k_agg64_lsm(const unsigned char* __restrict__ h,
                                                   const int2* __restrict__ csr_p,
                                                   const int* __restrict__ off,
                                                   const int* __restrict__ deg,
                                                   const float* __restrict__ dis,
                                                   const float* __restrict__ bias,
                                                   float* __restrict__ out, int n) {
    int wave = (int)((blockIdx.x * (size_t)blockDim.x + threadIdx.x) >> 6);
    int lane = threadIdx.x & 63;
    if (wave >= n) return;
    const int i = wave;
    const float di = dis[i];
    const int beg = off[i], cnt = deg[i] - 1, end = beg + cnt;

    float a0 = fmaf(fp8_dec1(h[(size_t)i * 64 + lane]), di * di, bias[lane]);
    float a1 = 0.f, a2 = 0.f, a3 = 0.f;

    for (int base = beg; base < end; base += 64) {
        int m = end - base; if (m > 64) m = 64;
        int2 p = (lane < m) ? csr_p[base + lane] : make_int2(0, 0);
        int   msrc = p.x;
        float mw   = (lane < m) ? i2f(p.y) * di : 0.f;
        int k = 0;
        for (; k + 4 <= m; k += 4) {
            int s0 = __shfl(msrc, k),     s1 = __shfl(msrc, k + 1);
            int s2 = __shfl(msrc, k + 2), s3 = __shfl(msrc, k + 3);
            float w0 = __shfl(mw, k),     w1 = __shfl(mw, k + 1);
            float w2 = __shfl(mw, k + 2), w3 = __shfl(mw, k + 3);
            a0 = fmaf(fp8_dec1(h[(size_t)s0 * 64 + lane]), w0, a0);
            a1 = fmaf(fp8_dec1(h[(size_t)s1 * 64 + lane]), w1, a1);
            a2 = fmaf(fp8_dec1(h[(size_t)s2 * 64 + lane]), w2, a2);
            a3 = fmaf(fp8_dec1(h[(size_t)s3 * 64 + lane]), w3, a3);
        }
        for (; k < m; ++k) {
            int s0 = __shfl(msrc, k); float w0 = __shfl(mw, k);
            a0 = fmaf(fp8_dec1(h[(size_t)s0 * 64 + lane]), w0, a0);
        }
    }
    float v = (a0 + a1) + (a2 + a3);

    float mx = v;
    #pragma unroll
    for (int o = 32; o > 0; o >>= 1) mx = fmaxf(mx, __shfl_xor(mx, o));
    float ex = __expf(v - mx);
    float ssum = ex;
    #pragma unroll
    for (int o = 32; o > 0; o >>= 1) ssum += __shfl_xor(ssum, o);
    out[(size_t)i * 64 + lane] = v - mx - logf(ssum);
}

// ---------------- launch ----------------

extern "C" void kernel_launch(void* const* d_in, const int* in_sizes, int n_in,
                              void* d_out, int out_size, void* d_ws, size_t ws_size,
                              hipStream_t stream) {
    const float* x  = (const float*)d_in[0];
    const int*   ei = (const int*)d_in[1];
    const float* W1 = (const float*)d_in[2];
    const float* b1 = (const float*)d_in[3];
    const float* W2 = (const float*)d_in[4];
    const float* b2 = (const float*)d_in[5];
    float* out = (float*)d_out;

    const int n = in_sizes[0] / 512;     // 100000
    const int E = in_sizes[1] / 2;       // 3200000
    const int* src = ei;
    const int* dst = ei + E;

    // workspace layout (bytes), 16B-aligned blocks
    char* ws = (char*)d_ws;
    int*    deg     = (int*)(ws + 0);               //    400,000
    int*    cursor  = (int*)(ws + 400000);          //    400,000
    float*  dis     = (float*)(ws + 800000);        //    400,000
    int*    offsets = (int*)(ws + 1200000);         //    400,000
    int*    partials= (int*)(ws + 1600000);         //        512
    int*    bhist   = (int*)(ws + 1600512);         //      1,024
    int*    bcur    = (int*)(ws + 1601536);         //      1,024
    int2*   csr_p   = (int2*)(ws + 1602560);        // 25,600,000 -> 27,202,560
    ushort* W1T     = (ushort*)(ws + 27202560);     //    262,144 -> 27,464,704
    ushort* W2T     = (ushort*)(ws + 27464704);     //     32,768 -> 27,497,472
    unsigned char* h1 = (unsigned char*)(ws + 27497472);  // 25,600,000 -> 53,097,472
    ushort* out1    = (ushort*)(ws + 53097472);     // 51,200,000 -> 104,297,472
    unsigned char* h2 = (unsigned char*)(ws + 104297472); //  6,400,000 -> 110,697,472
    int2*   sorted  = (int2*)(ws + 117097472);      // 25,600,000 -> 142,697,472

    const int SB = (n + 1023) / 1024;         // scan blocks
    const int PB = (E + 2047) / 2048;         // partition blocks (4x parallelism)
    const int SETUP_B = 577 + (n + 255) / 256;

    // 0. fused setup (weight transposes, bhist zero, deg init)
    k_setup<<<SETUP_B, 256, 0, stream>>>(W1, W1T, W2, W2T, bhist, deg, n);

    // 1. bucket partition of edges by dst>>9 (coalesced scatter)
    k_bhist<<<512, 256, 0, stream>>>(dst, E, bhist);
    k_bscan<<<1, 256, 0, stream>>>(bhist, bcur);
    k_partition<<<PB, 256, 0, stream>>>(src, dst, E, bcur, sorted);

    // 2. CSR build from bucket-sorted edges (deg atomics in hot window)
    k_count_sorted<<<(E + TB - 1) / TB, TB, 0, stream>>>(sorted, E, deg);
    k_scan_partial<<<SB, 256, 0, stream>>>(deg, partials, n);
    k_scan_tops<<<1, 128, 0, stream>>>(partials, SB);
    k_scan_final<<<SB, 256, 0, stream>>>(deg, partials, offsets, cursor, dis, n);
    k_fill_sorted<<<(E + TB - 1) / TB, TB, 0, stream>>>(sorted, E, cursor, dis, csr_p);

    // 3. h1 = fp8(x @ W1)
    k_gemm1<<<(n + 63) / 64, TB, 0, stream>>>(x, W1T, h1, n, 256, 512);

    // 4. out1 = b1 + Â h1  (fp8 gathers)
    k_agg256<<<(n + 3) / 4, TB, 0, stream>>>(h1, csr_p, offsets, deg, dis, b1, out1, n);

    // 5. h2 = fp8(relu(out1) @ W2)
    k_gemm2<<<(n + 127) / 128, TB, 0, stream>>>(out1, W2T, h2, n, 64, 256);

    // 6. out = b2 + Â h2, log-softmax fused (fp8 gathers, one 64B line per row)
    k_agg64_lsm<<<(n + 3) / 4, TB, 0, stream>>>(h2, csr_p, offsets, deg, dis, b2, out, n);
}

// Round 17
// 530.905 us; speedup vs baseline: 1.0612x; 1.0432x over previous
//
#include <hip/hip_runtime.h>
#include <hip/hip_bf16.h>
#include <math.h>

#define TB 256

typedef __attribute__((ext_vector_type(8))) short bf16x8;
typedef __attribute__((ext_vector_type(4))) float f32x4;
typedef __attribute__((ext_vector_type(2))) float f32x2;

__device__ inline float bf2f(ushort u) {
    union { uint u; float f; } c; c.u = ((uint)u) << 16; return c.f;
}
__device__ inline ushort f2bf(float f) {
    __hip_bfloat16 h = __float2bfloat16(f);
    union { __hip_bfloat16 h; ushort u; } c; c.h = h; return c.u;
}
__device__ inline float i2f(int i) { union { int i; float f; } c; c.i = i; return c.f; }
__device__ inline int f2i(float f) { union { float f; int i; } c; c.f = f; return c.i; }

// ---------------- fp8 e4m3 encode/decode (HW cvt preferred; manual fallback) ----------------

#if __has_builtin(__builtin_amdgcn_cvt_pk_fp8_f32) && __has_builtin(__builtin_amdgcn_cvt_pk_f32_fp8)
#define FP8_HW 1
#endif

__device__ inline unsigned char f2fp8(float v) {
#ifdef FP8_HW
    unsigned int r = __builtin_amdgcn_cvt_pk_fp8_f32(v, v, 0u, false);
    return (unsigned char)(r & 0xffu);
#else
    unsigned int s = (v < 0.f) ? 0x80u : 0u;
    float a = fabsf(v);
    if (a >= 448.f) return (unsigned char)(s | 0x7E);
    if (a < 0.015625f) {
        int m = (int)(a * 512.f + 0.5f);
        if (m >= 8) return (unsigned char)(s | 0x08);
        return (unsigned char)(s | m);
    }
    int e; float fr = frexpf(a, &e);
    int m = (int)(fr * 16.f + 0.5f) - 8;
    int E = e + 6;
    if (m == 8) { m = 0; E += 1; }
    if (E >= 16) return (unsigned char)(s | 0x7E);
    return (unsigned char)(s | (E << 3) | m);
#endif
}

#ifndef FP8_HW
__device__ inline float fp8_to_f(unsigned int b) {
    unsigned int s = (b & 0x80u) << 24;
    unsigned int e = (b >> 3) & 0xFu;
    unsigned int m = b & 7u;
    if (e == 0) { float val = (float)m * 0.001953125f; return s ? -val : val; }
    union { unsigned int u; float f; } c;
    c.u = s | ((e + 120u) << 23) | (m << 20);
    return c.f;
}
#endif

__device__ inline void fp8x4_fma(unsigned int v, float w, float4& acc) {
#ifdef FP8_HW
    f32x2 lo = __builtin_amdgcn_cvt_pk_f32_fp8(v, false);
    f32x2 hi = __builtin_amdgcn_cvt_pk_f32_fp8(v, true);
    acc.x = fmaf(lo.x, w, acc.x);
    acc.y = fmaf(lo.y, w, acc.y);
    acc.z = fmaf(hi.x, w, acc.z);
    acc.w = fmaf(hi.y, w, acc.w);
#else
    acc.x = fmaf(fp8_to_f(v & 0xff), w, acc.x);
    acc.y = fmaf(fp8_to_f((v >> 8) & 0xff), w, acc.y);
    acc.z = fmaf(fp8_to_f((v >> 16) & 0xff), w, acc.z);
    acc.w = fmaf(fp8_to_f(v >> 24), w, acc.w);
#endif
}

__device__ inline float fp8_dec1(unsigned int b) {
#ifdef FP8_HW
    f32x2 lo = __builtin_amdgcn_cvt_pk_f32_fp8(b & 0xffu, false);
    return lo.x;
#else
    return fp8_to_f(b & 0xffu);
#endif
}

// ---------------- fused setup: W1/W2 transpose+cast, bhist zero, deg init ----------------

__global__ __launch_bounds__(256) void k_setup(const float* __restrict__ W1, ushort* __restrict__ W1T,
                                               const float* __restrict__ W2, ushort* __restrict__ W2T,
                                               int* __restrict__ bhist, int* __restrict__ deg, int n) {
    int b = blockIdx.x;
    int t = threadIdx.x;
    if (b < 512) {
        int id = b * 256 + t;                 // K=512, N=256
        int k = id >> 8, nn = id & 255;
        W1T[(size_t)nn * 512 + k] = f2bf(W1[id]);
    } else if (b < 576) {
        int id = (b - 512) * 256 + t;         // K=256, N=64
        int k = id >> 6, nn = id & 63;
        W2T[(size_t)nn * 256 + k] = f2bf(W2[id]);
    } else if (b == 576) {
        bhist[t] = 0;
    } else {
        int i = (b - 577) * 256 + t;
        if (i < n) deg[i] = 1;
    }
}

// ---------------- bucket partition (256 buckets by dst>>9) ----------------

__global__ __launch_bounds__(256) void k_bhist(const int* __restrict__ dst, int E,
                                               int* __restrict__ hist) {
    __shared__ int lh[256];
    int t = threadIdx.x;
    lh[t] = 0;
    __syncthreads();
    for (int e = blockIdx.x * blockDim.x + t; e < E; e += gridDim.x * blockDim.x)
        atomicAdd(&lh[dst[e] >> 9], 1);
    __syncthreads();
    if (lh[t]) atomicAdd(&hist[t], lh[t]);
}

__global__ __launch_bounds__(256) void k_bscan(const int* __restrict__ hist,
                                               int* __restrict__ bcur) {
    __shared__ int sh[256];
    int t = threadIdx.x;
    int v = hist[t];
    sh[t] = v;
    __syncthreads();
    for (int off = 1; off < 256; off <<= 1) {
        int u = (t >= off) ? sh[t - off] : 0;
        __syncthreads();
        sh[t] += u;
        __syncthreads();
    }
    bcur[t] = sh[t] - v;   // exclusive
}

__global__ __launch_bounds__(256) void k_partition(const int* __restrict__ src,
                                                   const int* __restrict__ dst, int E,
                                                   int* __restrict__ bcur,
                                                   int2* __restrict__ sorted) {
    __shared__ int lh[256];
    const int per = 8192;
    int e0 = blockIdx.x * per;
    int e1 = min(E, e0 + per);
    int t = threadIdx.x;
    lh[t] = 0;
    __syncthreads();
    for (int e = e0 + t; e < e1; e += 256)
        atomicAdd(&lh[dst[e] >> 9], 1);
    __syncthreads();
    int cnt = lh[t];
    int base = cnt ? atomicAdd(&bcur[t], cnt) : 0;
    __syncthreads();
    lh[t] = base;
    __syncthreads();
    for (int e = e0 + t; e < e1; e += 256) {
        int d = dst[e], s = src[e];
        int pos = atomicAdd(&lh[d >> 9], 1);
        sorted[pos] = make_int2(s, d);
    }
}

// deg count on bucket-sorted edges: atomics land in a hot window
__global__ __launch_bounds__(256) void k_count_sorted(const int2* __restrict__ sorted, int E,
                                                      int* __restrict__ deg) {
    int e = blockIdx.x * blockDim.x + threadIdx.x;
    if (e < E) atomicAdd(&deg[sorted[e].y], 1);
}

// ---------------- hierarchical exclusive scan of (deg-1); also writes dis, cursor ----------------

__global__ __launch_bounds__(256) void k_scan_partial(const int* __restrict__ deg,
                                                      int* __restrict__ partials, int n) {
    __shared__ int red[256];
    int base = blockIdx.x * 1024;
    int t = threadIdx.x;
    int s = 0;
    #pragma unroll
    for (int j = 0; j < 4; ++j) {
        int i = base + t * 4 + j;
        if (i < n) s += deg[i] - 1;
    }
    red[t] = s;
    __syncthreads();
    for (int off = 128; off > 0; off >>= 1) {
        if (t < off) red[t] += red[t + off];
        __syncthreads();
    }
    if (t == 0) partials[blockIdx.x] = red[0];
}

__global__ __launch_bounds__(128) void k_scan_tops(int* __restrict__ partials, int B) {
    __shared__ int sh[128];
    int t = threadIdx.x;
    int v = (t < B) ? partials[t] : 0;
    sh[t] = v;
    __syncthreads();
    for (int off = 1; off < 128; off <<= 1) {
        int u = (t >= off) ? sh[t - off] : 0;
        __syncthreads();
        sh[t] += u;
        __syncthreads();
    }
    if (t < B) partials[t] = sh[t] - v;
}

__global__ __launch_bounds__(256) void k_scan_final(const int* __restrict__ deg,
                                                    const int* __restrict__ partials,
                                                    int* __restrict__ offsets,
                                                    int* __restrict__ cursor,
                                                    float* __restrict__ dis, int n) {
    __shared__ int sh[256];
    int base = blockIdx.x * 1024;
    int t = threadIdx.x;
    int c[4];
    int s = 0;
    #pragma unroll
    for (int j = 0; j < 4; ++j) {
        int i = base + t * 4 + j;
        c[j] = (i < n) ? deg[i] - 1 : 0;
        s += c[j];
    }
    sh[t] = s;
    __syncthreads();
    for (int off = 1; off < 256; off <<= 1) {
        int u = (t >= off) ? sh[t - off] : 0;
        __syncthreads();
        sh[t] += u;
        __syncthreads();
    }
    int run = partials[blockIdx.x] + sh[t] - s;
    #pragma unroll
    for (int j = 0; j < 4; ++j) {
        int i = base + t * 4 + j;
        if (i < n) {
            offsets[i] = run;
            cursor[i]  = run;
            dis[i] = rsqrtf((float)(c[j] + 1));
            run += c[j];
        }
    }
}

__global__ __launch_bounds__(256) void k_fill_sorted(const int2* __restrict__ sorted, int E,
                                                     int* cursor,
                                                     const float* __restrict__ dis,
                                                     int2* __restrict__ csr_p) {
    int e = blockIdx.x * blockDim.x + threadIdx.x;
    if (e >= E) return;
    int2 p = sorted[e];
    int pos = atomicAdd(&cursor[p.y], 1);
    csr_p[pos] = make_int2(p.x, f2i(dis[p.x]));
}

// ---------------- GEMM1 (LDS): h1_fp8[M,256] = fp8(bf16(A_fp32[M,512]) @ W1T[256,512]^T)

__global__ __launch_bounds__(256) void k_gemm1(const float* __restrict__ A,
                                               const ushort* __restrict__ BT,
                                               unsigned char* __restrict__ C,
                                               int M, int N, int K) {
    const int BM = 64, BK = 32;
    __shared__ ushort Al[BM][40];
    __shared__ ushort Bl[256][40];

    const int t    = threadIdx.x;
    const int lane = t & 63;
    const int wid  = t >> 6;
    const int m0   = blockIdx.x * BM;
    const int lr   = lane & 15;
    const int lg   = lane >> 4;

    f32x4 acc[4][4] = {};

    for (int k0 = 0; k0 < K; k0 += BK) {
        {
            int row = t >> 2, q = t & 3;
            int gm = m0 + row;
            ushort4 o0 = {0,0,0,0}, o1 = {0,0,0,0};
            if (gm < M) {
                const float* ap = A + (size_t)gm * K + k0 + q * 8;
                float4 u = *(const float4*)ap;
                float4 w = *(const float4*)(ap + 4);
                o0.x = f2bf(u.x); o0.y = f2bf(u.y); o0.z = f2bf(u.z); o0.w = f2bf(u.w);
                o1.x = f2bf(w.x); o1.y = f2bf(w.y); o1.z = f2bf(w.z); o1.w = f2bf(w.w);
            }
            *(ushort4*)(&Al[row][q * 8])     = o0;
            *(ushort4*)(&Al[row][q * 8 + 4]) = o1;
        }
        #pragma unroll
        for (int it = 0; it < 4; ++it) {
            int c = t + it * 256;
            int row = c >> 2, q = c & 3;
            uint4 v = *(const uint4*)(BT + (size_t)row * K + k0 + q * 8);
            *(uint4*)(&Bl[row][q * 8]) = v;
        }
        __syncthreads();

        bf16x8 fa[4], fb[4];
        #pragma unroll
        for (int mi = 0; mi < 4; ++mi)
            fa[mi] = *(const bf16x8*)(&Al[mi * 16 + lr][lg * 8]);
        #pragma unroll
        for (int ni = 0; ni < 4; ++ni)
            fb[ni] = *(const bf16x8*)(&Bl[wid * 64 + ni * 16 + lr][lg * 8]);
        #pragma unroll
        for (int mi = 0; mi < 4; ++mi)
            #pragma unroll
            for (int ni = 0; ni < 4; ++ni)
                acc[mi][ni] = __builtin_amdgcn_mfma_f32_16x16x32_bf16(fa[mi], fb[ni], acc[mi][ni], 0, 0, 0);
        __syncthreads();
    }

    #pragma unroll
    for (int mi = 0; mi < 4; ++mi) {
        int rbase = m0 + mi * 16 + lg * 4;
        #pragma unroll
        for (int v = 0; v < 4; ++v) {
            int gm = rbase + v;
            if (gm < M) {
                #pragma unroll
                for (int ni = 0; ni < 4; ++ni)
                    C[(size_t)gm * N + wid * 64 + ni * 16 + lr] = f2fp8(acc[mi][ni][v]);
            }
        }
    }
}

// ---------------- GEMM2 (LDS): h2_fp8[M,64] = fp8(relu(A_bf16[M,256]) @ W2T[64,256]^T) ----------------

__device__ inline uint relu_pk(uint u) {
    uint lo = u & 0x0000FFFFu;
    uint hi = u & 0xFFFF0000u;
    if (u & 0x00008000u) lo = 0;
    if (u & 0x80000000u) hi = 0;
    return lo | hi;
}

__global__ __launch_bounds__(256) void k_gemm2(const ushort* __restrict__ A,
                                               const ushort* __restrict__ BT,
                                               unsigned char* __restrict__ C,
                                               int M, int N, int K) {
    const int BM = 128, BK = 32;
    __shared__ ushort Al[BM][40];
    __shared__ ushort Bl[64][40];

    const int t    = threadIdx.x;
    const int lane = t & 63;
    const int wid  = t >> 6;
    const int wm   = wid >> 1, wn = wid & 1;
    const int m0   = blockIdx.x * BM;
    const int lr   = lane & 15;
    const int lg   = lane >> 4;

    f32x4 acc[4][2] = {};

    for (int k0 = 0; k0 < K; k0 += BK) {
        #pragma unroll
        for (int i = 0; i < 2; ++i) {
            int c = t + i * 256;
            int row = c >> 2, q = c & 3;
            int gm = m0 + row;
            uint4 v = make_uint4(0, 0, 0, 0);
            if (gm < M) v = *(const uint4*)(A + (size_t)gm * K + k0 + q * 8);
            v.x = relu_pk(v.x); v.y = relu_pk(v.y); v.z = relu_pk(v.z); v.w = relu_pk(v.w);
            *(uint4*)(&Al[row][q * 8]) = v;
        }
        {
            int row = t >> 2, q = t & 3;
            uint4 v = *(const uint4*)(BT + (size_t)(row) * K + k0 + q * 8);
            *(uint4*)(&Bl[row][q * 8]) = v;
        }
        __syncthreads();

        bf16x8 fa[4], fb[2];
        #pragma unroll
        for (int mi = 0; mi < 4; ++mi)
            fa[mi] = *(const bf16x8*)(&Al[wm * 64 + mi * 16 + lr][lg * 8]);
        #pragma unroll
        for (int ni = 0; ni < 2; ++ni)
            fb[ni] = *(const bf16x8*)(&Bl[wn * 32 + ni * 16 + lr][lg * 8]);
        #pragma unroll
        for (int mi = 0; mi < 4; ++mi)
            #pragma unroll
            for (int ni = 0; ni < 2; ++ni)
                acc[mi][ni] = __builtin_amdgcn_mfma_f32_16x16x32_bf16(fa[mi], fb[ni], acc[mi][ni], 0, 0, 0);
        __syncthreads();
    }

    #pragma unroll
    for (int mi = 0; mi < 4; ++mi) {
        int rbase = m0 + wm * 64 + mi * 16 + lg * 4;
        #pragma unroll
        for (int v = 0; v < 4; ++v) {
            int gm = rbase + v;
            if (gm < M) {
                #pragma unroll
                for (int ni = 0; ni < 2; ++ni)
                    C[(size_t)gm * N + wn * 32 + ni * 16 + lr] = f2fp8(acc[mi][ni][v]);
            }
        }
    }
}

// ---------------- gather aggregation (fp8 h1), one wave per dst node, 4-deep MLP ----------------

__global__ __launch_bounds__(256) void k_agg256(const unsigned char* __restrict__ h,
                                                const int2* __restrict__ csr_p,
                                                const int* __restrict__ off,
                                                const int* __restrict__ deg,
                                                const float* __restrict__ dis,
                                                const float* __restrict__ bias,
                                                ushort* __restrict__ out, int n) {
    int wave = (int)((blockIdx.x * (size_t)blockDim.x + threadIdx.x) >> 6);
    int lane = threadIdx.x & 63;
    if (wave >= n) return;
    const int i = wave;
    const float di = dis[i];
    const int beg = off[i], cnt = deg[i] - 1, end = beg + cnt;

    float4 bv = ((const float4*)bias)[lane];
    unsigned int hv = ((const unsigned int*)(h + (size_t)i * 256))[lane];
    float sl = di * di;
    float4 a0 = bv, a1 = {0,0,0,0}, a2 = {0,0,0,0}, a3 = {0,0,0,0};
    fp8x4_fma(hv, sl, a0);

    for (int base = beg; base < end; base += 64) {
        int m = end - base; if (m > 64) m = 64;
        int2 p = (lane < m) ? csr_p[base + lane] : make_int2(0, 0);
        int   msrc = p.x;
        float mw   = (lane < m) ? i2f(p.y) * di : 0.f;
        int k = 0;
        for (; k + 4 <= m; k += 4) {
            int s0 = __shfl(msrc, k),     s1 = __shfl(msrc, k + 1);
            int s2 = __shfl(msrc, k + 2), s3 = __shfl(msrc, k + 3);
            float w0 = __shfl(mw, k),     w1 = __shfl(mw, k + 1);
            float w2 = __shfl(mw, k + 2), w3 = __shfl(mw, k + 3);
            unsigned int v0 = ((const unsigned int*)(h + (size_t)s0 * 256))[lane];
            unsigned int v1 = ((const unsigned int*)(h + (size_t)s1 * 256))[lane];
            unsigned int v2 = ((const unsigned int*)(h + (size_t)s2 * 256))[lane];
            unsigned int v3 = ((const unsigned int*)(h + (size_t)s3 * 256))[lane];
            fp8x4_fma(v0, w0, a0);
            fp8x4_fma(v1, w1, a1);
            fp8x4_fma(v2, w2, a2);
            fp8x4_fma(v3, w3, a3);
        }
        for (; k < m; ++k) {
            int   s0 = __shfl(msrc, k); float w0 = __shfl(mw, k);
            unsigned int v0 = ((const unsigned int*)(h + (size_t)s0 * 256))[lane];
            fp8x4_fma(v0, w0, a0);
        }
    }
    ushort4 o;
    o.x = f2bf((a0.x + a1.x) + (a2.x + a3.x));
    o.y = f2bf((a0.y + a1.y) + (a2.y + a3.y));
    o.z = f2bf((a0.z + a1.z) + (a2.z + a3.z));
    o.w = f2bf((a0.w + a1.w) + (a2.w + a3.w));
    ((ushort4*)(out + (size_t)i * 256))[lane] = o;
}

// ---------------- agg64 (fp8 h2) fused with log-softmax: one wave per node; lane == class ----------------

__global__ __launch_bounds__(256) void k_agg64_lsm(const unsigned char* __restrict__ h,
                                                   const int2* __restrict__ csr_p,
                                                   const int* __restrict__ off,
                                                   const int* __restrict__ deg,
                                                   const float* __restrict__ dis,
                                                   const float* __restrict__ bias,
                                                   float* __restrict__ out, int n) {
    int wave = (int)((blockIdx.x * (size_t)blockDim.x + threadIdx.x) >> 6);
    int lane = threadIdx.x & 63;
    if (wave >= n) return;
    const int i = wave;
    const float di = dis[i];
    const int beg = off[i], cnt = deg[i] - 1, end = beg + cnt;

    float a0 = fmaf(fp8_dec1(h[(size_t)i * 64 + lane]), di * di, bias[lane]);
    float a1 = 0.f, a2 = 0.f, a3 = 0.f;

    for (int base = beg; base < end; base += 64) {
        int m = end - base; if (m > 64) m = 64;
        int2 p = (lane < m) ? csr_p[base + lane] : make_int2(0, 0);
        int   msrc = p.x;
        float mw   = (lane < m) ? i2f(p.y) * di : 0.f;
        int k = 0;
        for (; k + 4 <= m; k += 4) {
            int s0 = __shfl(msrc, k),     s1 = __shfl(msrc, k + 1);
            int s2 = __shfl(msrc, k + 2), s3 = __shfl(msrc, k + 3);
            float w0 = __shfl(mw, k),     w1 = __shfl(mw, k + 1);
            float w2 = __shfl(mw, k + 2), w3 = __shfl(mw, k + 3);
            a0 = fmaf(fp8_dec1(h[(size_t)s0 * 64 + lane]), w0, a0);
            a1 = fmaf(fp8_dec1(h[(size_t)s1 * 64 + lane]), w1, a1);
            a2 = fmaf(fp8_dec1(h[(size_t)s2 * 64 + lane]), w2, a2);
            a3 = fmaf(fp8_dec1(h[(size_t)s3 * 64 + lane]), w3, a3);
        }
        for (; k < m; ++k) {
            int s0 = __shfl(msrc, k); float w0 = __shfl(mw, k);
            a0 = fmaf(fp8_dec1(h[(size_t)s0 * 64 + lane]), w0, a0);
        }
    }
    float v = (a0 + a1) + (a2 + a3);

    float mx = v;
    #pragma unroll
    for (int o = 32; o > 0; o >>= 1) mx = fmaxf(mx, __shfl_xor(mx, o));
    float ex = __expf(v - mx);
    float ssum = ex;
    #pragma unroll
    for (int o = 32; o > 0; o >>= 1) ssum += __shfl_xor(ssum, o);
    out[(size_t)i * 64 + lane] = v - mx - logf(ssum);
}

// ---------------- launch ----------------

extern "C" void kernel_launch(void* const* d_in, const int* in_sizes, int n_in,
                              void* d_out, int out_size, void* d_ws, size_t ws_size,
                              hipStream_t stream) {
    const float* x  = (const float*)d_in[0];
    const int*   ei = (const int*)d_in[1];
    const float* W1 = (const float*)d_in[2];
    const float* b1 = (const float*)d_in[3];
    const float* W2 = (const float*)d_in[4];
    const float* b2 = (const float*)d_in[5];
    float* out = (float*)d_out;

    const int n = in_sizes[0] / 512;     // 100000
    const int E = in_sizes[1] / 2;       // 3200000
    const int* src = ei;
    const int* dst = ei + E;

    // workspace layout (bytes), 16B-aligned blocks
    char* ws = (char*)d_ws;
    int*    deg     = (int*)(ws + 0);               //    400,000
    int*    cursor  = (int*)(ws + 400000);          //    400,000
    float*  dis     = (float*)(ws + 800000);        //    400,000
    int*    offsets = (int*)(ws + 1200000);         //    400,000
    int*    partials= (int*)(ws + 1600000);         //        512
    int*    bhist   = (int*)(ws + 1600512);         //      1,024
    int*    bcur    = (int*)(ws + 1601536);         //      1,024
    int2*   csr_p   = (int2*)(ws + 1602560);        // 25,600,000 -> 27,202,560
    ushort* W1T     = (ushort*)(ws + 27202560);     //    262,144 -> 27,464,704
    ushort* W2T     = (ushort*)(ws + 27464704);     //     32,768 -> 27,497,472
    unsigned char* h1 = (unsigned char*)(ws + 27497472);  // 25,600,000 -> 53,097,472
    ushort* out1    = (ushort*)(ws + 53097472);     // 51,200,000 -> 104,297,472
    unsigned char* h2 = (unsigned char*)(ws + 104297472); //  6,400,000 -> 110,697,472
    int2*   sorted  = (int2*)(ws + 117097472);      // 25,600,000 -> 142,697,472

    const int SB = (n + 1023) / 1024;         // scan blocks
    const int PB = (E + 8191) / 8192;         // partition blocks
    const int SETUP_B = 577 + (n + 255) / 256;

    // 0. fused setup (weight transposes, bhist zero, deg init)
    k_setup<<<SETUP_B, 256, 0, stream>>>(W1, W1T, W2, W2T, bhist, deg, n);

    // 1. bucket partition of edges by dst>>9 (coalesced scatter)
    k_bhist<<<512, 256, 0, stream>>>(dst, E, bhist);
    k_bscan<<<1, 256, 0, stream>>>(bhist, bcur);
    k_partition<<<PB, 256, 0, stream>>>(src, dst, E, bcur, sorted);

    // 2. CSR build from bucket-sorted edges (deg atomics in hot window)
    k_count_sorted<<<(E + TB - 1) / TB, TB, 0, stream>>>(sorted, E, deg);
    k_scan_partial<<<SB, 256, 0, stream>>>(deg, partials, n);
    k_scan_tops<<<1, 128, 0, stream>>>(partials, SB);
    k_scan_final<<<SB, 256, 0, stream>>>(deg, partials, offsets, cursor, dis, n);
    k_fill_sorted<<<(E + TB - 1) / TB, TB, 0, stream>>>(sorted, E, cursor, dis, csr_p);

    // 3. h1 = fp8(x @ W1)
    k_gemm1<<<(n + 63) / 64, TB, 0, stream>>>(x, W1T, h1, n, 256, 512);

    // 4. out1 = b1 + Â h1  (fp8 gathers)
    k_agg256<<<(n + 3) / 4, TB, 0, stream>>>(h1, csr_p, offsets, deg, dis, b1, out1, n);

    // 5. h2 = fp8(relu(out1) @ W2)
    k_gemm2<<<(n + 127) / 128, TB, 0, stream>>>(out1, W2T, h2, n, 64, 256);

    // 6. out = b2 + Â h2, log-softmax fused (fp8 gathers, one 64B line per row)
    k_agg64_lsm<<<(n + 3) / 4, TB, 0, stream>>>(h2, csr_p, offsets, deg, dis, b2, out, n);
}

// Round 18
// 529.545 us; speedup vs baseline: 1.0640x; 1.0026x over previous
//
#include <hip/hip_runtime.h>
#include <hip/hip_bf16.h>
#include <math.h>

#define TB 256

typedef __attribute__((ext_vector_type(8))) short bf16x8;
typedef __attribute__((ext_vector_type(4))) float f32x4;
typedef __attribute__((ext_vector_type(2))) float f32x2;

__device__ inline float bf2f(ushort u) {
    union { uint u; float f; } c; c.u = ((uint)u) << 16; return c.f;
}
__device__ inline ushort f2bf(float f) {
    __hip_bfloat16 h = __float2bfloat16(f);
    union { __hip_bfloat16 h; ushort u; } c; c.h = h; return c.u;
}
__device__ inline float i2f(int i) { union { int i; float f; } c; c.i = i; return c.f; }
__device__ inline int f2i(float f) { union { float f; int i; } c; c.f = f; return c.i; }

// ---------------- fp8 e4m3 encode/decode (HW cvt preferred; manual fallback) ----------------

#if __has_builtin(__builtin_amdgcn_cvt_pk_fp8_f32) && __has_builtin(__builtin_amdgcn_cvt_pk_f32_fp8)
#define FP8_HW 1
#endif

__device__ inline unsigned char f2fp8(float v) {
#ifdef FP8_HW
    unsigned int r = __builtin_amdgcn_cvt_pk_fp8_f32(v, v, 0u, false);
    return (unsigned char)(r & 0xffu);
#else
    unsigned int s = (v < 0.f) ? 0x80u : 0u;
    float a = fabsf(v);
    if (a >= 448.f) return (unsigned char)(s | 0x7E);
    if (a < 0.015625f) {
        int m = (int)(a * 512.f + 0.5f);
        if (m >= 8) return (unsigned char)(s | 0x08);
        return (unsigned char)(s | m);
    }
    int e; float fr = frexpf(a, &e);
    int m = (int)(fr * 16.f + 0.5f) - 8;
    int E = e + 6;
    if (m == 8) { m = 0; E += 1; }
    if (E >= 16) return (unsigned char)(s | 0x7E);
    return (unsigned char)(s | (E << 3) | m);
#endif
}

#ifndef FP8_HW
__device__ inline float fp8_to_f(unsigned int b) {
    unsigned int s = (b & 0x80u) << 24;
    unsigned int e = (b >> 3) & 0xFu;
    unsigned int m = b & 7u;
    if (e == 0) { float val = (float)m * 0.001953125f; return s ? -val : val; }
    union { unsigned int u; float f; } c;
    c.u = s | ((e + 120u) << 23) | (m << 20);
    return c.f;
}
#endif

__device__ inline void fp8x4_fma(unsigned int v, float w, float4& acc) {
#ifdef FP8_HW
    f32x2 lo = __builtin_amdgcn_cvt_pk_f32_fp8(v, false);
    f32x2 hi = __builtin_amdgcn_cvt_pk_f32_fp8(v, true);
    acc.x = fmaf(lo.x, w, acc.x);
    acc.y = fmaf(lo.y, w, acc.y);
    acc.z = fmaf(hi.x, w, acc.z);
    acc.w = fmaf(hi.y, w, acc.w);
#else
    acc.x = fmaf(fp8_to_f(v & 0xff), w, acc.x);
    acc.y = fmaf(fp8_to_f((v >> 8) & 0xff), w, acc.y);
    acc.z = fmaf(fp8_to_f((v >> 16) & 0xff), w, acc.z);
    acc.w = fmaf(fp8_to_f(v >> 24), w, acc.w);
#endif
}

__device__ inline float fp8_dec1(unsigned int b) {
#ifdef FP8_HW
    f32x2 lo = __builtin_amdgcn_cvt_pk_f32_fp8(b & 0xffu, false);
    return lo.x;
#else
    return fp8_to_f(b & 0xffu);
#endif
}

// ---------------- fused setup: W1/W2 transpose+cast, bhist zero, deg init ----------------

__global__ __launch_bounds__(256) void k_setup(const float* __restrict__ W1, ushort* __restrict__ W1T,
                                               const float* __restrict__ W2, ushort* __restrict__ W2T,
                                               int* __restrict__ bhist, int* __restrict__ deg, int n) {
    int b = blockIdx.x;
    int t = threadIdx.x;
    if (b < 512) {
        int id = b * 256 + t;                 // K=512, N=256
        int k = id >> 8, nn = id & 255;
        W1T[(size_t)nn * 512 + k] = f2bf(W1[id]);
    } else if (b < 576) {
        int id = (b - 512) * 256 + t;         // K=256, N=64
        int k = id >> 6, nn = id & 63;
        W2T[(size_t)nn * 256 + k] = f2bf(W2[id]);
    } else if (b == 576) {
        bhist[t] = 0;
    } else {
        int i = (b - 577) * 256 + t;
        if (i < n) deg[i] = 1;
    }
}

// ---------------- bucket partition (256 buckets by dst>>9) ----------------

__global__ __launch_bounds__(256) void k_bhist(const int* __restrict__ dst, int E,
                                               int* __restrict__ hist) {
    __shared__ int lh[256];
    int t = threadIdx.x;
    lh[t] = 0;
    __syncthreads();
    for (int e = blockIdx.x * blockDim.x + t; e < E; e += gridDim.x * blockDim.x)
        atomicAdd(&lh[dst[e] >> 9], 1);
    __syncthreads();
    if (lh[t]) atomicAdd(&hist[t], lh[t]);
}

__global__ __launch_bounds__(256) void k_bscan(const int* __restrict__ hist,
                                               int* __restrict__ bcur) {
    __shared__ int sh[256];
    int t = threadIdx.x;
    int v = hist[t];
    sh[t] = v;
    __syncthreads();
    for (int off = 1; off < 256; off <<= 1) {
        int u = (t >= off) ? sh[t - off] : 0;
        __syncthreads();
        sh[t] += u;
        __syncthreads();
    }
    bcur[t] = sh[t] - v;   // exclusive
}

__global__ __launch_bounds__(256) void k_partition(const int* __restrict__ src,
                                                   const int* __restrict__ dst, int E,
                                                   int* __restrict__ bcur,
                                                   int2* __restrict__ sorted) {
    __shared__ int lh[256];
    const int per = 8192;
    int e0 = blockIdx.x * per;
    int e1 = min(E, e0 + per);
    int t = threadIdx.x;
    lh[t] = 0;
    __syncthreads();
    for (int e = e0 + t; e < e1; e += 256)
        atomicAdd(&lh[dst[e] >> 9], 1);
    __syncthreads();
    int cnt = lh[t];
    int base = cnt ? atomicAdd(&bcur[t], cnt) : 0;
    __syncthreads();
    lh[t] = base;
    __syncthreads();
    for (int e = e0 + t; e < e1; e += 256) {
        int d = dst[e], s = src[e];
        int pos = atomicAdd(&lh[d >> 9], 1);
        sorted[pos] = make_int2(s, d);
    }
}

// deg count on bucket-sorted edges: atomics land in a hot window
__global__ __launch_bounds__(256) void k_count_sorted(const int2* __restrict__ sorted, int E,
                                                      int* __restrict__ deg) {
    int e = blockIdx.x * blockDim.x + threadIdx.x;
    if (e < E) atomicAdd(&deg[sorted[e].y], 1);
}

// ---------------- hierarchical exclusive scan of (deg-1); also writes dis, cursor ----------------

__global__ __launch_bounds__(256) void k_scan_partial(const int* __restrict__ deg,
                                                      int* __restrict__ partials, int n) {
    __shared__ int red[256];
    int base = blockIdx.x * 1024;
    int t = threadIdx.x;
    int s = 0;
    #pragma unroll
    for (int j = 0; j < 4; ++j) {
        int i = base + t * 4 + j;
        if (i < n) s += deg[i] - 1;
    }
    red[t] = s;
    __syncthreads();
    for (int off = 128; off > 0; off >>= 1) {
        if (t < off) red[t] += red[t + off];
        __syncthreads();
    }
    if (t == 0) partials[blockIdx.x] = red[0];
}

__global__ __launch_bounds__(128) void k_scan_tops(int* __restrict__ partials, int B) {
    __shared__ int sh[128];
    int t = threadIdx.x;
    int v = (t < B) ? partials[t] : 0;
    sh[t] = v;
    __syncthreads();
    for (int off = 1; off < 128; off <<= 1) {
        int u = (t >= off) ? sh[t - off] : 0;
        __syncthreads();
        sh[t] += u;
        __syncthreads();
    }
    if (t < B) partials[t] = sh[t] - v;
}

__global__ __launch_bounds__(256) void k_scan_final(const int* __restrict__ deg,
                                                    const int* __restrict__ partials,
                                                    int* __restrict__ offsets,
                                                    int* __restrict__ cursor,
                                                    float* __restrict__ dis, int n) {
    __shared__ int sh[256];
    int base = blockIdx.x * 1024;
    int t = threadIdx.x;
    int c[4];
    int s = 0;
    #pragma unroll
    for (int j = 0; j < 4; ++j) {
        int i = base + t * 4 + j;
        c[j] = (i < n) ? deg[i] - 1 : 0;
        s += c[j];
    }
    sh[t] = s;
    __syncthreads();
    for (int off = 1; off < 256; off <<= 1) {
        int u = (t >= off) ? sh[t - off] : 0;
        __syncthreads();
        sh[t] += u;
        __syncthreads();
    }
    int run = partials[blockIdx.x] + sh[t] - s;
    #pragma unroll
    for (int j = 0; j < 4; ++j) {
        int i = base + t * 4 + j;
        if (i < n) {
            offsets[i] = run;
            cursor[i]  = run;
            dis[i] = rsqrtf((float)(c[j] + 1));
            run += c[j];
        }
    }
}

__global__ __launch_bounds__(256) void k_fill_sorted(const int2* __restrict__ sorted, int E,
                                                     int* cursor,
                                                     const float* __restrict__ dis,
                                                     int2* __restrict__ csr_p) {
    int e = blockIdx.x * blockDim.x + threadIdx.x;
    if (e >= E) return;
    int2 p = sorted[e];
    int pos = atomicAdd(&cursor[p.y], 1);
    csr_p[pos] = make_int2(p.x, f2i(dis[p.x]));
}

// ---------------- GEMM1 (LDS double-buffered): h1_fp8[M,256] = fp8(bf16(A[M,512]) @ W1T^T)
// One barrier per K-step: stage tile k+1 into buf^1 while computing tile k from buf.

__global__ __launch_bounds__(256) void k_gemm1(const float* __restrict__ A,
                                               const ushort* __restrict__ BT,
                                               unsigned char* __restrict__ C,
                                               int M, int N, int K) {
    const int BM = 64, BK = 32;
    __shared__ ushort Al[2][BM][40];
    __shared__ ushort Bl[2][256][40];

    const int t    = threadIdx.x;
    const int lane = t & 63;
    const int wid  = t >> 6;
    const int m0   = blockIdx.x * BM;
    const int lr   = lane & 15;
    const int lg   = lane >> 4;

    const int arow = t >> 2, aq = t & 3;
    const int agm  = min(m0 + arow, M - 1);
    const bool avalid = (m0 + arow) < M;

    f32x4 acc[4][4] = {};

    // stage tile 0 into buf 0
    {
        ushort4 o0 = {0,0,0,0}, o1 = {0,0,0,0};
        if (avalid) {
            const float* ap = A + (size_t)agm * K + aq * 8;
            float4 u = *(const float4*)ap;
            float4 w = *(const float4*)(ap + 4);
            o0.x = f2bf(u.x); o0.y = f2bf(u.y); o0.z = f2bf(u.z); o0.w = f2bf(u.w);
            o1.x = f2bf(w.x); o1.y = f2bf(w.y); o1.z = f2bf(w.z); o1.w = f2bf(w.w);
        }
        *(ushort4*)(&Al[0][arow][aq * 8])     = o0;
        *(ushort4*)(&Al[0][arow][aq * 8 + 4]) = o1;
        #pragma unroll
        for (int it = 0; it < 4; ++it) {
            int c = t + it * 256;
            int row = c >> 2, q = c & 3;
            uint4 v = *(const uint4*)(BT + (size_t)row * K + q * 8);
            *(uint4*)(&Bl[0][row][q * 8]) = v;
        }
    }
    __syncthreads();

    int buf = 0;
    for (int k0 = 0; k0 < K; k0 += BK) {
        // stage next tile into buf^1 (issues global loads early, overlaps MFMA)
        if (k0 + BK < K) {
            int nb = buf ^ 1;
            int kn = k0 + BK;
            ushort4 o0 = {0,0,0,0}, o1 = {0,0,0,0};
            if (avalid) {
                const float* ap = A + (size_t)agm * K + kn + aq * 8;
                float4 u = *(const float4*)ap;
                float4 w = *(const float4*)(ap + 4);
                o0.x = f2bf(u.x); o0.y = f2bf(u.y); o0.z = f2bf(u.z); o0.w = f2bf(u.w);
                o1.x = f2bf(w.x); o1.y = f2bf(w.y); o1.z = f2bf(w.z); o1.w = f2bf(w.w);
            }
            *(ushort4*)(&Al[nb][arow][aq * 8])     = o0;
            *(ushort4*)(&Al[nb][arow][aq * 8 + 4]) = o1;
            #pragma unroll
            for (int it = 0; it < 4; ++it) {
                int c = t + it * 256;
                int row = c >> 2, q = c & 3;
                uint4 v = *(const uint4*)(BT + (size_t)row * K + kn + q * 8);
                *(uint4*)(&Bl[nb][row][q * 8]) = v;
            }
        }

        bf16x8 fa[4], fb[4];
        #pragma unroll
        for (int mi = 0; mi < 4; ++mi)
            fa[mi] = *(const bf16x8*)(&Al[buf][mi * 16 + lr][lg * 8]);
        #pragma unroll
        for (int ni = 0; ni < 4; ++ni)
            fb[ni] = *(const bf16x8*)(&Bl[buf][wid * 64 + ni * 16 + lr][lg * 8]);
        #pragma unroll
        for (int mi = 0; mi < 4; ++mi)
            #pragma unroll
            for (int ni = 0; ni < 4; ++ni)
                acc[mi][ni] = __builtin_amdgcn_mfma_f32_16x16x32_bf16(fa[mi], fb[ni], acc[mi][ni], 0, 0, 0);
        __syncthreads();
        buf ^= 1;
    }

    #pragma unroll
    for (int mi = 0; mi < 4; ++mi) {
        int rbase = m0 + mi * 16 + lg * 4;
        #pragma unroll
        for (int v = 0; v < 4; ++v) {
            int gm = rbase + v;
            if (gm < M) {
                #pragma unroll
                for (int ni = 0; ni < 4; ++ni)
                    C[(size_t)gm * N + wid * 64 + ni * 16 + lr] = f2fp8(acc[mi][ni][v]);
            }
        }
    }
}

// ---------------- GEMM2 (LDS): h2_fp8[M,64] = fp8(relu(A_bf16[M,256]) @ W2T[64,256]^T) ----------------

__device__ inline uint relu_pk(uint u) {
    uint lo = u & 0x0000FFFFu;
    uint hi = u & 0xFFFF0000u;
    if (u & 0x00008000u) lo = 0;
    if (u & 0x80000000u) hi = 0;
    return lo | hi;
}

__global__ __launch_bounds__(256) void k_gemm2(const ushort* __restrict__ A,
                                               const ushort* __restrict__ BT,
                                               unsigned char* __restrict__ C,
                                               int M, int N, int K) {
    const int BM = 128, BK = 32;
    __shared__ ushort Al[BM][40];
    __shared__ ushort Bl[64][40];

    const int t    = threadIdx.x;
    const int lane = t & 63;
    const int wid  = t >> 6;
    const int wm   = wid >> 1, wn = wid & 1;
    const int m0   = blockIdx.x * BM;
    const int lr   = lane & 15;
    const int lg   = lane >> 4;

    f32x4 acc[4][2] = {};

    for (int k0 = 0; k0 < K; k0 += BK) {
        #pragma unroll
        for (int i = 0; i < 2; ++i) {
            int c = t + i * 256;
            int row = c >> 2, q = c & 3;
            int gm = m0 + row;
            uint4 v = make_uint4(0, 0, 0, 0);
            if (gm < M) v = *(const uint4*)(A + (size_t)gm * K + k0 + q * 8);
            v.x = relu_pk(v.x); v.y = relu_pk(v.y); v.z = relu_pk(v.z); v.w = relu_pk(v.w);
            *(uint4*)(&Al[row][q * 8]) = v;
        }
        {
            int row = t >> 2, q = t & 3;
            uint4 v = *(const uint4*)(BT + (size_t)(row) * K + k0 + q * 8);
            *(uint4*)(&Bl[row][q * 8]) = v;
        }
        __syncthreads();

        bf16x8 fa[4], fb[2];
        #pragma unroll
        for (int mi = 0; mi < 4; ++mi)
            fa[mi] = *(const bf16x8*)(&Al[wm * 64 + mi * 16 + lr][lg * 8]);
        #pragma unroll
        for (int ni = 0; ni < 2; ++ni)
            fb[ni] = *(const bf16x8*)(&Bl[wn * 32 + ni * 16 + lr][lg * 8]);
        #pragma unroll
        for (int mi = 0; mi < 4; ++mi)
            #pragma unroll
            for (int ni = 0; ni < 2; ++ni)
                acc[mi][ni] = __builtin_amdgcn_mfma_f32_16x16x32_bf16(fa[mi], fb[ni], acc[mi][ni], 0, 0, 0);
        __syncthreads();
    }

    #pragma unroll
    for (int mi = 0; mi < 4; ++mi) {
        int rbase = m0 + wm * 64 + mi * 16 + lg * 4;
        #pragma unroll
        for (int v = 0; v < 4; ++v) {
            int gm = rbase + v;
            if (gm < M) {
                #pragma unroll
                for (int ni = 0; ni < 2; ++ni)
                    C[(size_t)gm * N + wn * 32 + ni * 16 + lr] = f2fp8(acc[mi][ni][v]);
            }
        }
    }
}

// ---------------- gather aggregation (fp8 h1), one wave per dst node, 4-deep MLP ----------------

__global__ __launch_bounds__(256) void k_agg256(const unsigned char* __restrict__ h,
                                                const int2* __restrict__ csr_p,
                                                const int* __restrict__ off,
                                                const int* __restrict__ deg,
                                                const float* __restrict__ dis,
                                                const float* __restrict__ bias,
                                                ushort* __restrict__ out, int n) {
    int wave = (int)((blockIdx.x * (size_t)blockDim.x + threadIdx.x) >> 6);
    int lane = threadIdx.x & 63;
    if (wave >= n) return;
    const int i = wave;
    const float di = dis[i];
    const int beg = off[i], cnt = deg[i] - 1, end = beg + cnt;

    float4 bv = ((const float4*)bias)[lane];
    unsigned int hv = ((const unsigned int*)(h + (size_t)i * 256))[lane];
    float sl = di * di;
    float4 a0 = bv, a1 = {0,0,0,0}, a2 = {0,0,0,0}, a3 = {0,0,0,0};
    fp8x4_fma(hv, sl, a0);

    for (int base = beg; base < end; base += 64) {
        int m = end - base; if (m > 64) m = 64;
        int2 p = (lane < m) ? csr_p[base + lane] : make_int2(0, 0);
        int   msrc = p.x;
        float mw   = (lane < m) ? i2f(p.y) * di : 0.f;
        int k = 0;
        for (; k + 4 <= m; k += 4) {
            int s0 = __shfl(msrc, k),     s1 = __shfl(msrc, k + 1);
            int s2 = __shfl(msrc, k + 2), s3 = __shfl(msrc, k + 3);
            float w0 = __shfl(mw, k),     w1 = __shfl(mw, k + 1);
            float w2 = __shfl(mw, k + 2), w3 = __shfl(mw, k + 3);
            unsigned int v0 = ((const unsigned int*)(h + (size_t)s0 * 256))[lane];
            unsigned int v1 = ((const unsigned int*)(h + (size_t)s1 * 256))[lane];
            unsigned int v2 = ((const unsigned int*)(h + (size_t)s2 * 256))[lane];
            unsigned int v3 = ((const unsigned int*)(h + (size_t)s3 * 256))[lane];
            fp8x4_fma(v0, w0, a0);
            fp8x4_fma(v1, w1, a1);
            fp8x4_fma(v2, w2, a2);
            fp8x4_fma(v3, w3, a3);
        }
        for (; k < m; ++k) {
            int   s0 = __shfl(msrc, k); float w0 = __shfl(mw, k);
            unsigned int v0 = ((const unsigned int*)(h + (size_t)s0 * 256))[lane];
            fp8x4_fma(v0, w0, a0);
        }
    }
    ushort4 o;
    o.x = f2bf((a0.x + a1.x) + (a2.x + a3.x));
    o.y = f2bf((a0.y + a1.y) + (a2.y + a3.y));
    o.z = f2bf((a0.z + a1.z) + (a2.z + a3.z));
    o.w = f2bf((a0.w + a1.w) + (a2.w + a3.w));
    ((ushort4*)(out + (size_t)i * 256))[lane] = o;
}

// ---------------- agg64 (fp8 h2) fused with log-softmax: one wave per node; lane == class ----------------

__global__ __launch_bounds__(256) void k_agg64_lsm(const unsigned char* __restrict__ h,
                                                   const int2* __restrict__ csr_p,
                                                   const int* __restrict__ off,
                                                   const int* __restrict__ deg,
                                                   const float* __restrict__ dis,
                                                   const float* __restrict__ bias,
                                                   float* __restrict__ out, int n) {
    int wave = (int)((blockIdx.x * (size_t)blockDim.x + threadIdx.x) >> 6);
    int lane = threadIdx.x & 63;
    if (wave >= n) return;
    const int i = wave;
    const float di = dis[i];
    const int beg = off[i], cnt = deg[i] - 1, end = beg + cnt;

    float a0 = fmaf(fp8_dec1(h[(size_t)i * 64 + lane]), di * di, bias[lane]);
    float a1 = 0.f, a2 = 0.f, a3 = 0.f;

    for (int base = beg; base < end; base += 64) {
        int m = end - base; if (m > 64) m = 64;
        int2 p = (lane < m) ? csr_p[base + lane] : make_int2(0, 0);
        int   msrc = p.x;
        float mw   = (lane < m) ? i2f(p.y) * di : 0.f;
        int k = 0;
        for (; k + 4 <= m; k += 4) {
            int s0 = __shfl(msrc, k),     s1 = __shfl(msrc, k + 1);
            int s2 = __shfl(msrc, k + 2), s3 = __shfl(msrc, k + 3);
            float w0 = __shfl(mw, k),     w1 = __shfl(mw, k + 1);
            float w2 = __shfl(mw, k + 2), w3 = __shfl(mw, k + 3);
            a0 = fmaf(fp8_dec1(h[(size_t)s0 * 64 + lane]), w0, a0);
            a1 = fmaf(fp8_dec1(h[(size_t)s1 * 64 + lane]), w1, a1);
            a2 = fmaf(fp8_dec1(h[(size_t)s2 * 64 + lane]), w2, a2);
            a3 = fmaf(fp8_dec1(h[(size_t)s3 * 64 + lane]), w3, a3);
        }
        for (; k < m; ++k) {
            int s0 = __shfl(msrc, k); float w0 = __shfl(mw, k);
            a0 = fmaf(fp8_dec1(h[(size_t)s0 * 64 + lane]), w0, a0);
        }
    }
    float v = (a0 + a1) + (a2 + a3);

    float mx = v;
    #pragma unroll
    for (int o = 32; o > 0; o >>= 1) mx = fmaxf(mx, __shfl_xor(mx, o));
    float ex = __expf(v - mx);
    float ssum = ex;
    #pragma unroll
    for (int o = 32; o > 0; o >>= 1) ssum += __shfl_xor(ssum, o);
    out[(size_t)i * 64 + lane] = v - mx - logf(ssum);
}

// ---------------- launch ----------------

extern "C" void kernel_launch(void* const* d_in, const int* in_sizes, int n_in,
                              void* d_out, int out_size, void* d_ws, size_t ws_size,
                              hipStream_t stream) {
    const float* x  = (const float*)d_in[0];
    const int*   ei = (const int*)d_in[1];
    const float* W1 = (const float*)d_in[2];
    const float* b1 = (const float*)d_in[3];
    const float* W2 = (const float*)d_in[4];
    const float* b2 = (const float*)d_in[5];
    float* out = (float*)d_out;

    const int n = in_sizes[0] / 512;     // 100000
    const int E = in_sizes[1] / 2;       // 3200000
    const int* src = ei;
    const int* dst = ei + E;

    // workspace layout (bytes), 16B-aligned blocks
    char* ws = (char*)d_ws;
    int*    deg     = (int*)(ws + 0);               //    400,000
    int*    cursor  = (int*)(ws + 400000);          //    400,000
    float*  dis     = (float*)(ws + 800000);        //    400,000
    int*    offsets = (int*)(ws + 1200000);         //    400,000
    int*    partials= (int*)(ws + 1600000);         //        512
    int*    bhist   = (int*)(ws + 1600512);         //      1,024
    int*    bcur    = (int*)(ws + 1601536);         //      1,024
    int2*   csr_p   = (int2*)(ws + 1602560);        // 25,600,000 -> 27,202,560
    ushort* W1T     = (ushort*)(ws + 27202560);     //    262,144 -> 27,464,704
    ushort* W2T     = (ushort*)(ws + 27464704);     //     32,768 -> 27,497,472
    unsigned char* h1 = (unsigned char*)(ws + 27497472);  // 25,600,000 -> 53,097,472
    ushort* out1    = (ushort*)(ws + 53097472);     // 51,200,000 -> 104,297,472
    unsigned char* h2 = (unsigned char*)(ws + 104297472); //  6,400,000 -> 110,697,472
    int2*   sorted  = (int2*)(ws + 117097472);      // 25,600,000 -> 142,697,472

    const int SB = (n + 1023) / 1024;         // scan blocks
    const int PB = (E + 8191) / 8192;         // partition blocks
    const int SETUP_B = 577 + (n + 255) / 256;

    // 0. fused setup (weight transposes, bhist zero, deg init)
    k_setup<<<SETUP_B, 256, 0, stream>>>(W1, W1T, W2, W2T, bhist, deg, n);

    // 1. bucket partition of edges by dst>>9 (coalesced scatter)
    k_bhist<<<512, 256, 0, stream>>>(dst, E, bhist);
    k_bscan<<<1, 256, 0, stream>>>(bhist, bcur);
    k_partition<<<PB, 256, 0, stream>>>(src, dst, E, bcur, sorted);

    // 2. CSR build from bucket-sorted edges (deg atomics in hot window)
    k_count_sorted<<<(E + TB - 1) / TB, TB, 0, stream>>>(sorted, E, deg);
    k_scan_partial<<<SB, 256, 0, stream>>>(deg, partials, n);
    k_scan_tops<<<1, 128, 0, stream>>>(partials, SB);
    k_scan_final<<<SB, 256, 0, stream>>>(deg, partials, offsets, cursor, dis, n);
    k_fill_sorted<<<(E + TB - 1) / TB, TB, 0, stream>>>(sorted, E, cursor, dis, csr_p);

    // 3. h1 = fp8(x @ W1)  (double-buffered LDS, one barrier per K-step)
    k_gemm1<<<(n + 63) / 64, TB, 0, stream>>>(x, W1T, h1, n, 256, 512);

    // 4. out1 = b1 + Â h1  (fp8 gathers)
    k_agg256<<<(n + 3) / 4, TB, 0, stream>>>(h1, csr_p, offsets, deg, dis, b1, out1, n);

    // 5. h2 = fp8(relu(out1) @ W2)
    k_gemm2<<<(n + 127) / 128, TB, 0, stream>>>(out1, W2T, h2, n, 64, 256);

    // 6. out = b2 + Â h2, log-softmax fused (fp8 gathers, one 64B line per row)
    k_agg64_lsm<<<(n + 3) / 4, TB, 0, stream>>>(h2, csr_p, offsets, deg, dis, b2, out, n);
}

// Round 19
// 427.968 us; speedup vs baseline: 1.3165x; 1.2373x over previous
//
#include <hip/hip_runtime.h>
#include <hip/hip_bf16.h>
#include <math.h>

#define TB 256

typedef __attribute__((ext_vector_type(8))) short bf16x8;
typedef __attribute__((ext_vector_type(4))) float f32x4;
typedef __attribute__((ext_vector_type(2))) float f32x2;

__device__ inline float bf2f(ushort u) {
    union { uint u; float f; } c; c.u = ((uint)u) << 16; return c.f;
}
__device__ inline ushort f2bf(float f) {
    __hip_bfloat16 h = __float2bfloat16(f);
    union { __hip_bfloat16 h; ushort u; } c; c.h = h; return c.u;
}
__device__ inline float i2f(int i) { union { int i; float f; } c; c.i = i; return c.f; }
__device__ inline int f2i(float f) { union { float f; int i; } c; c.f = f; return c.i; }

// ---------------- fp8 e4m3 encode/decode (HW cvt preferred; manual fallback) ----------------

#if __has_builtin(__builtin_amdgcn_cvt_pk_fp8_f32) && __has_builtin(__builtin_amdgcn_cvt_pk_f32_fp8)
#define FP8_HW 1
#endif

__device__ inline unsigned char f2fp8(float v) {
#ifdef FP8_HW
    unsigned int r = __builtin_amdgcn_cvt_pk_fp8_f32(v, v, 0u, false);
    return (unsigned char)(r & 0xffu);
#else
    unsigned int s = (v < 0.f) ? 0x80u : 0u;
    float a = fabsf(v);
    if (a >= 448.f) return (unsigned char)(s | 0x7E);
    if (a < 0.015625f) {
        int m = (int)(a * 512.f + 0.5f);
        if (m >= 8) return (unsigned char)(s | 0x08);
        return (unsigned char)(s | m);
    }
    int e; float fr = frexpf(a, &e);
    int m = (int)(fr * 16.f + 0.5f) - 8;
    int E = e + 6;
    if (m == 8) { m = 0; E += 1; }
    if (E >= 16) return (unsigned char)(s | 0x7E);
    return (unsigned char)(s | (E << 3) | m);
#endif
}

#ifndef FP8_HW
__device__ inline float fp8_to_f(unsigned int b) {
    unsigned int s = (b & 0x80u) << 24;
    unsigned int e = (b >> 3) & 0xFu;
    unsigned int m = b & 7u;
    if (e == 0) { float val = (float)m * 0.001953125f; return s ? -val : val; }
    union { unsigned int u; float f; } c;
    c.u = s | ((e + 120u) << 23) | (m << 20);
    return c.f;
}
#endif

__device__ inline void fp8x4_fma(unsigned int v, float w, float4& acc) {
#ifdef FP8_HW
    f32x2 lo = __builtin_amdgcn_cvt_pk_f32_fp8(v, false);
    f32x2 hi = __builtin_amdgcn_cvt_pk_f32_fp8(v, true);
    acc.x = fmaf(lo.x, w, acc.x);
    acc.y = fmaf(lo.y, w, acc.y);
    acc.z = fmaf(hi.x, w, acc.z);
    acc.w = fmaf(hi.y, w, acc.w);
#else
    acc.x = fmaf(fp8_to_f(v & 0xff), w, acc.x);
    acc.y = fmaf(fp8_to_f((v >> 8) & 0xff), w, acc.y);
    acc.z = fmaf(fp8_to_f((v >> 16) & 0xff), w, acc.z);
    acc.w = fmaf(fp8_to_f(v >> 24), w, acc.w);
#endif
}

__device__ inline float fp8_dec1(unsigned int b) {
#ifdef FP8_HW
    f32x2 lo = __builtin_amdgcn_cvt_pk_f32_fp8(b & 0xffu, false);
    return lo.x;
#else
    return fp8_to_f(b & 0xffu);
#endif
}

// ---------------- fused setup: W1/W2 transpose+cast, bhist zero ----------------

__global__ __launch_bounds__(256) void k_setup(const float* __restrict__ W1, ushort* __restrict__ W1T,
                                               const float* __restrict__ W2, ushort* __restrict__ W2T,
                                               int* __restrict__ bhist) {
    int b = blockIdx.x;
    int t = threadIdx.x;
    if (b < 512) {
        int id = b * 256 + t;                 // K=512, N=256
        int k = id >> 8, nn = id & 255;
        W1T[(size_t)nn * 512 + k] = f2bf(W1[id]);
    } else if (b < 576) {
        int id = (b - 512) * 256 + t;         // K=256, N=64
        int k = id >> 6, nn = id & 63;
        W2T[(size_t)nn * 256 + k] = f2bf(W2[id]);
    } else {
        bhist[t] = 0;
    }
}

// ---------------- bucket partition (256 buckets by dst>>9) ----------------

__global__ __launch_bounds__(256) void k_bhist(const int* __restrict__ dst, int E,
                                               int* __restrict__ hist) {
    __shared__ int lh[256];
    int t = threadIdx.x;
    lh[t] = 0;
    __syncthreads();
    for (int e = blockIdx.x * blockDim.x + t; e < E; e += gridDim.x * blockDim.x)
        atomicAdd(&lh[dst[e] >> 9], 1);
    __syncthreads();
    if (lh[t]) atomicAdd(&hist[t], lh[t]);
}

__global__ __launch_bounds__(256) void k_bscan(const int* __restrict__ hist,
                                               int* __restrict__ bcur,
                                               int* __restrict__ bbase) {
    __shared__ int sh[256];
    int t = threadIdx.x;
    int v = hist[t];
    sh[t] = v;
    __syncthreads();
    for (int off = 1; off < 256; off <<= 1) {
        int u = (t >= off) ? sh[t - off] : 0;
        __syncthreads();
        sh[t] += u;
        __syncthreads();
    }
    int excl = sh[t] - v;
    bcur[t]  = excl;   // mutable cursor for partition
    bbase[t] = excl;   // immutable bucket base
}

__global__ __launch_bounds__(256) void k_partition(const int* __restrict__ src,
                                                   const int* __restrict__ dst, int E,
                                                   int* __restrict__ bcur,
                                                   int2* __restrict__ sorted) {
    __shared__ int lh[256];
    const int per = 8192;
    int e0 = blockIdx.x * per;
    int e1 = min(E, e0 + per);
    int t = threadIdx.x;
    lh[t] = 0;
    __syncthreads();
    for (int e = e0 + t; e < e1; e += 256)
        atomicAdd(&lh[dst[e] >> 9], 1);
    __syncthreads();
    int cnt = lh[t];
    int base = cnt ? atomicAdd(&bcur[t], cnt) : 0;
    __syncthreads();
    lh[t] = base;
    __syncthreads();
    for (int e = e0 + t; e < e1; e += 256) {
        int d = dst[e], s = src[e];
        int pos = atomicAdd(&lh[d >> 9], 1);
        sorted[pos] = make_int2(s, d);
    }
}

// ---------------- bucket-local CSR build (replaces count + scans + global-cursor fill) ----------------
// Bucket b owns nodes [512b, 512b+512) and edge slice [bbase[b], bbase[b+1]).
// Pass 1: LDS deg count + LDS scan -> deg/offsets/dis directly.

__global__ __launch_bounds__(256) void k_bucket_deg(const int2* __restrict__ sorted, int E,
                                                    const int* __restrict__ bbase,
                                                    int* __restrict__ deg,
                                                    int* __restrict__ offsets,
                                                    float* __restrict__ dis, int n) {
    __shared__ int cnt[512];
    __shared__ int pr[256];
    const int b = blockIdx.x;
    const int t = threadIdx.x;
    const int bstart = bbase[b];
    const int bend   = (b < 255) ? bbase[b + 1] : E;
    const int node0  = b << 9;

    cnt[t] = 0; cnt[t + 256] = 0;
    __syncthreads();
    for (int e = bstart + t; e < bend; e += 256)
        atomicAdd(&cnt[sorted[e].y & 511], 1);
    __syncthreads();

    int c0 = cnt[2 * t], c1 = cnt[2 * t + 1];
    pr[t] = c0 + c1;
    __syncthreads();
    for (int off = 1; off < 256; off <<= 1) {
        int u = (t >= off) ? pr[t - off] : 0;
        __syncthreads();
        pr[t] += u;
        __syncthreads();
    }
    int excl = pr[t] - (c0 + c1);

    int i0 = node0 + 2 * t, i1 = i0 + 1;
    if (i0 < n) {
        deg[i0] = c0 + 1;
        offsets[i0] = bstart + excl;
        dis[i0] = rsqrtf((float)(c0 + 1));
    }
    if (i1 < n) {
        deg[i1] = c1 + 1;
        offsets[i1] = bstart + excl + c0;
        dis[i1] = rsqrtf((float)(c1 + 1));
    }
}

// Pass 2: LDS cursors (loaded from offsets), fill csr_p with LDS atomics.
__global__ __launch_bounds__(256) void k_bucket_fill(const int2* __restrict__ sorted, int E,
                                                     const int* __restrict__ bbase,
                                                     const int* __restrict__ offsets,
                                                     const float* __restrict__ dis,
                                                     int2* __restrict__ csr_p, int n) {
    __shared__ int cur[512];
    const int b = blockIdx.x;
    const int t = threadIdx.x;
    const int bstart = bbase[b];
    const int bend   = (b < 255) ? bbase[b + 1] : E;
    const int node0  = b << 9;

    int i0 = node0 + t, i1 = i0 + 256;
    cur[t]       = (i0 < n) ? offsets[i0] : 0;
    cur[t + 256] = (i1 < n) ? offsets[i1] : 0;
    __syncthreads();

    for (int e = bstart + t; e < bend; e += 256) {
        int2 p = sorted[e];
        int pos = atomicAdd(&cur[p.y & 511], 1);
        csr_p[pos] = make_int2(p.x, f2i(dis[p.x]));
    }
}

// ---------------- GEMM1 (LDS double-buffered): h1_fp8[M,256] = fp8(bf16(A[M,512]) @ W1T^T)

__global__ __launch_bounds__(256) void k_gemm1(const float* __restrict__ A,
                                               const ushort* __restrict__ BT,
                                               unsigned char* __restrict__ C,
                                               int M, int N, int K) {
    const int BM = 64, BK = 32;
    __shared__ ushort Al[2][BM][40];
    __shared__ ushort Bl[2][256][40];

    const int t    = threadIdx.x;
    const int lane = t & 63;
    const int wid  = t >> 6;
    const int m0   = blockIdx.x * BM;
    const int lr   = lane & 15;
    const int lg   = lane >> 4;

    const int arow = t >> 2, aq = t & 3;
    const int agm  = min(m0 + arow, M - 1);
    const bool avalid = (m0 + arow) < M;

    f32x4 acc[4][4] = {};

    {
        ushort4 o0 = {0,0,0,0}, o1 = {0,0,0,0};
        if (avalid) {
            const float* ap = A + (size_t)agm * K + aq * 8;
            float4 u = *(const float4*)ap;
            float4 w = *(const float4*)(ap + 4);
            o0.x = f2bf(u.x); o0.y = f2bf(u.y); o0.z = f2bf(u.z); o0.w = f2bf(u.w);
            o1.x = f2bf(w.x); o1.y = f2bf(w.y); o1.z = f2bf(w.z); o1.w = f2bf(w.w);
        }
        *(ushort4*)(&Al[0][arow][aq * 8])     = o0;
        *(ushort4*)(&Al[0][arow][aq * 8 + 4]) = o1;
        #pragma unroll
        for (int it = 0; it < 4; ++it) {
            int c = t + it * 256;
            int row = c >> 2, q = c & 3;
            uint4 v = *(const uint4*)(BT + (size_t)row * K + q * 8);
            *(uint4*)(&Bl[0][row][q * 8]) = v;
        }
    }
    __syncthreads();

    int buf = 0;
    for (int k0 = 0; k0 < K; k0 += BK) {
        if (k0 + BK < K) {
            int nb = buf ^ 1;
            int kn = k0 + BK;
            ushort4 o0 = {0,0,0,0}, o1 = {0,0,0,0};
            if (avalid) {
                const float* ap = A + (size_t)agm * K + kn + aq * 8;
                float4 u = *(const float4*)ap;
                float4 w = *(const float4*)(ap + 4);
                o0.x = f2bf(u.x); o0.y = f2bf(u.y); o0.z = f2bf(u.z); o0.w = f2bf(u.w);
                o1.x = f2bf(w.x); o1.y = f2bf(w.y); o1.z = f2bf(w.z); o1.w = f2bf(w.w);
            }
            *(ushort4*)(&Al[nb][arow][aq * 8])     = o0;
            *(ushort4*)(&Al[nb][arow][aq * 8 + 4]) = o1;
            #pragma unroll
            for (int it = 0; it < 4; ++it) {
                int c = t + it * 256;
                int row = c >> 2, q = c & 3;
                uint4 v = *(const uint4*)(BT + (size_t)row * K + kn + q * 8);
                *(uint4*)(&Bl[nb][row][q * 8]) = v;
            }
        }

        bf16x8 fa[4], fb[4];
        #pragma unroll
        for (int mi = 0; mi < 4; ++mi)
            fa[mi] = *(const bf16x8*)(&Al[buf][mi * 16 + lr][lg * 8]);
        #pragma unroll
        for (int ni = 0; ni < 4; ++ni)
            fb[ni] = *(const bf16x8*)(&Bl[buf][wid * 64 + ni * 16 + lr][lg * 8]);
        #pragma unroll
        for (int mi = 0; mi < 4; ++mi)
            #pragma unroll
            for (int ni = 0; ni < 4; ++ni)
                acc[mi][ni] = __builtin_amdgcn_mfma_f32_16x16x32_bf16(fa[mi], fb[ni], acc[mi][ni], 0, 0, 0);
        __syncthreads();
        buf ^= 1;
    }

    #pragma unroll
    for (int mi = 0; mi < 4; ++mi) {
        int rbase = m0 + mi * 16 + lg * 4;
        #pragma unroll
        for (int v = 0; v < 4; ++v) {
            int gm = rbase + v;
            if (gm < M) {
                #pragma unroll
                for (int ni = 0; ni < 4; ++ni)
                    C[(size_t)gm * N + wid * 64 + ni * 16 + lr] = f2fp8(acc[mi][ni][v]);
            }
        }
    }
}

// ---------------- GEMM2 (LDS): h2_fp8[M,64] = fp8(relu(A_bf16[M,256]) @ W2T[64,256]^T) ----------------

__device__ inline uint relu_pk(uint u) {
    uint lo = u & 0x0000FFFFu;
    uint hi = u & 0xFFFF0000u;
    if (u & 0x00008000u) lo = 0;
    if (u & 0x80000000u) hi = 0;
    return lo | hi;
}

__global__ __launch_bounds__(256) void k_gemm2(const ushort* __restrict__ A,
                                               const ushort* __restrict__ BT,
                                               unsigned char* __restrict__ C,
                                               int M, int N, int K) {
    const int BM = 128, BK = 32;
    __shared__ ushort Al[BM][40];
    __shared__ ushort Bl[64][40];

    const int t    = threadIdx.x;
    const int lane = t & 63;
    const int wid  = t >> 6;
    const int wm   = wid >> 1, wn = wid & 1;
    const int m0   = blockIdx.x * BM;
    const int lr   = lane & 15;
    const int lg   = lane >> 4;

    f32x4 acc[4][2] = {};

    for (int k0 = 0; k0 < K; k0 += BK) {
        #pragma unroll
        for (int i = 0; i < 2; ++i) {
            int c = t + i * 256;
            int row = c >> 2, q = c & 3;
            int gm = m0 + row;
            uint4 v = make_uint4(0, 0, 0, 0);
            if (gm < M) v = *(const uint4*)(A + (size_t)gm * K + k0 + q * 8);
            v.x = relu_pk(v.x); v.y = relu_pk(v.y); v.z = relu_pk(v.z); v.w = relu_pk(v.w);
            *(uint4*)(&Al[row][q * 8]) = v;
        }
        {
            int row = t >> 2, q = t & 3;
            uint4 v = *(const uint4*)(BT + (size_t)(row) * K + k0 + q * 8);
            *(uint4*)(&Bl[row][q * 8]) = v;
        }
        __syncthreads();

        bf16x8 fa[4], fb[2];
        #pragma unroll
        for (int mi = 0; mi < 4; ++mi)
            fa[mi] = *(const bf16x8*)(&Al[wm * 64 + mi * 16 + lr][lg * 8]);
        #pragma unroll
        for (int ni = 0; ni < 2; ++ni)
            fb[ni] = *(const bf16x8*)(&Bl[wn * 32 + ni * 16 + lr][lg * 8]);
        #pragma unroll
        for (int mi = 0; mi < 4; ++mi)
            #pragma unroll
            for (int ni = 0; ni < 2; ++ni)
                acc[mi][ni] = __builtin_amdgcn_mfma_f32_16x16x32_bf16(fa[mi], fb[ni], acc[mi][ni], 0, 0, 0);
        __syncthreads();
    }

    #pragma unroll
    for (int mi = 0; mi < 4; ++mi) {
        int rbase = m0 + wm * 64 + mi * 16 + lg * 4;
        #pragma unroll
        for (int v = 0; v < 4; ++v) {
            int gm = rbase + v;
            if (gm < M) {
                #pragma unroll
                for (int ni = 0; ni < 2; ++ni)
                    C[(size_t)gm * N + wn * 32 + ni * 16 + lr] = f2fp8(acc[mi][ni][v]);
            }
        }
    }
}

// ---------------- gather aggregation (fp8 h1), one wave per dst node, 4-deep MLP ----------------

__global__ __launch_bounds__(256) void k_agg256(const unsigned char* __restrict__ h,
                                                const int2* __restrict__ csr_p,
                                                const int* __restrict__ off,
                                                const int* __restrict__ deg,
                                                const float* __restrict__ dis,
                                                const float* __restrict__ bias,
                                                ushort* __restrict__ out, int n) {
    int wave = (int)((blockIdx.x * (size_t)blockDim.x + threadIdx.x) >> 6);
    int lane = threadIdx.x & 63;
    if (wave >= n) return;
    const int i = wave;
    const float di = dis[i];
    const int beg = off[i], cnt = deg[i] - 1, end = beg + cnt;

    float4 bv = ((const float4*)bias)[lane];
    unsigned int hv = ((const unsigned int*)(h + (size_t)i * 256))[lane];
    float sl = di * di;
    float4 a0 = bv, a1 = {0,0,0,0}, a2 = {0,0,0,0}, a3 = {0,0,0,0};
    fp8x4_fma(hv, sl, a0);

    for (int base = beg; base < end; base += 64) {
        int m = end - base; if (m > 64) m = 64;
        int2 p = (lane < m) ? csr_p[base + lane] : make_int2(0, 0);
        int   msrc = p.x;
        float mw   = (lane < m) ? i2f(p.y) * di : 0.f;
        int k = 0;
        for (; k + 4 <= m; k += 4) {
            int s0 = __shfl(msrc, k),     s1 = __shfl(msrc, k + 1);
            int s2 = __shfl(msrc, k + 2), s3 = __shfl(msrc, k + 3);
            float w0 = __shfl(mw, k),     w1 = __shfl(mw, k + 1);
            float w2 = __shfl(mw, k + 2), w3 = __shfl(mw, k + 3);
            unsigned int v0 = ((const unsigned int*)(h + (size_t)s0 * 256))[lane];
            unsigned int v1 = ((const unsigned int*)(h + (size_t)s1 * 256))[lane];
            unsigned int v2 = ((const unsigned int*)(h + (size_t)s2 * 256))[lane];
            unsigned int v3 = ((const unsigned int*)(h + (size_t)s3 * 256))[lane];
            fp8x4_fma(v0, w0, a0);
            fp8x4_fma(v1, w1, a1);
            fp8x4_fma(v2, w2, a2);
            fp8x4_fma(v3, w3, a3);
        }
        for (; k < m; ++k) {
            int   s0 = __shfl(msrc, k); float w0 = __shfl(mw, k);
            unsigned int v0 = ((const unsigned int*)(h + (size_t)s0 * 256))[lane];
            fp8x4_fma(v0, w0, a0);
        }
    }
    ushort4 o;
    o.x = f2bf((a0.x + a1.x) + (a2.x + a3.x));
    o.y = f2bf((a0.y + a1.y) + (a2.y + a3.y));
    o.z = f2bf((a0.z + a1.z) + (a2.z + a3.z));
    o.w = f2bf((a0.w + a1.w) + (a2.w + a3.w));
    ((ushort4*)(out + (size_t)i * 256))[lane] = o;
}

// ---------------- agg64 (fp8 h2) fused with log-softmax: one wave per node; lane == class ----------------

__global__ __launch_bounds__(256) void k_agg64_lsm(const unsigned char* __restrict__ h,
                                                   const int2* __restrict__ csr_p,
                                                   const int* __restrict__ off,
                                                   const int* __restrict__ deg,
                                                   const float* __restrict__ dis,
                                                   const float* __restrict__ bias,
                                                   float* __restrict__ out, int n) {
    int wave = (int)((blockIdx.x * (size_t)blockDim.x + threadIdx.x) >> 6);
    int lane = threadIdx.x & 63;
    if (wave >= n) return;
    const int i = wave;
    const float di = dis[i];
    const int beg = off[i], cnt = deg[i] - 1, end = beg + cnt;

    float a0 = fmaf(fp8_dec1(h[(size_t)i * 64 + lane]), di * di, bias[lane]);
    float a1 = 0.f, a2 = 0.f, a3 = 0.f;

    for (int base = beg; base < end; base += 64) {
        int m = end - base; if (m > 64) m = 64;
        int2 p = (lane < m) ? csr_p[base + lane] : make_int2(0, 0);
        int   msrc = p.x;
        float mw   = (lane < m) ? i2f(p.y) * di : 0.f;
        int k = 0;
        for (; k + 4 <= m; k += 4) {
            int s0 = __shfl(msrc, k),     s1 = __shfl(msrc, k + 1);
            int s2 = __shfl(msrc, k + 2), s3 = __shfl(msrc, k + 3);
            float w0 = __shfl(mw, k),     w1 = __shfl(mw, k + 1);
            float w2 = __shfl(mw, k + 2), w3 = __shfl(mw, k + 3);
            a0 = fmaf(fp8_dec1(h[(size_t)s0 * 64 + lane]), w0, a0);
            a1 = fmaf(fp8_dec1(h[(size_t)s1 * 64 + lane]), w1, a1);
            a2 = fmaf(fp8_dec1(h[(size_t)s2 * 64 + lane]), w2, a2);
            a3 = fmaf(fp8_dec1(h[(size_t)s3 * 64 + lane]), w3, a3);
        }
        for (; k < m; ++k) {
            int s0 = __shfl(msrc, k); float w0 = __shfl(mw, k);
            a0 = fmaf(fp8_dec1(h[(size_t)s0 * 64 + lane]), w0, a0);
        }
    }
    float v = (a0 + a1) + (a2 + a3);

    float mx = v;
    #pragma unroll
    for (int o = 32; o > 0; o >>= 1) mx = fmaxf(mx, __shfl_xor(mx, o));
    float ex = __expf(v - mx);
    float ssum = ex;
    #pragma unroll
    for (int o = 32; o > 0; o >>= 1) ssum += __shfl_xor(ssum, o);
    out[(size_t)i * 64 + lane] = v - mx - logf(ssum);
}

// ---------------- launch ----------------

extern "C" void kernel_launch(void* const* d_in, const int* in_sizes, int n_in,
                              void* d_out, int out_size, void* d_ws, size_t ws_size,
                              hipStream_t stream) {
    const float* x  = (const float*)d_in[0];
    const int*   ei = (const int*)d_in[1];
    const float* W1 = (const float*)d_in[2];
    const float* b1 = (const float*)d_in[3];
    const float* W2 = (const float*)d_in[4];
    const float* b2 = (const float*)d_in[5];
    float* out = (float*)d_out;

    const int n = in_sizes[0] / 512;     // 100000
    const int E = in_sizes[1] / 2;       // 3200000
    const int* src = ei;
    const int* dst = ei + E;

    // workspace layout (bytes), 16B-aligned blocks
    char* ws = (char*)d_ws;
    int*    deg     = (int*)(ws + 0);               //    400,000
    float*  dis     = (float*)(ws + 400000);        //    400,000
    int*    offsets = (int*)(ws + 800000);          //    400,000
    int*    bhist   = (int*)(ws + 1200000);         //      1,024
    int*    bcur    = (int*)(ws + 1201024);         //      1,024
    int*    bbase   = (int*)(ws + 1202048);         //      1,024
    int2*   csr_p   = (int2*)(ws + 1203072);        // 25,600,000 -> 26,803,072
    ushort* W1T     = (ushort*)(ws + 26803072);     //    262,144 -> 27,065,216
    ushort* W2T     = (ushort*)(ws + 27065216);     //     32,768 -> 27,097,984
    unsigned char* h1 = (unsigned char*)(ws + 27097984);  // 25,600,000 -> 52,697,984
    ushort* out1    = (ushort*)(ws + 52697984);     // 51,200,000 -> 103,897,984
    unsigned char* h2 = (unsigned char*)(ws + 103897984); //  6,400,000 -> 110,297,984
    int2*   sorted  = (int2*)(ws + 110297984);      // 25,600,000 -> 135,897,984

    const int PB   = (E + 8191) / 8192;     // partition blocks
    const int NBKT = (n + 511) / 512;       // active buckets (196)

    // 0. fused setup (weight transposes, bhist zero)
    k_setup<<<577, 256, 0, stream>>>(W1, W1T, W2, W2T, bhist);

    // 1. bucket partition of edges by dst>>9 (coalesced scatter)
    k_bhist<<<512, 256, 0, stream>>>(dst, E, bhist);
    k_bscan<<<1, 256, 0, stream>>>(bhist, bcur, bbase);
    k_partition<<<PB, 256, 0, stream>>>(src, dst, E, bcur, sorted);

    // 2. bucket-local CSR build (LDS counts/scans/cursors; no global atomics)
    k_bucket_deg<<<NBKT, 256, 0, stream>>>(sorted, E, bbase, deg, offsets, dis, n);
    k_bucket_fill<<<NBKT, 256, 0, stream>>>(sorted, E, bbase, offsets, dis, csr_p, n);

    // 3. h1 = fp8(x @ W1)  (double-buffered LDS)
    k_gemm1<<<(n + 63) / 64, TB, 0, stream>>>(x, W1T, h1, n, 256, 512);

    // 4. out1 = b1 + Â h1  (fp8 gathers)
    k_agg256<<<(n + 3) / 4, TB, 0, stream>>>(h1, csr_p, offsets, deg, dis, b1, out1, n);

    // 5. h2 = fp8(relu(out1) @ W2)
    k_gemm2<<<(n + 127) / 128, TB, 0, stream>>>(out1, W2T, h2, n, 64, 256);

    // 6. out = b2 + Â h2, log-softmax fused (fp8 gathers, one 64B line per row)
    k_agg64_lsm<<<(n + 3) / 4, TB, 0, stream>>>(h2, csr_p, offsets, deg, dis, b2, out, n);
}

// Round 20
// 416.524 us; speedup vs baseline: 1.3527x; 1.0275x over previous
//
#include <hip/hip_runtime.h>
#include <hip/hip_bf16.h>
#include <math.h>

#define TB 256

typedef __attribute__((ext_vector_type(8))) short bf16x8;
typedef __attribute__((ext_vector_type(4))) float f32x4;
typedef __attribute__((ext_vector_type(2))) float f32x2;

__device__ inline float bf2f(ushort u) {
    union { uint u; float f; } c; c.u = ((uint)u) << 16; return c.f;
}
__device__ inline ushort f2bf(float f) {
    __hip_bfloat16 h = __float2bfloat16(f);
    union { __hip_bfloat16 h; ushort u; } c; c.h = h; return c.u;
}
__device__ inline float i2f(int i) { union { int i; float f; } c; c.i = i; return c.f; }
__device__ inline int f2i(float f) { union { float f; int i; } c; c.f = f; return c.i; }

// ---------------- fp8 e4m3 encode/decode (HW cvt preferred; manual fallback) ----------------

#if __has_builtin(__builtin_amdgcn_cvt_pk_fp8_f32) && __has_builtin(__builtin_amdgcn_cvt_pk_f32_fp8)
#define FP8_HW 1
#endif

__device__ inline unsigned char f2fp8(float v) {
#ifdef FP8_HW
    unsigned int r = __builtin_amdgcn_cvt_pk_fp8_f32(v, v, 0u, false);
    return (unsigned char)(r & 0xffu);
#else
    unsigned int s = (v < 0.f) ? 0x80u : 0u;
    float a = fabsf(v);
    if (a >= 448.f) return (unsigned char)(s | 0x7E);
    if (a < 0.015625f) {
        int m = (int)(a * 512.f + 0.5f);
        if (m >= 8) return (unsigned char)(s | 0x08);
        return (unsigned char)(s | m);
    }
    int e; float fr = frexpf(a, &e);
    int m = (int)(fr * 16.f + 0.5f) - 8;
    int E = e + 6;
    if (m == 8) { m = 0; E += 1; }
    if (E >= 16) return (unsigned char)(s | 0x7E);
    return (unsigned char)(s | (E << 3) | m);
#endif
}

#ifndef FP8_HW
__device__ inline float fp8_to_f(unsigned int b) {
    unsigned int s = (b & 0x80u) << 24;
    unsigned int e = (b >> 3) & 0xFu;
    unsigned int m = b & 7u;
    if (e == 0) { float val = (float)m * 0.001953125f; return s ? -val : val; }
    union { unsigned int u; float f; } c;
    c.u = s | ((e + 120u) << 23) | (m << 20);
    return c.f;
}
#endif

__device__ inline void fp8x4_fma(unsigned int v, float w, float4& acc) {
#ifdef FP8_HW
    f32x2 lo = __builtin_amdgcn_cvt_pk_f32_fp8(v, false);
    f32x2 hi = __builtin_amdgcn_cvt_pk_f32_fp8(v, true);
    acc.x = fmaf(lo.x, w, acc.x);
    acc.y = fmaf(lo.y, w, acc.y);
    acc.z = fmaf(hi.x, w, acc.z);
    acc.w = fmaf(hi.y, w, acc.w);
#else
    acc.x = fmaf(fp8_to_f(v & 0xff), w, acc.x);
    acc.y = fmaf(fp8_to_f((v >> 8) & 0xff), w, acc.y);
    acc.z = fmaf(fp8_to_f((v >> 16) & 0xff), w, acc.z);
    acc.w = fmaf(fp8_to_f(v >> 24), w, acc.w);
#endif
}

__device__ inline float fp8_dec1(unsigned int b) {
#ifdef FP8_HW
    f32x2 lo = __builtin_amdgcn_cvt_pk_f32_fp8(b & 0xffu, false);
    return lo.x;
#else
    return fp8_to_f(b & 0xffu);
#endif
}

// ---------------- fused setup: W1/W2 transpose+cast, bhist zero ----------------

__global__ __launch_bounds__(256) void k_setup(const float* __restrict__ W1, ushort* __restrict__ W1T,
                                               const float* __restrict__ W2, ushort* __restrict__ W2T,
                                               int* __restrict__ bhist) {
    int b = blockIdx.x;
    int t = threadIdx.x;
    if (b < 512) {
        int id = b * 256 + t;                 // K=512, N=256
        int k = id >> 8, nn = id & 255;
        W1T[(size_t)nn * 512 + k] = f2bf(W1[id]);
    } else if (b < 576) {
        int id = (b - 512) * 256 + t;         // K=256, N=64
        int k = id >> 6, nn = id & 63;
        W2T[(size_t)nn * 256 + k] = f2bf(W2[id]);
    } else {
        bhist[t] = 0;
    }
}

// ---------------- bucket partition (256 buckets by dst>>9) ----------------

__global__ __launch_bounds__(256) void k_bhist(const int* __restrict__ dst, int E,
                                               int* __restrict__ hist) {
    __shared__ int lh[256];
    int t = threadIdx.x;
    lh[t] = 0;
    __syncthreads();
    for (int e = blockIdx.x * blockDim.x + t; e < E; e += gridDim.x * blockDim.x)
        atomicAdd(&lh[dst[e] >> 9], 1);
    __syncthreads();
    if (lh[t]) atomicAdd(&hist[t], lh[t]);
}

__global__ __launch_bounds__(256) void k_bscan(const int* __restrict__ hist,
                                               int* __restrict__ bcur,
                                               int* __restrict__ bbase) {
    __shared__ int sh[256];
    int t = threadIdx.x;
    int v = hist[t];
    sh[t] = v;
    __syncthreads();
    for (int off = 1; off < 256; off <<= 1) {
        int u = (t >= off) ? sh[t - off] : 0;
        __syncthreads();
        sh[t] += u;
        __syncthreads();
    }
    int excl = sh[t] - v;
    bcur[t]  = excl;   // mutable cursor for partition
    bbase[t] = excl;   // immutable bucket base
}

// LDS-staged multisplit: bin 8192 edges into LDS in bucket order, then write each
// bucket's run contiguously to its reserved global window (coalesced stores).
__global__ __launch_bounds__(256) void k_partition(const int* __restrict__ src,
                                                   const int* __restrict__ dst, int E,
                                                   int* __restrict__ bcur,
                                                   int2* __restrict__ sorted) {
    __shared__ int  lcnt[256];
    __shared__ int  pr[256];
    __shared__ int  lbase[256];
    __shared__ int  gbase[256];
    __shared__ int  lcur[256];
    __shared__ int2 lsort[8192];

    const int per = 8192;
    const int e0 = blockIdx.x * per;
    const int e1 = min(E, e0 + per);
    const int m  = e1 - e0;
    const int t  = threadIdx.x;

    lcnt[t] = 0;
    __syncthreads();
    for (int e = e0 + t; e < e1; e += 256)
        atomicAdd(&lcnt[dst[e] >> 9], 1);
    __syncthreads();

    int v = lcnt[t];
    pr[t] = v;
    __syncthreads();
    for (int off = 1; off < 256; off <<= 1) {
        int u = (t >= off) ? pr[t - off] : 0;
        __syncthreads();
        pr[t] += u;
        __syncthreads();
    }
    int excl = pr[t] - v;
    lbase[t] = excl;
    lcur[t]  = excl;
    gbase[t] = v ? atomicAdd(&bcur[t], v) : 0;
    __syncthreads();

    // bin into LDS in bucket order
    for (int e = e0 + t; e < e1; e += 256) {
        int d = dst[e], s = src[e];
        int lpos = atomicAdd(&lcur[d >> 9], 1);
        lsort[lpos] = make_int2(s, d);
    }
    __syncthreads();

    // linear sweep -> contiguous per-bucket global writes
    for (int j = t; j < m; j += 256) {
        int2 p = lsort[j];
        int b = p.y >> 9;
        sorted[gbase[b] + (j - lbase[b])] = p;
    }
}

// ---------------- bucket-local CSR build ----------------
// Bucket b owns nodes [512b, 512b+512) and edge slice [bbase[b], bbase[b+1]).

__global__ __launch_bounds__(256) void k_bucket_deg(const int2* __restrict__ sorted, int E,
                                                    const int* __restrict__ bbase,
                                                    int* __restrict__ deg,
                                                    int* __restrict__ offsets,
                                                    float* __restrict__ dis, int n) {
    __shared__ int cnt[512];
    __shared__ int pr[256];
    const int b = blockIdx.x;
    const int t = threadIdx.x;
    const int bstart = bbase[b];
    const int bend   = (b < 255) ? bbase[b + 1] : E;
    const int node0  = b << 9;

    cnt[t] = 0; cnt[t + 256] = 0;
    __syncthreads();
    for (int e = bstart + t; e < bend; e += 256)
        atomicAdd(&cnt[sorted[e].y & 511], 1);
    __syncthreads();

    int c0 = cnt[2 * t], c1 = cnt[2 * t + 1];
    pr[t] = c0 + c1;
    __syncthreads();
    for (int off = 1; off < 256; off <<= 1) {
        int u = (t >= off) ? pr[t - off] : 0;
        __syncthreads();
        pr[t] += u;
        __syncthreads();
    }
    int excl = pr[t] - (c0 + c1);

    int i0 = node0 + 2 * t, i1 = i0 + 1;
    if (i0 < n) {
        deg[i0] = c0 + 1;
        offsets[i0] = bstart + excl;
        dis[i0] = rsqrtf((float)(c0 + 1));
    }
    if (i1 < n) {
        deg[i1] = c1 + 1;
        offsets[i1] = bstart + excl + c0;
        dis[i1] = rsqrtf((float)(c1 + 1));
    }
}

__global__ __launch_bounds__(256) void k_bucket_fill(const int2* __restrict__ sorted, int E,
                                                     const int* __restrict__ bbase,
                                                     const int* __restrict__ offsets,
                                                     const float* __restrict__ dis,
                                                     int2* __restrict__ csr_p, int n) {
    __shared__ int cur[512];
    const int b = blockIdx.x;
    const int t = threadIdx.x;
    const int bstart = bbase[b];
    const int bend   = (b < 255) ? bbase[b + 1] : E;
    const int node0  = b << 9;

    int i0 = node0 + t, i1 = i0 + 256;
    cur[t]       = (i0 < n) ? offsets[i0] : 0;
    cur[t + 256] = (i1 < n) ? offsets[i1] : 0;
    __syncthreads();

    for (int e = bstart + t; e < bend; e += 256) {
        int2 p = sorted[e];
        int pos = atomicAdd(&cur[p.y & 511], 1);
        csr_p[pos] = make_int2(p.x, f2i(dis[p.x]));
    }
}

// ---------------- GEMM1 (LDS double-buffered): h1_fp8[M,256] = fp8(bf16(A[M,512]) @ W1T^T)

__global__ __launch_bounds__(256) void k_gemm1(const float* __restrict__ A,
                                               const ushort* __restrict__ BT,
                                               unsigned char* __restrict__ C,
                                               int M, int N, int K) {
    const int BM = 64, BK = 32;
    __shared__ ushort Al[2][BM][40];
    __shared__ ushort Bl[2][256][40];

    const int t    = threadIdx.x;
    const int lane = t & 63;
    const int wid  = t >> 6;
    const int m0   = blockIdx.x * BM;
    const int lr   = lane & 15;
    const int lg   = lane >> 4;

    const int arow = t >> 2, aq = t & 3;
    const int agm  = min(m0 + arow, M - 1);
    const bool avalid = (m0 + arow) < M;

    f32x4 acc[4][4] = {};

    {
        ushort4 o0 = {0,0,0,0}, o1 = {0,0,0,0};
        if (avalid) {
            const float* ap = A + (size_t)agm * K + aq * 8;
            float4 u = *(const float4*)ap;
            float4 w = *(const float4*)(ap + 4);
            o0.x = f2bf(u.x); o0.y = f2bf(u.y); o0.z = f2bf(u.z); o0.w = f2bf(u.w);
            o1.x = f2bf(w.x); o1.y = f2bf(w.y); o1.z = f2bf(w.z); o1.w = f2bf(w.w);
        }
        *(ushort4*)(&Al[0][arow][aq * 8])     = o0;
        *(ushort4*)(&Al[0][arow][aq * 8 + 4]) = o1;
        #pragma unroll
        for (int it = 0; it < 4; ++it) {
            int c = t + it * 256;
            int row = c >> 2, q = c & 3;
            uint4 v = *(const uint4*)(BT + (size_t)row * K + q * 8);
            *(uint4*)(&Bl[0][row][q * 8]) = v;
        }
    }
    __syncthreads();

    int buf = 0;
    for (int k0 = 0; k0 < K; k0 += BK) {
        if (k0 + BK < K) {
            int nb = buf ^ 1;
            int kn = k0 + BK;
            ushort4 o0 = {0,0,0,0}, o1 = {0,0,0,0};
            if (avalid) {
                const float* ap = A + (size_t)agm * K + kn + aq * 8;
                float4 u = *(const float4*)ap;
                float4 w = *(const float4*)(ap + 4);
                o0.x = f2bf(u.x); o0.y = f2bf(u.y); o0.z = f2bf(u.z); o0.w = f2bf(u.w);
                o1.x = f2bf(w.x); o1.y = f2bf(w.y); o1.z = f2bf(w.z); o1.w = f2bf(w.w);
            }
            *(ushort4*)(&Al[nb][arow][aq * 8])     = o0;
            *(ushort4*)(&Al[nb][arow][aq * 8 + 4]) = o1;
            #pragma unroll
            for (int it = 0; it < 4; ++it) {
                int c = t + it * 256;
                int row = c >> 2, q = c & 3;
                uint4 v = *(const uint4*)(BT + (size_t)row * K + kn + q * 8);
                *(uint4*)(&Bl[nb][row][q * 8]) = v;
            }
        }

        bf16x8 fa[4], fb[4];
        #pragma unroll
        for (int mi = 0; mi < 4; ++mi)
            fa[mi] = *(const bf16x8*)(&Al[buf][mi * 16 + lr][lg * 8]);
        #pragma unroll
        for (int ni = 0; ni < 4; ++ni)
            fb[ni] = *(const bf16x8*)(&Bl[buf][wid * 64 + ni * 16 + lr][lg * 8]);
        #pragma unroll
        for (int mi = 0; mi < 4; ++mi)
            #pragma unroll
            for (int ni = 0; ni < 4; ++ni)
                acc[mi][ni] = __builtin_amdgcn_mfma_f32_16x16x32_bf16(fa[mi], fb[ni], acc[mi][ni], 0, 0, 0);
        __syncthreads();
        buf ^= 1;
    }

    #pragma unroll
    for (int mi = 0; mi < 4; ++mi) {
        int rbase = m0 + mi * 16 + lg * 4;
        #pragma unroll
        for (int v = 0; v < 4; ++v) {
            int gm = rbase + v;
            if (gm < M) {
                #pragma unroll
                for (int ni = 0; ni < 4; ++ni)
                    C[(size_t)gm * N + wid * 64 + ni * 16 + lr] = f2fp8(acc[mi][ni][v]);
            }
        }
    }
}

// ---------------- GEMM2 (LDS): h2_fp8[M,64] = fp8(relu(A_bf16[M,256]) @ W2T[64,256]^T) ----------------

__device__ inline uint relu_pk(uint u) {
    uint lo = u & 0x0000FFFFu;
    uint hi = u & 0xFFFF0000u;
    if (u & 0x00008000u) lo = 0;
    if (u & 0x80000000u) hi = 0;
    return lo | hi;
}

__global__ __launch_bounds__(256) void k_gemm2(const ushort* __restrict__ A,
                                               const ushort* __restrict__ BT,
                                               unsigned char* __restrict__ C,
                                               int M, int N, int K) {
    const int BM = 128, BK = 32;
    __shared__ ushort Al[BM][40];
    __shared__ ushort Bl[64][40];

    const int t    = threadIdx.x;
    const int lane = t & 63;
    const int wid  = t >> 6;
    const int wm   = wid >> 1, wn = wid & 1;
    const int m0   = blockIdx.x * BM;
    const int lr   = lane & 15;
    const int lg   = lane >> 4;

    f32x4 acc[4][2] = {};

    for (int k0 = 0; k0 < K; k0 += BK) {
        #pragma unroll
        for (int i = 0; i < 2; ++i) {
            int c = t + i * 256;
            int row = c >> 2, q = c & 3;
            int gm = m0 + row;
            uint4 v = make_uint4(0, 0, 0, 0);
            if (gm < M) v = *(const uint4*)(A + (size_t)gm * K + k0 + q * 8);
            v.x = relu_pk(v.x); v.y = relu_pk(v.y); v.z = relu_pk(v.z); v.w = relu_pk(v.w);
            *(uint4*)(&Al[row][q * 8]) = v;
        }
        {
            int row = t >> 2, q = t & 3;
            uint4 v = *(const uint4*)(BT + (size_t)(row) * K + k0 + q * 8);
            *(uint4*)(&Bl[row][q * 8]) = v;
        }
        __syncthreads();

        bf16x8 fa[4], fb[2];
        #pragma unroll
        for (int mi = 0; mi < 4; ++mi)
            fa[mi] = *(const bf16x8*)(&Al[wm * 64 + mi * 16 + lr][lg * 8]);
        #pragma unroll
        for (int ni = 0; ni < 2; ++ni)
            fb[ni] = *(const bf16x8*)(&Bl[wn * 32 + ni * 16 + lr][lg * 8]);
        #pragma unroll
        for (int mi = 0; mi < 4; ++mi)
            #pragma unroll
            for (int ni = 0; ni < 2; ++ni)
                acc[mi][ni] = __builtin_amdgcn_mfma_f32_16x16x32_bf16(fa[mi], fb[ni], acc[mi][ni], 0, 0, 0);
        __syncthreads();
    }

    #pragma unroll
    for (int mi = 0; mi < 4; ++mi) {
        int rbase = m0 + wm * 64 + mi * 16 + lg * 4;
        #pragma unroll
        for (int v = 0; v < 4; ++v) {
            int gm = rbase + v;
            if (gm < M) {
                #pragma unroll
                for (int ni = 0; ni < 2; ++ni)
                    C[(size_t)gm * N + wn * 32 + ni * 16 + lr] = f2fp8(acc[mi][ni][v]);
            }
        }
    }
}

// ---------------- gather aggregation (fp8 h1), one wave per dst node, 4-deep MLP ----------------

__global__ __launch_bounds__(256) void k_agg256(const unsigned char* __restrict__ h,
                                                const int2* __restrict__ csr_p,
                                                const int* __restrict__ off,
                                                const int* __restrict__ deg,
                                                const float* __restrict__ dis,
                                                const float* __restrict__ bias,
                                                ushort* __restrict__ out, int n) {
    int wave = (int)((blockIdx.x * (size_t)blockDim.x + threadIdx.x) >> 6);
    int lane = threadIdx.x & 63;
    if (wave >= n) return;
    const int i = wave;
    const float di = dis[i];
    const int beg = off[i], cnt = deg[i] - 1, end = beg + cnt;

    float4 bv = ((const float4*)bias)[lane];
    unsigned int hv = ((const unsigned int*)(h + (size_t)i * 256))[lane];
    float sl = di * di;
    float4 a0 = bv, a1 = {0,0,0,0}, a2 = {0,0,0,0}, a3 = {0,0,0,0};
    fp8x4_fma(hv, sl, a0);

    for (int base = beg; base < end; base += 64) {
        int m = end - base; if (m > 64) m = 64;
        int2 p = (lane < m) ? csr_p[base + lane] : make_int2(0, 0);
        int   msrc = p.x;
        float mw   = (lane < m) ? i2f(p.y) * di : 0.f;
        int k = 0;
        for (; k + 4 <= m; k += 4) {
            int s0 = __shfl(msrc, k),     s1 = __shfl(msrc, k + 1);
            int s2 = __shfl(msrc, k + 2), s3 = __shfl(msrc, k + 3);
            float w0 = __shfl(mw, k),     w1 = __shfl(mw, k + 1);
            float w2 = __shfl(mw, k + 2), w3 = __shfl(mw, k + 3);
            unsigned int v0 = ((const unsigned int*)(h + (size_t)s0 * 256))[lane];
            unsigned int v1 = ((const unsigned int*)(h + (size_t)s1 * 256))[lane];
            unsigned int v2 = ((const unsigned int*)(h + (size_t)s2 * 256))[lane];
            unsigned int v3 = ((const unsigned int*)(h + (size_t)s3 * 256))[lane];
            fp8x4_fma(v0, w0, a0);
            fp8x4_fma(v1, w1, a1);
            fp8x4_fma(v2, w2, a2);
            fp8x4_fma(v3, w3, a3);
        }
        for (; k < m; ++k) {
            int   s0 = __shfl(msrc, k); float w0 = __shfl(mw, k);
            unsigned int v0 = ((const unsigned int*)(h + (size_t)s0 * 256))[lane];
            fp8x4_fma(v0, w0, a0);
        }
    }
    ushort4 o;
    o.x = f2bf((a0.x + a1.x) + (a2.x + a3.x));
    o.y = f2bf((a0.y + a1.y) + (a2.y + a3.y));
    o.z = f2bf((a0.z + a1.z) + (a2.z + a3.z));
    o.w = f2bf((a0.w + a1.w) + (a2.w + a3.w));
    ((ushort4*)(out + (size_t)i * 256))[lane] = o;
}

// ---------------- agg64 (fp8 h2) fused with log-softmax: one wave per node; lane == class ----------------

__global__ __launch_bounds__(256) void k_agg64_lsm(const unsigned char* __restrict__ h,
                                                   const int2* __restrict__ csr_p,
                                                   const int* __restrict__ off,
                                                   const int* __restrict__ deg,
                                                   const float* __restrict__ dis,
                                                   const float* __restrict__ bias,
                                                   float* __restrict__ out, int n) {
    int wave = (int)((blockIdx.x * (size_t)blockDim.x + threadIdx.x) >> 6);
    int lane = threadIdx.x & 63;
    if (wave >= n) return;
    const int i = wave;
    const float di = dis[i];
    const int beg = off[i], cnt = deg[i] - 1, end = beg + cnt;

    float a0 = fmaf(fp8_dec1(h[(size_t)i * 64 + lane]), di * di, bias[lane]);
    float a1 = 0.f, a2 = 0.f, a3 = 0.f;

    for (int base = beg; base < end; base += 64) {
        int m = end - base; if (m > 64) m = 64;
        int2 p = (lane < m) ? csr_p[base + lane] : make_int2(0, 0);
        int   msrc = p.x;
        float mw   = (lane < m) ? i2f(p.y) * di : 0.f;
        int k = 0;
        for (; k + 4 <= m; k += 4) {
            int s0 = __shfl(msrc, k),     s1 = __shfl(msrc, k + 1);
            int s2 = __shfl(msrc, k + 2), s3 = __shfl(msrc, k + 3);
            float w0 = __shfl(mw, k),     w1 = __shfl(mw, k + 1);
            float w2 = __shfl(mw, k + 2), w3 = __shfl(mw, k + 3);
            a0 = fmaf(fp8_dec1(h[(size_t)s0 * 64 + lane]), w0, a0);
            a1 = fmaf(fp8_dec1(h[(size_t)s1 * 64 + lane]), w1, a1);
            a2 = fmaf(fp8_dec1(h[(size_t)s2 * 64 + lane]), w2, a2);
            a3 = fmaf(fp8_dec1(h[(size_t)s3 * 64 + lane]), w3, a3);
        }
        for (; k < m; ++k) {
            int s0 = __shfl(msrc, k); float w0 = __shfl(mw, k);
            a0 = fmaf(fp8_dec1(h[(size_t)s0 * 64 + lane]), w0, a0);
        }
    }
    float v = (a0 + a1) + (a2 + a3);

    float mx = v;
    #pragma unroll
    for (int o = 32; o > 0; o >>= 1) mx = fmaxf(mx, __shfl_xor(mx, o));
    float ex = __expf(v - mx);
    float ssum = ex;
    #pragma unroll
    for (int o = 32; o > 0; o >>= 1) ssum += __shfl_xor(ssum, o);
    out[(size_t)i * 64 + lane] = v - mx - logf(ssum);
}

// ---------------- launch ----------------

extern "C" void kernel_launch(void* const* d_in, const int* in_sizes, int n_in,
                              void* d_out, int out_size, void* d_ws, size_t ws_size,
                              hipStream_t stream) {
    const float* x  = (const float*)d_in[0];
    const int*   ei = (const int*)d_in[1];
    const float* W1 = (const float*)d_in[2];
    const float* b1 = (const float*)d_in[3];
    const float* W2 = (const float*)d_in[4];
    const float* b2 = (const float*)d_in[5];
    float* out = (float*)d_out;

    const int n = in_sizes[0] / 512;     // 100000
    const int E = in_sizes[1] / 2;       // 3200000
    const int* src = ei;
    const int* dst = ei + E;

    // workspace layout (bytes), 16B-aligned blocks
    char* ws = (char*)d_ws;
    int*    deg     = (int*)(ws + 0);               //    400,000
    float*  dis     = (float*)(ws + 400000);        //    400,000
    int*    offsets = (int*)(ws + 800000);          //    400,000
    int*    bhist   = (int*)(ws + 1200000);         //      1,024
    int*    bcur    = (int*)(ws + 1201024);         //      1,024
    int*    bbase   = (int*)(ws + 1202048);         //      1,024
    int2*   csr_p   = (int2*)(ws + 1203072);        // 25,600,000 -> 26,803,072
    ushort* W1T     = (ushort*)(ws + 26803072);     //    262,144 -> 27,065,216
    ushort* W2T     = (ushort*)(ws + 27065216);     //     32,768 -> 27,097,984
    unsigned char* h1 = (unsigned char*)(ws + 27097984);  // 25,600,000 -> 52,697,984
    ushort* out1    = (ushort*)(ws + 52697984);     // 51,200,000 -> 103,897,984
    unsigned char* h2 = (unsigned char*)(ws + 103897984); //  6,400,000 -> 110,297,984
    int2*   sorted  = (int2*)(ws + 110297984);      // 25,600,000 -> 135,897,984

    const int PB   = (E + 8191) / 8192;     // partition blocks
    const int NBKT = (n + 511) / 512;       // active buckets (196)

    // 0. fused setup (weight transposes, bhist zero)
    k_setup<<<577, 256, 0, stream>>>(W1, W1T, W2, W2T, bhist);

    // 1. bucket partition of edges by dst>>9 (LDS-staged multisplit, coalesced out)
    k_bhist<<<512, 256, 0, stream>>>(dst, E, bhist);
    k_bscan<<<1, 256, 0, stream>>>(bhist, bcur, bbase);
    k_partition<<<PB, 256, 0, stream>>>(src, dst, E, bcur, sorted);

    // 2. bucket-local CSR build (LDS counts/scans/cursors; no global atomics)
    k_bucket_deg<<<NBKT, 256, 0, stream>>>(sorted, E, bbase, deg, offsets, dis, n);
    k_bucket_fill<<<NBKT, 256, 0, stream>>>(sorted, E, bbase, offsets, dis, csr_p, n);

    // 3. h1 = fp8(x @ W1)  (double-buffered LDS)
    k_gemm1<<<(n + 63) / 64, TB, 0, stream>>>(x, W1T, h1, n, 256, 512);

    // 4. out1 = b1 + Â h1  (fp8 gathers)
    k_agg256<<<(n + 3) / 4, TB, 0, stream>>>(h1, csr_p, offsets, deg, dis, b1, out1, n);

    // 5. h2 = fp8(relu(out1) @ W2)
    k_gemm2<<<(n + 127) / 128, TB, 0, stream>>>(out1, W2T, h2, n, 64, 256);

    // 6. out = b2 + Â h2, log-softmax fused (fp8 gathers, one 64B line per row)
    k_agg64_lsm<<<(n + 3) / 4, TB, 0, stream>>>(h2, csr_p, offsets, deg, dis, b2, out, n);
}

// Round 22
// 416.505 us; speedup vs baseline: 1.3527x; 1.0000x over previous
//
#include <hip/hip_runtime.h>
#include <hip/hip_bf16.h>
#include <math.h>

#define TB 256

typedef __attribute__((ext_vector_type(8))) short bf16x8;
typedef __attribute__((ext_vector_type(4))) float f32x4;
typedef __attribute__((ext_vector_type(2))) float f32x2;

__device__ inline float bf2f(ushort u) {
    union { uint u; float f; } c; c.u = ((uint)u) << 16; return c.f;
}
__device__ inline ushort f2bf(float f) {
    __hip_bfloat16 h = __float2bfloat16(f);
    union { __hip_bfloat16 h; ushort u; } c; c.h = h; return c.u;
}
__device__ inline float i2f(int i) { union { int i; float f; } c; c.i = i; return c.f; }
__device__ inline int f2i(float f) { union { float f; int i; } c; c.f = f; return c.i; }

// ---------------- fp8 e4m3 encode/decode (HW cvt preferred; manual fallback) ----------------

#if __has_builtin(__builtin_amdgcn_cvt_pk_fp8_f32) && __has_builtin(__builtin_amdgcn_cvt_pk_f32_fp8)
#define FP8_HW 1
#endif

__device__ inline unsigned char f2fp8(float v) {
#ifdef FP8_HW
    unsigned int r = __builtin_amdgcn_cvt_pk_fp8_f32(v, v, 0u, false);
    return (unsigned char)(r & 0xffu);
#else
    unsigned int s = (v < 0.f) ? 0x80u : 0u;
    float a = fabsf(v);
    if (a >= 448.f) return (unsigned char)(s | 0x7E);
    if (a < 0.015625f) {
        int m = (int)(a * 512.f + 0.5f);
        if (m >= 8) return (unsigned char)(s | 0x08);
        return (unsigned char)(s | m);
    }
    int e; float fr = frexpf(a, &e);
    int m = (int)(fr * 16.f + 0.5f) - 8;
    int E = e + 6;
    if (m == 8) { m = 0; E += 1; }
    if (E >= 16) return (unsigned char)(s | 0x7E);
    return (unsigned char)(s | (E << 3) | m);
#endif
}

#ifndef FP8_HW
__device__ inline float fp8_to_f(unsigned int b) {
    unsigned int s = (b & 0x80u) << 24;
    unsigned int e = (b >> 3) & 0xFu;
    unsigned int m = b & 7u;
    if (e == 0) { float val = (float)m * 0.001953125f; return s ? -val : val; }
    union { unsigned int u; float f; } c;
    c.u = s | ((e + 120u) << 23) | (m << 20);
    return c.f;
}
#endif

__device__ inline void fp8x4_fma(unsigned int v, float w, float4& acc) {
#ifdef FP8_HW
    f32x2 lo = __builtin_amdgcn_cvt_pk_f32_fp8(v, false);
    f32x2 hi = __builtin_amdgcn_cvt_pk_f32_fp8(v, true);
    acc.x = fmaf(lo.x, w, acc.x);
    acc.y = fmaf(lo.y, w, acc.y);
    acc.z = fmaf(hi.x, w, acc.z);
    acc.w = fmaf(hi.y, w, acc.w);
#else
    acc.x = fmaf(fp8_to_f(v & 0xff), w, acc.x);
    acc.y = fmaf(fp8_to_f((v >> 8) & 0xff), w, acc.y);
    acc.z = fmaf(fp8_to_f((v >> 16) & 0xff), w, acc.z);
    acc.w = fmaf(fp8_to_f(v >> 24), w, acc.w);
#endif
}

__device__ inline float fp8_dec1(unsigned int b) {
#ifdef FP8_HW
    f32x2 lo = __builtin_amdgcn_cvt_pk_f32_fp8(b & 0xffu, false);
    return lo.x;
#else
    return fp8_to_f(b & 0xffu);
#endif
}

// ---------------- fused setup: W1/W2 transpose+cast, bhist zero ----------------

__global__ __launch_bounds__(256) void k_setup(const float* __restrict__ W1, ushort* __restrict__ W1T,
                                               const float* __restrict__ W2, ushort* __restrict__ W2T,
                                               int* __restrict__ bhist) {
    int b = blockIdx.x;
    int t = threadIdx.x;
    if (b < 512) {
        int id = b * 256 + t;                 // K=512, N=256
        int k = id >> 8, nn = id & 255;
        W1T[(size_t)nn * 512 + k] = f2bf(W1[id]);
    } else if (b < 576) {
        int id = (b - 512) * 256 + t;         // K=256, N=64
        int k = id >> 6, nn = id & 63;
        W2T[(size_t)nn * 256 + k] = f2bf(W2[id]);
    } else {
        bhist[t] = 0;
    }
}

// ---------------- bucket partition (256 buckets by dst>>9) ----------------

__global__ __launch_bounds__(256) void k_bhist(const int* __restrict__ dst, int E,
                                               int* __restrict__ hist) {
    __shared__ int lh[256];
    int t = threadIdx.x;
    lh[t] = 0;
    __syncthreads();
    for (int e = blockIdx.x * blockDim.x + t; e < E; e += gridDim.x * blockDim.x)
        atomicAdd(&lh[dst[e] >> 9], 1);
    __syncthreads();
    if (lh[t]) atomicAdd(&hist[t], lh[t]);
}

__global__ __launch_bounds__(256) void k_bscan(const int* __restrict__ hist,
                                               int* __restrict__ bcur,
                                               int* __restrict__ bbase) {
    __shared__ int sh[256];
    int t = threadIdx.x;
    int v = hist[t];
    sh[t] = v;
    __syncthreads();
    for (int off = 1; off < 256; off <<= 1) {
        int u = (t >= off) ? sh[t - off] : 0;
        __syncthreads();
        sh[t] += u;
        __syncthreads();
    }
    int excl = sh[t] - v;
    bcur[t]  = excl;   // mutable cursor for partition
    bbase[t] = excl;   // immutable bucket base
}

// LDS-staged multisplit: bin 8192 edges into LDS in bucket order, then write each
// bucket's run contiguously to its reserved global window (coalesced stores).
__global__ __launch_bounds__(256) void k_partition(const int* __restrict__ src,
                                                   const int* __restrict__ dst, int E,
                                                   int* __restrict__ bcur,
                                                   int2* __restrict__ sorted) {
    __shared__ int  lcnt[256];
    __shared__ int  pr[256];
    __shared__ int  lbase[256];
    __shared__ int  gbase[256];
    __shared__ int  lcur[256];
    __shared__ int2 lsort[8192];

    const int per = 8192;
    const int e0 = blockIdx.x * per;
    const int e1 = min(E, e0 + per);
    const int m  = e1 - e0;
    const int t  = threadIdx.x;

    lcnt[t] = 0;
    __syncthreads();
    for (int e = e0 + t; e < e1; e += 256)
        atomicAdd(&lcnt[dst[e] >> 9], 1);
    __syncthreads();

    int v = lcnt[t];
    pr[t] = v;
    __syncthreads();
    for (int off = 1; off < 256; off <<= 1) {
        int u = (t >= off) ? pr[t - off] : 0;
        __syncthreads();
        pr[t] += u;
        __syncthreads();
    }
    int excl = pr[t] - v;
    lbase[t] = excl;
    lcur[t]  = excl;
    gbase[t] = v ? atomicAdd(&bcur[t], v) : 0;
    __syncthreads();

    // bin into LDS in bucket order
    for (int e = e0 + t; e < e1; e += 256) {
        int d = dst[e], s = src[e];
        int lpos = atomicAdd(&lcur[d >> 9], 1);
        lsort[lpos] = make_int2(s, d);
    }
    __syncthreads();

    // linear sweep -> contiguous per-bucket global writes
    for (int j = t; j < m; j += 256) {
        int2 p = lsort[j];
        int b = p.y >> 9;
        sorted[gbase[b] + (j - lbase[b])] = p;
    }
}

// ---------------- bucket-local CSR build (two phases; dis must be globally complete
// before fill, so these stay separate kernels) ----------------

__global__ __launch_bounds__(256) void k_bucket_deg(const int2* __restrict__ sorted, int E,
                                                    const int* __restrict__ bbase,
                                                    int* __restrict__ deg,
                                                    int* __restrict__ offsets,
                                                    float* __restrict__ dis, int n) {
    __shared__ int cnt[512];
    __shared__ int pr[256];
    const int b = blockIdx.x;
    const int t = threadIdx.x;
    const int bstart = bbase[b];
    const int bend   = (b < 255) ? bbase[b + 1] : E;
    const int node0  = b << 9;

    cnt[t] = 0; cnt[t + 256] = 0;
    __syncthreads();
    for (int e = bstart + t; e < bend; e += 256)
        atomicAdd(&cnt[sorted[e].y & 511], 1);
    __syncthreads();

    int c0 = cnt[2 * t], c1 = cnt[2 * t + 1];
    pr[t] = c0 + c1;
    __syncthreads();
    for (int off = 1; off < 256; off <<= 1) {
        int u = (t >= off) ? pr[t - off] : 0;
        __syncthreads();
        pr[t] += u;
        __syncthreads();
    }
    int excl = pr[t] - (c0 + c1);

    int i0 = node0 + 2 * t, i1 = i0 + 1;
    if (i0 < n) {
        deg[i0] = c0 + 1;
        offsets[i0] = bstart + excl;
        dis[i0] = rsqrtf((float)(c0 + 1));
    }
    if (i1 < n) {
        deg[i1] = c1 + 1;
        offsets[i1] = bstart + excl + c0;
        dis[i1] = rsqrtf((float)(c1 + 1));
    }
}

__global__ __launch_bounds__(256) void k_bucket_fill(const int2* __restrict__ sorted, int E,
                                                     const int* __restrict__ bbase,
                                                     const int* __restrict__ offsets,
                                                     const float* __restrict__ dis,
                                                     int2* __restrict__ csr_p, int n) {
    __shared__ int cur[512];
    const int b = blockIdx.x;
    const int t = threadIdx.x;
    const int bstart = bbase[b];
    const int bend   = (b < 255) ? bbase[b + 1] : E;
    const int node0  = b << 9;

    int i0 = node0 + t, i1 = i0 + 256;
    cur[t]       = (i0 < n) ? offsets[i0] : 0;
    cur[t + 256] = (i1 < n) ? offsets[i1] : 0;
    __syncthreads();

    for (int e = bstart + t; e < bend; e += 256) {
        int2 p = sorted[e];
        int pos = atomicAdd(&cur[p.y & 511], 1);
        csr_p[pos] = make_int2(p.x, f2i(dis[p.x]));
    }
}

// ---------------- GEMM1 (LDS double-buffered): h1_fp8[M,256] = fp8(bf16(A[M,512]) @ W1T^T)

__global__ __launch_bounds__(256) void k_gemm1(const float* __restrict__ A,
                                               const ushort* __restrict__ BT,
                                               unsigned char* __restrict__ C,
                                               int M, int N, int K) {
    const int BM = 64, BK = 32;
    __shared__ ushort Al[2][BM][40];
    __shared__ ushort Bl[2][256][40];

    const int t    = threadIdx.x;
    const int lane = t & 63;
    const int wid  = t >> 6;
    const int m0   = blockIdx.x * BM;
    const int lr   = lane & 15;
    const int lg   = lane >> 4;

    const int arow = t >> 2, aq = t & 3;
    const int agm  = min(m0 + arow, M - 1);
    const bool avalid = (m0 + arow) < M;

    f32x4 acc[4][4] = {};

    {
        ushort4 o0 = {0,0,0,0}, o1 = {0,0,0,0};
        if (avalid) {
            const float* ap = A + (size_t)agm * K + aq * 8;
            float4 u = *(const float4*)ap;
            float4 w = *(const float4*)(ap + 4);
            o0.x = f2bf(u.x); o0.y = f2bf(u.y); o0.z = f2bf(u.z); o0.w = f2bf(u.w);
            o1.x = f2bf(w.x); o1.y = f2bf(w.y); o1.z = f2bf(w.z); o1.w = f2bf(w.w);
        }
        *(ushort4*)(&Al[0][arow][aq * 8])     = o0;
        *(ushort4*)(&Al[0][arow][aq * 8 + 4]) = o1;
        #pragma unroll
        for (int it = 0; it < 4; ++it) {
            int c = t + it * 256;
            int row = c >> 2, q = c & 3;
            uint4 v = *(const uint4*)(BT + (size_t)row * K + q * 8);
            *(uint4*)(&Bl[0][row][q * 8]) = v;
        }
    }
    __syncthreads();

    int buf = 0;
    for (int k0 = 0; k0 < K; k0 += BK) {
        if (k0 + BK < K) {
            int nb = buf ^ 1;
            int kn = k0 + BK;
            ushort4 o0 = {0,0,0,0}, o1 = {0,0,0,0};
            if (avalid) {
                const float* ap = A + (size_t)agm * K + kn + aq * 8;
                float4 u = *(const float4*)ap;
                float4 w = *(const float4*)(ap + 4);
                o0.x = f2bf(u.x); o0.y = f2bf(u.y); o0.z = f2bf(u.z); o0.w = f2bf(u.w);
                o1.x = f2bf(w.x); o1.y = f2bf(w.y); o1.z = f2bf(w.z); o1.w = f2bf(w.w);
            }
            *(ushort4*)(&Al[nb][arow][aq * 8])     = o0;
            *(ushort4*)(&Al[nb][arow][aq * 8 + 4]) = o1;
            #pragma unroll
            for (int it = 0; it < 4; ++it) {
                int c = t + it * 256;
                int row = c >> 2, q = c & 3;
                uint4 v = *(const uint4*)(BT + (size_t)row * K + kn + q * 8);
                *(uint4*)(&Bl[nb][row][q * 8]) = v;
            }
        }

        bf16x8 fa[4], fb[4];
        #pragma unroll
        for (int mi = 0; mi < 4; ++mi)
            fa[mi] = *(const bf16x8*)(&Al[buf][mi * 16 + lr][lg * 8]);
        #pragma unroll
        for (int ni = 0; ni < 4; ++ni)
            fb[ni] = *(const bf16x8*)(&Bl[buf][wid * 64 + ni * 16 + lr][lg * 8]);
        #pragma unroll
        for (int mi = 0; mi < 4; ++mi)
            #pragma unroll
            for (int ni = 0; ni < 4; ++ni)
                acc[mi][ni] = __builtin_amdgcn_mfma_f32_16x16x32_bf16(fa[mi], fb[ni], acc[mi][ni], 0, 0, 0);
        __syncthreads();
        buf ^= 1;
    }

    #pragma unroll
    for (int mi = 0; mi < 4; ++mi) {
        int rbase = m0 + mi * 16 + lg * 4;
        #pragma unroll
        for (int v = 0; v < 4; ++v) {
            int gm = rbase + v;
            if (gm < M) {
                #pragma unroll
                for (int ni = 0; ni < 4; ++ni)
                    C[(size_t)gm * N + wid * 64 + ni * 16 + lr] = f2fp8(acc[mi][ni][v]);
            }
        }
    }
}

// ---------------- GEMM2 (LDS): h2_fp8[M,64] = fp8(relu(A_bf16[M,256]) @ W2T[64,256]^T) ----------------

__device__ inline uint relu_pk(uint u) {
    uint lo = u & 0x0000FFFFu;
    uint hi = u & 0xFFFF0000u;
    if (u & 0x00008000u) lo = 0;
    if (u & 0x80000000u) hi = 0;
    return lo | hi;
}

__global__ __launch_bounds__(256) void k_gemm2(const ushort* __restrict__ A,
                                               const ushort* __restrict__ BT,
                                               unsigned char* __restrict__ C,
                                               int M, int N, int K) {
    const int BM = 128, BK = 32;
    __shared__ ushort Al[BM][40];
    __shared__ ushort Bl[64][40];

    const int t    = threadIdx.x;
    const int lane = t & 63;
    const int wid  = t >> 6;
    const int wm   = wid >> 1, wn = wid & 1;
    const int m0   = blockIdx.x * BM;
    const int lr   = lane & 15;
    const int lg   = lane >> 4;

    f32x4 acc[4][2] = {};

    for (int k0 = 0; k0 < K; k0 += BK) {
        #pragma unroll
        for (int i = 0; i < 2; ++i) {
            int c = t + i * 256;
            int row = c >> 2, q = c & 3;
            int gm = m0 + row;
            uint4 v = make_uint4(0, 0, 0, 0);
            if (gm < M) v = *(const uint4*)(A + (size_t)gm * K + k0 + q * 8);
            v.x = relu_pk(v.x); v.y = relu_pk(v.y); v.z = relu_pk(v.z); v.w = relu_pk(v.w);
            *(uint4*)(&Al[row][q * 8]) = v;
        }
        {
            int row = t >> 2, q = t & 3;
            uint4 v = *(const uint4*)(BT + (size_t)(row) * K + k0 + q * 8);
            *(uint4*)(&Bl[row][q * 8]) = v;
        }
        __syncthreads();

        bf16x8 fa[4], fb[2];
        #pragma unroll
        for (int mi = 0; mi < 4; ++mi)
            fa[mi] = *(const bf16x8*)(&Al[wm * 64 + mi * 16 + lr][lg * 8]);
        #pragma unroll
        for (int ni = 0; ni < 2; ++ni)
            fb[ni] = *(const bf16x8*)(&Bl[wn * 32 + ni * 16 + lr][lg * 8]);
        #pragma unroll
        for (int mi = 0; mi < 4; ++mi)
            #pragma unroll
            for (int ni = 0; ni < 2; ++ni)
                acc[mi][ni] = __builtin_amdgcn_mfma_f32_16x16x32_bf16(fa[mi], fb[ni], acc[mi][ni], 0, 0, 0);
        __syncthreads();
    }

    #pragma unroll
    for (int mi = 0; mi < 4; ++mi) {
        int rbase = m0 + wm * 64 + mi * 16 + lg * 4;
        #pragma unroll
        for (int v = 0; v < 4; ++v) {
            int gm = rbase + v;
            if (gm < M) {
                #pragma unroll
                for (int ni = 0; ni < 2; ++ni)
                    C[(size_t)gm * N + wn * 32 + ni * 16 + lr] = f2fp8(acc[mi][ni][v]);
            }
        }
    }
}

// ---------------- gather aggregation (fp8 h1), one wave per dst node, 4-deep MLP ----------------

__global__ __launch_bounds__(256) void k_agg256(const unsigned char* __restrict__ h,
                                                const int2* __restrict__ csr_p,
                                                const int* __restrict__ off,
                                                const int* __restrict__ deg,
                                                const float* __restrict__ dis,
                                                const float* __restrict__ bias,
                                                ushort* __restrict__ out, int n) {
    int wave = (int)((blockIdx.x * (size_t)blockDim.x + threadIdx.x) >> 6);
    int lane = threadIdx.x & 63;
    if (wave >= n) return;
    const int i = wave;
    const float di = dis[i];
    const int beg = off[i], cnt = deg[i] - 1, end = beg + cnt;

    float4 bv = ((const float4*)bias)[lane];
    unsigned int hv = ((const unsigned int*)(h + (size_t)i * 256))[lane];
    float sl = di * di;
    float4 a0 = bv, a1 = {0,0,0,0}, a2 = {0,0,0,0}, a3 = {0,0,0,0};
    fp8x4_fma(hv, sl, a0);

    for (int base = beg; base < end; base += 64) {
        int m = end - base; if (m > 64) m = 64;
        int2 p = (lane < m) ? csr_p[base + lane] : make_int2(0, 0);
        int   msrc = p.x;
        float mw   = (lane < m) ? i2f(p.y) * di : 0.f;
        int k = 0;
        for (; k + 4 <= m; k += 4) {
            int s0 = __shfl(msrc, k),     s1 = __shfl(msrc, k + 1);
            int s2 = __shfl(msrc, k + 2), s3 = __shfl(msrc, k + 3);
            float w0 = __shfl(mw, k),     w1 = __shfl(mw, k + 1);
            float w2 = __shfl(mw, k + 2), w3 = __shfl(mw, k + 3);
            unsigned int v0 = ((const unsigned int*)(h + (size_t)s0 * 256))[lane];
            unsigned int v1 = ((const unsigned int*)(h + (size_t)s1 * 256))[lane];
            unsigned int v2 = ((const unsigned int*)(h + (size_t)s2 * 256))[lane];
            unsigned int v3 = ((const unsigned int*)(h + (size_t)s3 * 256))[lane];
            fp8x4_fma(v0, w0, a0);
            fp8x4_fma(v1, w1, a1);
            fp8x4_fma(v2, w2, a2);
            fp8x4_fma(v3, w3, a3);
        }
        for (; k < m; ++k) {
            int   s0 = __shfl(msrc, k); float w0 = __shfl(mw, k);
            unsigned int v0 = ((const unsigned int*)(h + (size_t)s0 * 256))[lane];
            fp8x4_fma(v0, w0, a0);
        }
    }
    ushort4 o;
    o.x = f2bf((a0.x + a1.x) + (a2.x + a3.x));
    o.y = f2bf((a0.y + a1.y) + (a2.y + a3.y));
    o.z = f2bf((a0.z + a1.z) + (a2.z + a3.z));
    o.w = f2bf((a0.w + a1.w) + (a2.w + a3.w));
    ((ushort4*)(out + (size_t)i * 256))[lane] = o;
}

// ---------------- agg64 (fp8 h2) fused with log-softmax: one wave per node; lane == class ----------------

__global__ __launch_bounds__(256) void k_agg64_lsm(const unsigned char* __restrict__ h,
                                                   const int2* __restrict__ csr_p,
                                                   const int* __restrict__ off,
                                                   const int* __restrict__ deg,
                                                   const float* __restrict__ dis,
                                                   const float* __restrict__ bias,
                                                   float* __restrict__ out, int n) {
    int wave = (int)((blockIdx.x * (size_t)blockDim.x + threadIdx.x) >> 6);
    int lane = threadIdx.x & 63;
    if (wave >= n) return;
    const int i = wave;
    const float di = dis[i];
    const int beg = off[i], cnt = deg[i] - 1, end = beg + cnt;

    float a0 = fmaf(fp8_dec1(h[(size_t)i * 64 + lane]), di * di, bias[lane]);
    float a1 = 0.f, a2 = 0.f, a3 = 0.f;

    for (int base = beg; base < end; base += 64) {
        int m = end - base; if (m > 64) m = 64;
        int2 p = (lane < m) ? csr_p[base + lane] : make_int2(0, 0);
        int   msrc = p.x;
        float mw   = (lane < m) ? i2f(p.y) * di : 0.f;
        int k = 0;
        for (; k + 4 <= m; k += 4) {
            int s0 = __shfl(msrc, k),     s1 = __shfl(msrc, k + 1);
            int s2 = __shfl(msrc, k + 2), s3 = __shfl(msrc, k + 3);
            float w0 = __shfl(mw, k),     w1 = __shfl(mw, k + 1);
            float w2 = __shfl(mw, k + 2), w3 = __shfl(mw, k + 3);
            a0 = fmaf(fp8_dec1(h[(size_t)s0 * 64 + lane]), w0, a0);
            a1 = fmaf(fp8_dec1(h[(size_t)s1 * 64 + lane]), w1, a1);
            a2 = fmaf(fp8_dec1(h[(size_t)s2 * 64 + lane]), w2, a2);
            a3 = fmaf(fp8_dec1(h[(size_t)s3 * 64 + lane]), w3, a3);
        }
        for (; k < m; ++k) {
            int s0 = __shfl(msrc, k); float w0 = __shfl(mw, k);
            a0 = fmaf(fp8_dec1(h[(size_t)s0 * 64 + lane]), w0, a0);
        }
    }
    float v = (a0 + a1) + (a2 + a3);

    float mx = v;
    #pragma unroll
    for (int o = 32; o > 0; o >>= 1) mx = fmaxf(mx, __shfl_xor(mx, o));
    float ex = __expf(v - mx);
    float ssum = ex;
    #pragma unroll
    for (int o = 32; o > 0; o >>= 1) ssum += __shfl_xor(ssum, o);
    out[(size_t)i * 64 + lane] = v - mx - logf(ssum);
}

// ---------------- launch ----------------

extern "C" void kernel_launch(void* const* d_in, const int* in_sizes, int n_in,
                              void* d_out, int out_size, void* d_ws, size_t ws_size,
                              hipStream_t stream) {
    const float* x  = (const float*)d_in[0];
    const int*   ei = (const int*)d_in[1];
    const float* W1 = (const float*)d_in[2];
    const float* b1 = (const float*)d_in[3];
    const float* W2 = (const float*)d_in[4];
    const float* b2 = (const float*)d_in[5];
    float* out = (float*)d_out;

    const int n = in_sizes[0] / 512;     // 100000
    const int E = in_sizes[1] / 2;       // 3200000
    const int* src = ei;
    const int* dst = ei + E;

    // workspace layout (bytes), 16B-aligned blocks
    char* ws = (char*)d_ws;
    int*    deg     = (int*)(ws + 0);               //    400,000
    float*  dis     = (float*)(ws + 400000);        //    400,000
    int*    offsets = (int*)(ws + 800000);          //    400,000
    int*    bhist   = (int*)(ws + 1200000);         //      1,024
    int*    bcur    = (int*)(ws + 1201024);         //      1,024
    int*    bbase   = (int*)(ws + 1202048);         //      1,024
    int2*   csr_p   = (int2*)(ws + 1203072);        // 25,600,000 -> 26,803,072
    ushort* W1T     = (ushort*)(ws + 26803072);     //    262,144 -> 27,065,216
    ushort* W2T     = (ushort*)(ws + 27065216);     //     32,768 -> 27,097,984
    unsigned char* h1 = (unsigned char*)(ws + 27097984);  // 25,600,000 -> 52,697,984
    ushort* out1    = (ushort*)(ws + 52697984);     // 51,200,000 -> 103,897,984
    unsigned char* h2 = (unsigned char*)(ws + 103897984); //  6,400,000 -> 110,297,984
    int2*   sorted  = (int2*)(ws + 110297984);      // 25,600,000 -> 135,897,984

    const int PB   = (E + 8191) / 8192;     // partition blocks
    const int NBKT = (n + 511) / 512;       // active buckets (196)

    // 0. fused setup (weight transposes, bhist zero)
    k_setup<<<577, 256, 0, stream>>>(W1, W1T, W2, W2T, bhist);

    // 1. bucket partition of edges by dst>>9 (LDS-staged multisplit, coalesced out)
    k_bhist<<<512, 256, 0, stream>>>(dst, E, bhist);
    k_bscan<<<1, 256, 0, stream>>>(bhist, bcur, bbase);
    k_partition<<<PB, 256, 0, stream>>>(src, dst, E, bcur, sorted);

    // 2. bucket-local CSR build (two phases: dis must be globally complete before fill)
    k_bucket_deg<<<NBKT, 256, 0, stream>>>(sorted, E, bbase, deg, offsets, dis, n);
    k_bucket_fill<<<NBKT, 256, 0, stream>>>(sorted, E, bbase, offsets, dis, csr_p, n);

    // 3. h1 = fp8(x @ W1)  (double-buffered LDS)
    k_gemm1<<<(n + 63) / 64, TB, 0, stream>>>(x, W1T, h1, n, 256, 512);

    // 4. out1 = b1 + Â h1  (fp8 gathers)
    k_agg256<<<(n + 3) / 4, TB, 0, stream>>>(h1, csr_p, offsets, deg, dis, b1, out1, n);

    // 5. h2 = fp8(relu(out1) @ W2)
    k_gemm2<<<(n + 127) / 128, TB, 0, stream>>>(out1, W2T, h2, n, 64, 256);

    // 6. out = b2 + Â h2, log-softmax fused (fp8 gathers, one 64B line per row)
    k_agg64_lsm<<<(n + 3) / 4, TB, 0, stream>>>(h2, csr_p, offsets, deg, dis, b2, out, n);
}

// Round 23
// 413.713 us; speedup vs baseline: 1.3619x; 1.0067x over previous
//
#include <hip/hip_runtime.h>
#include <hip/hip_bf16.h>
#include <math.h>

#define TB 256

typedef __attribute__((ext_vector_type(8))) short bf16x8;
typedef __attribute__((ext_vector_type(4))) float f32x4;
typedef __attribute__((ext_vector_type(2))) float f32x2;

__device__ inline float bf2f(ushort u) {
    union { uint u; float f; } c; c.u = ((uint)u) << 16; return c.f;
}
__device__ inline ushort f2bf(float f) {
    __hip_bfloat16 h = __float2bfloat16(f);
    union { __hip_bfloat16 h; ushort u; } c; c.h = h; return c.u;
}

// ---------------- fp8 e4m3 encode/decode (HW cvt preferred; manual fallback) ----------------

#if __has_builtin(__builtin_amdgcn_cvt_pk_fp8_f32) && __has_builtin(__builtin_amdgcn_cvt_pk_f32_fp8)
#define FP8_HW 1
#endif

__device__ inline unsigned char f2fp8(float v) {
#ifdef FP8_HW
    unsigned int r = __builtin_amdgcn_cvt_pk_fp8_f32(v, v, 0u, false);
    return (unsigned char)(r & 0xffu);
#else
    unsigned int s = (v < 0.f) ? 0x80u : 0u;
    float a = fabsf(v);
    if (a >= 448.f) return (unsigned char)(s | 0x7E);
    if (a < 0.015625f) {
        int m = (int)(a * 512.f + 0.5f);
        if (m >= 8) return (unsigned char)(s | 0x08);
        return (unsigned char)(s | m);
    }
    int e; float fr = frexpf(a, &e);
    int m = (int)(fr * 16.f + 0.5f) - 8;
    int E = e + 6;
    if (m == 8) { m = 0; E += 1; }
    if (E >= 16) return (unsigned char)(s | 0x7E);
    return (unsigned char)(s | (E << 3) | m);
#endif
}

#ifndef FP8_HW
__device__ inline float fp8_to_f(unsigned int b) {
    unsigned int s = (b & 0x80u) << 24;
    unsigned int e = (b >> 3) & 0xFu;
    unsigned int m = b & 7u;
    if (e == 0) { float val = (float)m * 0.001953125f; return s ? -val : val; }
    union { unsigned int u; float f; } c;
    c.u = s | ((e + 120u) << 23) | (m << 20);
    return c.f;
}
#endif

__device__ inline void fp8x4_fma(unsigned int v, float w, float4& acc) {
#ifdef FP8_HW
    f32x2 lo = __builtin_amdgcn_cvt_pk_f32_fp8(v, false);
    f32x2 hi = __builtin_amdgcn_cvt_pk_f32_fp8(v, true);
    acc.x = fmaf(lo.x, w, acc.x);
    acc.y = fmaf(lo.y, w, acc.y);
    acc.z = fmaf(hi.x, w, acc.z);
    acc.w = fmaf(hi.y, w, acc.w);
#else
    acc.x = fmaf(fp8_to_f(v & 0xff), w, acc.x);
    acc.y = fmaf(fp8_to_f((v >> 8) & 0xff), w, acc.y);
    acc.z = fmaf(fp8_to_f((v >> 16) & 0xff), w, acc.z);
    acc.w = fmaf(fp8_to_f(v >> 24), w, acc.w);
#endif
}

__device__ inline float fp8_dec1(unsigned int b) {
#ifdef FP8_HW
    f32x2 lo = __builtin_amdgcn_cvt_pk_f32_fp8(b & 0xffu, false);
    return lo.x;
#else
    return fp8_to_f(b & 0xffu);
#endif
}

// ---------------- fused setup: W1/W2 transpose+cast, bhist zero ----------------

__global__ __launch_bounds__(256) void k_setup(const float* __restrict__ W1, ushort* __restrict__ W1T,
                                               const float* __restrict__ W2, ushort* __restrict__ W2T,
                                               int* __restrict__ bhist) {
    int b = blockIdx.x;
    int t = threadIdx.x;
    if (b < 512) {
        int id = b * 256 + t;                 // K=512, N=256
        int k = id >> 8, nn = id & 255;
        W1T[(size_t)nn * 512 + k] = f2bf(W1[id]);
    } else if (b < 576) {
        int id = (b - 512) * 256 + t;         // K=256, N=64
        int k = id >> 6, nn = id & 63;
        W2T[(size_t)nn * 256 + k] = f2bf(W2[id]);
    } else {
        bhist[t] = 0;
    }
}

// ---------------- bucket partition (256 buckets by dst>>9) ----------------

__global__ __launch_bounds__(256) void k_bhist(const int* __restrict__ dst, int E,
                                               int* __restrict__ hist) {
    __shared__ int lh[256];
    int t = threadIdx.x;
    lh[t] = 0;
    __syncthreads();
    for (int e = blockIdx.x * blockDim.x + t; e < E; e += gridDim.x * blockDim.x)
        atomicAdd(&lh[dst[e] >> 9], 1);
    __syncthreads();
    if (lh[t]) atomicAdd(&hist[t], lh[t]);
}

__global__ __launch_bounds__(256) void k_bscan(const int* __restrict__ hist,
                                               int* __restrict__ bcur,
                                               int* __restrict__ bbase) {
    __shared__ int sh[256];
    int t = threadIdx.x;
    int v = hist[t];
    sh[t] = v;
    __syncthreads();
    for (int off = 1; off < 256; off <<= 1) {
        int u = (t >= off) ? sh[t - off] : 0;
        __syncthreads();
        sh[t] += u;
        __syncthreads();
    }
    int excl = sh[t] - v;
    bcur[t]  = excl;   // mutable cursor for partition
    bbase[t] = excl;   // immutable bucket base
}

// LDS-staged multisplit; global output packed: (src<<9)|(dst&511), bucket implied by slice.
__global__ __launch_bounds__(256) void k_partition(const int* __restrict__ src,
                                                   const int* __restrict__ dst, int E,
                                                   int* __restrict__ bcur,
                                                   unsigned int* __restrict__ sorted) {
    __shared__ int  lcnt[256];
    __shared__ int  pr[256];
    __shared__ int  lbase[256];
    __shared__ int  gbase[256];
    __shared__ int  lcur[256];
    __shared__ int2 lsort[8192];

    const int per = 8192;
    const int e0 = blockIdx.x * per;
    const int e1 = min(E, e0 + per);
    const int m  = e1 - e0;
    const int t  = threadIdx.x;

    lcnt[t] = 0;
    __syncthreads();
    for (int e = e0 + t; e < e1; e += 256)
        atomicAdd(&lcnt[dst[e] >> 9], 1);
    __syncthreads();

    int v = lcnt[t];
    pr[t] = v;
    __syncthreads();
    for (int off = 1; off < 256; off <<= 1) {
        int u = (t >= off) ? pr[t - off] : 0;
        __syncthreads();
        pr[t] += u;
        __syncthreads();
    }
    int excl = pr[t] - v;
    lbase[t] = excl;
    lcur[t]  = excl;
    gbase[t] = v ? atomicAdd(&bcur[t], v) : 0;
    __syncthreads();

    // bin into LDS in bucket order
    for (int e = e0 + t; e < e1; e += 256) {
        int d = dst[e], s = src[e];
        int lpos = atomicAdd(&lcur[d >> 9], 1);
        lsort[lpos] = make_int2(s, d);
    }
    __syncthreads();

    // linear sweep -> contiguous per-bucket packed global writes
    for (int j = t; j < m; j += 256) {
        int2 p = lsort[j];
        int b = p.y >> 9;
        sorted[gbase[b] + (j - lbase[b])] = ((unsigned int)p.x << 9) | (unsigned int)(p.y & 511);
    }
}

// ---------------- bucket-local CSR build (two phases; dis must be globally complete
// before fill, so these stay separate kernels) ----------------
// sorted entry: (src<<9)|(node&511); csr entry: (src<<15)|dis_q (15-bit fixed-point dis)

__global__ __launch_bounds__(256) void k_bucket_deg(const unsigned int* __restrict__ sorted, int E,
                                                    const int* __restrict__ bbase,
                                                    int* __restrict__ deg,
                                                    int* __restrict__ offsets,
                                                    float* __restrict__ dis, int n) {
    __shared__ int cnt[512];
    __shared__ int pr[256];
    const int b = blockIdx.x;
    const int t = threadIdx.x;
    const int bstart = bbase[b];
    const int bend   = (b < 255) ? bbase[b + 1] : E;
    const int node0  = b << 9;

    cnt[t] = 0; cnt[t + 256] = 0;
    __syncthreads();
    for (int e = bstart + t; e < bend; e += 256)
        atomicAdd(&cnt[sorted[e] & 511u], 1);
    __syncthreads();

    int c0 = cnt[2 * t], c1 = cnt[2 * t + 1];
    pr[t] = c0 + c1;
    __syncthreads();
    for (int off = 1; off < 256; off <<= 1) {
        int u = (t >= off) ? pr[t - off] : 0;
        __syncthreads();
        pr[t] += u;
        __syncthreads();
    }
    int excl = pr[t] - (c0 + c1);

    int i0 = node0 + 2 * t, i1 = i0 + 1;
    if (i0 < n) {
        deg[i0] = c0 + 1;
        offsets[i0] = bstart + excl;
        dis[i0] = rsqrtf((float)(c0 + 1));
    }
    if (i1 < n) {
        deg[i1] = c1 + 1;
        offsets[i1] = bstart + excl + c0;
        dis[i1] = rsqrtf((float)(c1 + 1));
    }
}

__global__ __launch_bounds__(256) void k_bucket_fill(const unsigned int* __restrict__ sorted, int E,
                                                     const int* __restrict__ bbase,
                                                     const int* __restrict__ offsets,
                                                     const float* __restrict__ dis,
                                                     unsigned int* __restrict__ csr_p, int n) {
    __shared__ int cur[512];
    const int b = blockIdx.x;
    const int t = threadIdx.x;
    const int bstart = bbase[b];
    const int bend   = (b < 255) ? bbase[b + 1] : E;
    const int node0  = b << 9;

    int i0 = node0 + t, i1 = i0 + 256;
    cur[t]       = (i0 < n) ? offsets[i0] : 0;
    cur[t + 256] = (i1 < n) ? offsets[i1] : 0;
    __syncthreads();

    for (int e = bstart + t; e < bend; e += 256) {
        unsigned int p = sorted[e];
        int s = (int)(p >> 9);
        int pos = atomicAdd(&cur[p & 511u], 1);
        unsigned int dq = (unsigned int)(dis[s] * 32767.0f + 0.5f);
        csr_p[pos] = ((unsigned int)s << 15) | dq;
    }
}

// ---------------- GEMM1 (LDS double-buffered): h1_fp8[M,256] = fp8(bf16(A[M,512]) @ W1T^T)

__global__ __launch_bounds__(256) void k_gemm1(const float* __restrict__ A,
                                               const ushort* __restrict__ BT,
                                               unsigned char* __restrict__ C,
                                               int M, int N, int K) {
    const int BM = 64, BK = 32;
    __shared__ ushort Al[2][BM][40];
    __shared__ ushort Bl[2][256][40];

    const int t    = threadIdx.x;
    const int lane = t & 63;
    const int wid  = t >> 6;
    const int m0   = blockIdx.x * BM;
    const int lr   = lane & 15;
    const int lg   = lane >> 4;

    const int arow = t >> 2, aq = t & 3;
    const int agm  = min(m0 + arow, M - 1);
    const bool avalid = (m0 + arow) < M;

    f32x4 acc[4][4] = {};

    {
        ushort4 o0 = {0,0,0,0}, o1 = {0,0,0,0};
        if (avalid) {
            const float* ap = A + (size_t)agm * K + aq * 8;
            float4 u = *(const float4*)ap;
            float4 w = *(const float4*)(ap + 4);
            o0.x = f2bf(u.x); o0.y = f2bf(u.y); o0.z = f2bf(u.z); o0.w = f2bf(u.w);
            o1.x = f2bf(w.x); o1.y = f2bf(w.y); o1.z = f2bf(w.z); o1.w = f2bf(w.w);
        }
        *(ushort4*)(&Al[0][arow][aq * 8])     = o0;
        *(ushort4*)(&Al[0][arow][aq * 8 + 4]) = o1;
        #pragma unroll
        for (int it = 0; it < 4; ++it) {
            int c = t + it * 256;
            int row = c >> 2, q = c & 3;
            uint4 v = *(const uint4*)(BT + (size_t)row * K + q * 8);
            *(uint4*)(&Bl[0][row][q * 8]) = v;
        }
    }
    __syncthreads();

    int buf = 0;
    for (int k0 = 0; k0 < K; k0 += BK) {
        if (k0 + BK < K) {
            int nb = buf ^ 1;
            int kn = k0 + BK;
            ushort4 o0 = {0,0,0,0}, o1 = {0,0,0,0};
            if (avalid) {
                const float* ap = A + (size_t)agm * K + kn + aq * 8;
                float4 u = *(const float4*)ap;
                float4 w = *(const float4*)(ap + 4);
                o0.x = f2bf(u.x); o0.y = f2bf(u.y); o0.z = f2bf(u.z); o0.w = f2bf(u.w);
                o1.x = f2bf(w.x); o1.y = f2bf(w.y); o1.z = f2bf(w.z); o1.w = f2bf(w.w);
            }
            *(ushort4*)(&Al[nb][arow][aq * 8])     = o0;
            *(ushort4*)(&Al[nb][arow][aq * 8 + 4]) = o1;
            #pragma unroll
            for (int it = 0; it < 4; ++it) {
                int c = t + it * 256;
                int row = c >> 2, q = c & 3;
                uint4 v = *(const uint4*)(BT + (size_t)row * K + kn + q * 8);
                *(uint4*)(&Bl[nb][row][q * 8]) = v;
            }
        }

        bf16x8 fa[4], fb[4];
        #pragma unroll
        for (int mi = 0; mi < 4; ++mi)
            fa[mi] = *(const bf16x8*)(&Al[buf][mi * 16 + lr][lg * 8]);
        #pragma unroll
        for (int ni = 0; ni < 4; ++ni)
            fb[ni] = *(const bf16x8*)(&Bl[buf][wid * 64 + ni * 16 + lr][lg * 8]);
        #pragma unroll
        for (int mi = 0; mi < 4; ++mi)
            #pragma unroll
            for (int ni = 0; ni < 4; ++ni)
                acc[mi][ni] = __builtin_amdgcn_mfma_f32_16x16x32_bf16(fa[mi], fb[ni], acc[mi][ni], 0, 0, 0);
        __syncthreads();
        buf ^= 1;
    }

    #pragma unroll
    for (int mi = 0; mi < 4; ++mi) {
        int rbase = m0 + mi * 16 + lg * 4;
        #pragma unroll
        for (int v = 0; v < 4; ++v) {
            int gm = rbase + v;
            if (gm < M) {
                #pragma unroll
                for (int ni = 0; ni < 4; ++ni)
                    C[(size_t)gm * N + wid * 64 + ni * 16 + lr] = f2fp8(acc[mi][ni][v]);
            }
        }
    }
}

// ---------------- GEMM2 (LDS): h2_fp8[M,64] = fp8(relu(A_bf16[M,256]) @ W2T[64,256]^T) ----------------

__device__ inline uint relu_pk(uint u) {
    uint lo = u & 0x0000FFFFu;
    uint hi = u & 0xFFFF0000u;
    if (u & 0x00008000u) lo = 0;
    if (u & 0x80000000u) hi = 0;
    return lo | hi;
}

__global__ __launch_bounds__(256) void k_gemm2(const ushort* __restrict__ A,
                                               const ushort* __restrict__ BT,
                                               unsigned char* __restrict__ C,
                                               int M, int N, int K) {
    const int BM = 128, BK = 32;
    __shared__ ushort Al[BM][40];
    __shared__ ushort Bl[64][40];

    const int t    = threadIdx.x;
    const int lane = t & 63;
    const int wid  = t >> 6;
    const int wm   = wid >> 1, wn = wid & 1;
    const int m0   = blockIdx.x * BM;
    const int lr   = lane & 15;
    const int lg   = lane >> 4;

    f32x4 acc[4][2] = {};

    for (int k0 = 0; k0 < K; k0 += BK) {
        #pragma unroll
        for (int i = 0; i < 2; ++i) {
            int c = t + i * 256;
            int row = c >> 2, q = c & 3;
            int gm = m0 + row;
            uint4 v = make_uint4(0, 0, 0, 0);
            if (gm < M) v = *(const uint4*)(A + (size_t)gm * K + k0 + q * 8);
            v.x = relu_pk(v.x); v.y = relu_pk(v.y); v.z = relu_pk(v.z); v.w = relu_pk(v.w);
            *(uint4*)(&Al[row][q * 8]) = v;
        }
        {
            int row = t >> 2, q = t & 3;
            uint4 v = *(const uint4*)(BT + (size_t)(row) * K + k0 + q * 8);
            *(uint4*)(&Bl[row][q * 8]) = v;
        }
        __syncthreads();

        bf16x8 fa[4], fb[2];
        #pragma unroll
        for (int mi = 0; mi < 4; ++mi)
            fa[mi] = *(const bf16x8*)(&Al[wm * 64 + mi * 16 + lr][lg * 8]);
        #pragma unroll
        for (int ni = 0; ni < 2; ++ni)
            fb[ni] = *(const bf16x8*)(&Bl[wn * 32 + ni * 16 + lr][lg * 8]);
        #pragma unroll
        for (int mi = 0; mi < 4; ++mi)
            #pragma unroll
            for (int ni = 0; ni < 2; ++ni)
                acc[mi][ni] = __builtin_amdgcn_mfma_f32_16x16x32_bf16(fa[mi], fb[ni], acc[mi][ni], 0, 0, 0);
        __syncthreads();
    }

    #pragma unroll
    for (int mi = 0; mi < 4; ++mi) {
        int rbase = m0 + wm * 64 + mi * 16 + lg * 4;
        #pragma unroll
        for (int v = 0; v < 4; ++v) {
            int gm = rbase + v;
            if (gm < M) {
                #pragma unroll
                for (int ni = 0; ni < 2; ++ni)
                    C[(size_t)gm * N + wn * 32 + ni * 16 + lr] = f2fp8(acc[mi][ni][v]);
            }
        }
    }
}

// ---------------- gather aggregation (fp8 h1, packed csr), one wave per dst node ----------------

__global__ __launch_bounds__(256) void k_agg256(const unsigned char* __restrict__ h,
                                                const unsigned int* __restrict__ csr_p,
                                                const int* __restrict__ off,
                                                const int* __restrict__ deg,
                                                const float* __restrict__ dis,
                                                const float* __restrict__ bias,
                                                ushort* __restrict__ out, int n) {
    int wave = (int)((blockIdx.x * (size_t)blockDim.x + threadIdx.x) >> 6);
    int lane = threadIdx.x & 63;
    if (wave >= n) return;
    const int i = wave;
    const float di = dis[i];
    const float dscale = di * (1.0f / 32767.0f);
    const int beg = off[i], cnt = deg[i] - 1, end = beg + cnt;

    float4 bv = ((const float4*)bias)[lane];
    unsigned int hv = ((const unsigned int*)(h + (size_t)i * 256))[lane];
    float sl = di * di;
    float4 a0 = bv, a1 = {0,0,0,0}, a2 = {0,0,0,0}, a3 = {0,0,0,0};
    fp8x4_fma(hv, sl, a0);

    for (int base = beg; base < end; base += 64) {
        int m = end - base; if (m > 64) m = 64;
        unsigned int p = (lane < m) ? csr_p[base + lane] : 0u;
        int   msrc = (int)(p >> 15);
        float mw   = (float)(p & 0x7fffu) * dscale;
        int k = 0;
        for (; k + 4 <= m; k += 4) {
            int s0 = __shfl(msrc, k),     s1 = __shfl(msrc, k + 1);
            int s2 = __shfl(msrc, k + 2), s3 = __shfl(msrc, k + 3);
            float w0 = __shfl(mw, k),     w1 = __shfl(mw, k + 1);
            float w2 = __shfl(mw, k + 2), w3 = __shfl(mw, k + 3);
            unsigned int v0 = ((const unsigned int*)(h + (size_t)s0 * 256))[lane];
            unsigned int v1 = ((const unsigned int*)(h + (size_t)s1 * 256))[lane];
            unsigned int v2 = ((const unsigned int*)(h + (size_t)s2 * 256))[lane];
            unsigned int v3 = ((const unsigned int*)(h + (size_t)s3 * 256))[lane];
            fp8x4_fma(v0, w0, a0);
            fp8x4_fma(v1, w1, a1);
            fp8x4_fma(v2, w2, a2);
            fp8x4_fma(v3, w3, a3);
        }
        for (; k < m; ++k) {
            int   s0 = __shfl(msrc, k); float w0 = __shfl(mw, k);
            unsigned int v0 = ((const unsigned int*)(h + (size_t)s0 * 256))[lane];
            fp8x4_fma(v0, w0, a0);
        }
    }
    ushort4 o;
    o.x = f2bf((a0.x + a1.x) + (a2.x + a3.x));
    o.y = f2bf((a0.y + a1.y) + (a2.y + a3.y));
    o.z = f2bf((a0.z + a1.z) + (a2.z + a3.z));
    o.w = f2bf((a0.w + a1.w) + (a2.w + a3.w));
    ((ushort4*)(out + (size_t)i * 256))[lane] = o;
}

// ---------------- agg64 (fp8 h2, packed csr) fused with log-softmax ----------------

__global__ __launch_bounds__(256) void k_agg64_lsm(const unsigned char* __restrict__ h,
                                                   const unsigned int* __restrict__ csr_p,
                                                   const int* __restrict__ off,
                                                   const int* __restrict__ deg,
                                                   const float* __restrict__ dis,
                                                   const float* __restrict__ bias,
                                                   float* __restrict__ out, int n) {
    int wave = (int)((blockIdx.x * (size_t)blockDim.x + threadIdx.x) >> 6);
    int lane = threadIdx.x & 63;
    if (wave >= n) return;
    const int i = wave;
    const float di = dis[i];
    const float dscale = di * (1.0f / 32767.0f);
    const int beg = off[i], cnt = deg[i] - 1, end = beg + cnt;

    float a0 = fmaf(fp8_dec1(h[(size_t)i * 64 + lane]), di * di, bias[lane]);
    float a1 = 0.f, a2 = 0.f, a3 = 0.f;

    for (int base = beg; base < end; base += 64) {
        int m = end - base; if (m > 64) m = 64;
        unsigned int p = (lane < m) ? csr_p[base + lane] : 0u;
        int   msrc = (int)(p >> 15);
        float mw   = (float)(p & 0x7fffu) * dscale;
        int k = 0;
        for (; k + 4 <= m; k += 4) {
            int s0 = __shfl(msrc, k),     s1 = __shfl(msrc, k + 1);
            int s2 = __shfl(msrc, k + 2), s3 = __shfl(msrc, k + 3);
            float w0 = __shfl(mw, k),     w1 = __shfl(mw, k + 1);
            float w2 = __shfl(mw, k + 2), w3 = __shfl(mw, k + 3);
            a0 = fmaf(fp8_dec1(h[(size_t)s0 * 64 + lane]), w0, a0);
            a1 = fmaf(fp8_dec1(h[(size_t)s1 * 64 + lane]), w1, a1);
            a2 = fmaf(fp8_dec1(h[(size_t)s2 * 64 + lane]), w2, a2);
            a3 = fmaf(fp8_dec1(h[(size_t)s3 * 64 + lane]), w3, a3);
        }
        for (; k < m; ++k) {
            int s0 = __shfl(msrc, k); float w0 = __shfl(mw, k);
            a0 = fmaf(fp8_dec1(h[(size_t)s0 * 64 + lane]), w0, a0);
        }
    }
    float v = (a0 + a1) + (a2 + a3);

    float mx = v;
    #pragma unroll
    for (int o = 32; o > 0; o >>= 1) mx = fmaxf(mx, __shfl_xor(mx, o));
    float ex = __expf(v - mx);
    float ssum = ex;
    #pragma unroll
    for (int o = 32; o > 0; o >>= 1) ssum += __shfl_xor(ssum, o);
    out[(size_t)i * 64 + lane] = v - mx - logf(ssum);
}

// ---------------- launch ----------------

extern "C" void kernel_launch(void* const* d_in, const int* in_sizes, int n_in,
                              void* d_out, int out_size, void* d_ws, size_t ws_size,
                              hipStream_t stream) {
    const float* x  = (const float*)d_in[0];
    const int*   ei = (const int*)d_in[1];
    const float* W1 = (const float*)d_in[2];
    const float* b1 = (const float*)d_in[3];
    const float* W2 = (const float*)d_in[4];
    const float* b2 = (const float*)d_in[5];
    float* out = (float*)d_out;

    const int n = in_sizes[0] / 512;     // 100000
    const int E = in_sizes[1] / 2;       // 3200000
    const int* src = ei;
    const int* dst = ei + E;

    // workspace layout (bytes), 16B-aligned blocks
    char* ws = (char*)d_ws;
    int*    deg     = (int*)(ws + 0);               //    400,000
    float*  dis     = (float*)(ws + 400000);        //    400,000
    int*    offsets = (int*)(ws + 800000);          //    400,000
    int*    bhist   = (int*)(ws + 1200000);         //      1,024
    int*    bcur    = (int*)(ws + 1201024);         //      1,024
    int*    bbase   = (int*)(ws + 1202048);         //      1,024
    unsigned int* csr_p = (unsigned int*)(ws + 1203072);   // 12,800,000 -> 14,003,072
    ushort* W1T     = (ushort*)(ws + 14003072);     //    262,144 -> 14,265,216
    ushort* W2T     = (ushort*)(ws + 14265216);     //     32,768 -> 14,297,984
    unsigned char* h1 = (unsigned char*)(ws + 14297984);   // 25,600,000 -> 39,897,984
    ushort* out1    = (ushort*)(ws + 39897984);     // 51,200,000 -> 91,097,984
    unsigned char* h2 = (unsigned char*)(ws + 91097984);   //  6,400,000 -> 97,497,984
    unsigned int* sorted = (unsigned int*)(ws + 97497984); // 12,800,000 -> 110,297,984

    const int PB   = (E + 8191) / 8192;     // partition blocks
    const int NBKT = (n + 511) / 512;       // active buckets (196)

    // 0. fused setup (weight transposes, bhist zero)
    k_setup<<<577, 256, 0, stream>>>(W1, W1T, W2, W2T, bhist);

    // 1. bucket partition of edges by dst>>9 (LDS-staged multisplit, packed coalesced out)
    k_bhist<<<512, 256, 0, stream>>>(dst, E, bhist);
    k_bscan<<<1, 256, 0, stream>>>(bhist, bcur, bbase);
    k_partition<<<PB, 256, 0, stream>>>(src, dst, E, bcur, sorted);

    // 2. bucket-local CSR build (two phases: dis must be globally complete before fill)
    k_bucket_deg<<<NBKT, 256, 0, stream>>>(sorted, E, bbase, deg, offsets, dis, n);
    k_bucket_fill<<<NBKT, 256, 0, stream>>>(sorted, E, bbase, offsets, dis, csr_p, n);

    // 3. h1 = fp8(x @ W1)  (double-buffered LDS)
    k_gemm1<<<(n + 63) / 64, TB, 0, stream>>>(x, W1T, h1, n, 256, 512);

    // 4. out1 = b1 + Â h1  (fp8 gathers, packed csr)
    k_agg256<<<(n + 3) / 4, TB, 0, stream>>>(h1, csr_p, offsets, deg, dis, b1, out1, n);

    // 5. h2 = fp8(relu(out1) @ W2)
    k_gemm2<<<(n + 127) / 128, TB, 0, stream>>>(out1, W2T, h2, n, 64, 256);

    // 6. out = b2 + Â h2, log-softmax fused (fp8 gathers, packed csr)
    k_agg64_lsm<<<(n + 3) / 4, TB, 0, stream>>>(h2, csr_p, offsets, deg, dis, b2, out, n);
}